// Round 1
// baseline (1253.994 us; speedup 1.0000x reference)
//
#include <hip/hip_runtime.h>
#include <math.h>

#define D64 64
#define KTAB 4096   // lerp table intervals over r in [0,5]

// ---------------- helpers ----------------
__device__ __forceinline__ void atomAddF(float* p, float v) {
  __hip_atomic_fetch_add(p, v, __ATOMIC_RELAXED, __HIP_MEMORY_SCOPE_AGENT);
}
__device__ __forceinline__ unsigned fkey(float f) {
  unsigned u = __float_as_uint(f);
  return (u & 0x80000000u) ? ~u : (u | 0x80000000u);
}
__device__ __forceinline__ float funkey(unsigned k) {
  return __uint_as_float((k & 0x80000000u) ? (k & 0x7fffffffu) : ~k);
}
__device__ __forceinline__ float swishf(float x) { return x / (1.0f + expf(-x)); }

// feat[i,d] = emb[z[i],d]
__global__ void k_init(const int* __restrict__ z, const float* __restrict__ emb,
                       float* __restrict__ feat, int total) {
  int idx = blockIdx.x * 256 + threadIdx.x;
  if (idx < total) feat[idx] = emb[z[idx >> 6] * D64 + (idx & 63)];
}

__global__ void k_hist(const int* __restrict__ dst, int* __restrict__ deg, int E) {
  for (int i = blockIdx.x * blockDim.x + threadIdx.x; i < E; i += gridDim.x * blockDim.x)
    atomicAdd(&deg[dst[i]], 1);
}

// single-block exclusive scan over deg[0..n) -> rp[0..n], also copies into cur
__global__ void k_scan(const int* __restrict__ deg, int* __restrict__ rp,
                       int* __restrict__ cur, int n) {
  __shared__ int sb[1024];
  __shared__ int carry_s;
  const int tid = threadIdx.x;
  if (tid == 0) carry_s = 0;
  __syncthreads();
  for (int base = 0; base < n; base += 4096) {
    int i0 = base + tid * 4;
    int v[4];
#pragma unroll
    for (int q = 0; q < 4; ++q) { int i = i0 + q; v[q] = (i < n) ? deg[i] : 0; }
    int s = v[0] + v[1] + v[2] + v[3];
    sb[tid] = s;
    __syncthreads();
    for (int o = 1; o < 1024; o <<= 1) {
      int t = (tid >= o) ? sb[tid - o] : 0;
      __syncthreads();
      sb[tid] += t;
      __syncthreads();
    }
    int incl = sb[tid];
    int carry = carry_s;
    int excl = carry + incl - s;
#pragma unroll
    for (int q = 0; q < 4; ++q) {
      int i = i0 + q;
      if (i < n) { rp[i] = excl; cur[i] = excl; }
      excl += v[q];
    }
    __syncthreads();
    if (tid == 1023) carry_s = carry + incl;
    __syncthreads();
  }
  if (tid == 0) rp[n] = carry_s;
}

// bucket edges by dst: ep[pos] = {src, float_bits(r * KTAB/5)}
__global__ void k_scatter(const int* __restrict__ src, const int* __restrict__ dst,
                          const float* __restrict__ rij, int* __restrict__ cur,
                          int2* __restrict__ ep, int E, float ks) {
  for (int i = blockIdx.x * blockDim.x + threadIdx.x; i < E; i += gridDim.x * blockDim.x) {
    int nd = dst[i];
    int pos = atomicAdd(&cur[nd], 1);
    ep[pos] = make_int2(src[i], __float_as_int(rij[i] * ks));
  }
}

// T[l][g][d] = (swish(fij(r_g)@Wf1[l]+bf1[l]) @ Wf2[l] + bf2[l])[d] * C(r_g)
__global__ __launch_bounds__(256) void k_tables(const float* __restrict__ Wf1,
                                                const float* __restrict__ bf1,
                                                const float* __restrict__ Wf2,
                                                const float* __restrict__ bf2,
                                                float* __restrict__ T) {
  __shared__ __align__(16) float rb[4][D64];
  const int lane = threadIdx.x & 63;
  const int wsl = threadIdx.x >> 6;
  const int wid = blockIdx.x * 4 + wsl;
  if (wid >= 3 * (KTAB + 1)) return;
  const int l = wid / (KTAB + 1);
  const int g = wid - l * (KTAB + 1);
  const float r = (float)g * (5.0f / KTAB);
  const float width = 5.0f / 24.0f;
  const float coeff = -0.5f / (width * width);
  float fv = 0.0f;
  if (lane < 25) { float dd = r - (float)lane * width; fv = expf(coeff * dd * dd); }
  rb[wsl][lane] = fv;
  float a1 = bf1[l * D64 + lane];
#pragma unroll
  for (int b = 0; b < 25; ++b)
    a1 = fmaf(rb[wsl][b], Wf1[(l * 25 + b) * D64 + lane], a1);
  float sw = swishf(a1);
  rb[wsl][lane] = sw;   // same-wave reuse; program order preserves DS deps
  float a2 = bf2[l * D64 + lane];
#pragma unroll
  for (int k = 0; k < D64; ++k)
    a2 = fmaf(rb[wsl][k], Wf2[l * D64 * D64 + k * D64 + lane], a2);
  float C = (r < 5.0f) ? 0.5f * (cosf(r * 0.62831853f) + 1.0f) : 0.0f;
  T[(size_t)(l * (KTAB + 1) + g) * D64 + lane] = a2 * C;
}

// x1 = feat @ Win  (wave per row; Win column in VGPRs; row broadcast via LDS)
__global__ __launch_bounds__(256) void k_x1(const float* __restrict__ feat,
                                            const float* __restrict__ Win,
                                            float* __restrict__ x1, int n) {
  __shared__ __align__(16) float rb[4][D64];
  const int lane = threadIdx.x & 63;
  const int wsl = threadIdx.x >> 6;
  float wcol[D64];
#pragma unroll
  for (int k = 0; k < D64; ++k) wcol[k] = Win[k * D64 + lane];
  const int wid = blockIdx.x * 4 + wsl;
  const int nw = gridDim.x * 4;
  for (int row = wid; row < n; row += nw) {
    rb[wsl][lane] = feat[(size_t)row * D64 + lane];
    float acc = 0.0f;
#pragma unroll
    for (int k4 = 0; k4 < 16; ++k4) {
      float4 f4 = *(const float4*)&rb[wsl][k4 * 4];
      acc = fmaf(f4.x, wcol[k4 * 4 + 0], acc);
      acc = fmaf(f4.y, wcol[k4 * 4 + 1], acc);
      acc = fmaf(f4.z, wcol[k4 * 4 + 2], acc);
      acc = fmaf(f4.w, wcol[k4 * 4 + 3], acc);
    }
    x1[(size_t)row * D64 + lane] = acc;
  }
}

// agg[nd] = sum over incoming edges of x1[src] * lerp(T, r)
__global__ __launch_bounds__(256) void k_gather(const float* __restrict__ x1,
                                                const float* __restrict__ T,
                                                const int2* __restrict__ ep,
                                                const int* __restrict__ rp,
                                                float* __restrict__ agg, int n) {
  const int lane = threadIdx.x & 63;
  const int wid = (blockIdx.x * blockDim.x + threadIdx.x) >> 6;
  const int nw = (gridDim.x * blockDim.x) >> 6;
  for (int nd = wid; nd < n; nd += nw) {
    const int j0 = rp[nd], j1 = rp[nd + 1];
    float acc = 0.0f;
    for (int j = j0; j < j1; ++j) {
      const int2 e = ep[j];
      const float p = __int_as_float(e.y);
      int k = (int)p;
      k = (k > KTAB - 1) ? (KTAB - 1) : k;
      const float t = p - (float)k;
      const float w0 = T[(size_t)k * D64 + lane];
      const float w1 = T[(size_t)k * D64 + D64 + lane];
      acc = fmaf(x1[(size_t)e.x * D64 + lane], fmaf(t, w1 - w0, w0), acc);
    }
    agg[(size_t)nd * D64 + lane] = acc;
  }
}

// y = swish(agg@Wo1+bo1)@Wo2+bo2; feat += y; accumulate sum(f), sum(f^2)
__global__ __launch_bounds__(256) void k_out(const float* __restrict__ agg,
                                             const float* __restrict__ Wo1,
                                             const float* __restrict__ bo1,
                                             const float* __restrict__ Wo2,
                                             const float* __restrict__ bo2,
                                             float* __restrict__ feat,
                                             float* __restrict__ stats, int n) {
  __shared__ __align__(16) float rb[4][D64];
  const int lane = threadIdx.x & 63;
  const int wsl = threadIdx.x >> 6;
  float w1c[D64], w2c[D64];
#pragma unroll
  for (int k = 0; k < D64; ++k) w1c[k] = Wo1[k * D64 + lane];
#pragma unroll
  for (int k = 0; k < D64; ++k) w2c[k] = Wo2[k * D64 + lane];
  const float b1 = bo1[lane], b2 = bo2[lane];
  float sf = 0.0f, sf2 = 0.0f;
  const int wid = blockIdx.x * 4 + wsl;
  const int nw = gridDim.x * 4;
  for (int row = wid; row < n; row += nw) {
    rb[wsl][lane] = agg[(size_t)row * D64 + lane];
    float a1 = b1;
#pragma unroll
    for (int k4 = 0; k4 < 16; ++k4) {
      float4 f4 = *(const float4*)&rb[wsl][k4 * 4];
      a1 = fmaf(f4.x, w1c[k4 * 4 + 0], a1);
      a1 = fmaf(f4.y, w1c[k4 * 4 + 1], a1);
      a1 = fmaf(f4.z, w1c[k4 * 4 + 2], a1);
      a1 = fmaf(f4.w, w1c[k4 * 4 + 3], a1);
    }
    float sw = swishf(a1);
    rb[wsl][lane] = sw;   // reuse: program-order DS dependence keeps this safe in-wave
    float a2 = b2;
#pragma unroll
    for (int k4 = 0; k4 < 16; ++k4) {
      float4 f4 = *(const float4*)&rb[wsl][k4 * 4];
      a2 = fmaf(f4.x, w2c[k4 * 4 + 0], a2);
      a2 = fmaf(f4.y, w2c[k4 * 4 + 1], a2);
      a2 = fmaf(f4.z, w2c[k4 * 4 + 2], a2);
      a2 = fmaf(f4.w, w2c[k4 * 4 + 3], a2);
    }
    float fn = feat[(size_t)row * D64 + lane] + a2;
    feat[(size_t)row * D64 + lane] = fn;
    sf += fn;
    sf2 += fn * fn;
  }
  atomAddF(&stats[lane], sf);
  atomAddF(&stats[64 + lane], sf2);
}

// per-feature: scale/shift for GraphNorm. var = E[f^2] - (2a - a^2) mu^2
__global__ void k_nfin(float* __restrict__ stats, const float* __restrict__ al,
                       const float* __restrict__ ga, const float* __restrict__ be, int n) {
  int d = threadIdx.x;
  if (d >= D64) return;
  float invN = 1.0f / (float)n;
  float mu = stats[d] * invN;
  float ex2 = stats[64 + d] * invN;
  float a = al[d];
  float var = ex2 - (2.0f * a - a * a) * mu * mu;
  float sc = ga[d] * rsqrtf(var + 1e-5f);
  stats[128 + d] = sc;
  stats[192 + d] = be[d] - sc * a * mu;
}

__global__ void k_napp(float* __restrict__ feat, const float* __restrict__ stats, int total) {
  int idx = blockIdx.x * 256 + threadIdx.x;
  if (idx < total) {
    int d = idx & 63;
    feat[idx] = fmaf(feat[idx], stats[128 + d], stats[192 + d]);
  }
}

__global__ __launch_bounds__(256) void k_colmax(const float* __restrict__ feat,
                                                unsigned* __restrict__ um, int n) {
  const int lane = threadIdx.x & 63;
  const int wid = (blockIdx.x * blockDim.x + threadIdx.x) >> 6;
  const int nw = (gridDim.x * blockDim.x) >> 6;
  float m = -3.402823e38f;
  for (int r = wid; r < n; r += nw) m = fmaxf(m, feat[(size_t)r * D64 + lane]);
  atomicMax(&um[lane], fkey(m));
}

__global__ __launch_bounds__(256) void k_colsum(const float* __restrict__ feat,
                                                float* __restrict__ rd, int n) {
  const unsigned* um = (const unsigned*)rd;
  const int lane = threadIdx.x & 63;
  const int wid = (blockIdx.x * blockDim.x + threadIdx.x) >> 6;
  const int nw = (gridDim.x * blockDim.x) >> 6;
  const float mx = funkey(um[lane]);
  float s1 = 0.0f, s2 = 0.0f;
  for (int r = wid; r < n; r += nw) {
    float f = feat[(size_t)r * D64 + lane];
    float e = expf(f - mx);
    s1 += e;
    s2 += e * f;
  }
  atomAddF(&rd[64 + lane], s1);
  atomAddF(&rd[128 + lane], s2);
}

__global__ void k_pooled(const float* __restrict__ rd, float* __restrict__ out) {
  int d = threadIdx.x;
  if (d < D64) out[d] = rd[128 + d] / rd[64 + d];
}

extern "C" void kernel_launch(void* const* d_in, const int* in_sizes, int n_in,
                              void* d_out, int out_size, void* d_ws, size_t ws_size,
                              hipStream_t stream) {
  const int* z = (const int*)d_in[0];
  const int* src = (const int*)d_in[1];
  const int* dst = (const int*)d_in[2];
  const float* rij = (const float*)d_in[3];
  const float* emb = (const float*)d_in[4];
  const float* Win = (const float*)d_in[5];
  const float* Wf1 = (const float*)d_in[6];
  const float* bf1 = (const float*)d_in[7];
  const float* Wf2 = (const float*)d_in[8];
  const float* bf2 = (const float*)d_in[9];
  const float* Wo1 = (const float*)d_in[10];
  const float* bo1 = (const float*)d_in[11];
  const float* Wo2 = (const float*)d_in[12];
  const float* bo2 = (const float*)d_in[13];
  const float* gal = (const float*)d_in[14];
  const float* gga = (const float*)d_in[15];
  const float* gbe = (const float*)d_in[16];
  const int n = in_sizes[0];
  const int E = in_sizes[1];
  (void)n_in; (void)out_size; (void)ws_size;

  float* feat = (float*)d_out;                 // [n,64] lives in d_out
  float* pooled = feat + (size_t)n * D64;      // [64]

  char* w = (char*)d_ws;
  size_t off = 0;
  auto take = [&](size_t bytes) {
    size_t o = (off + 255) & ~(size_t)255;
    off = o + bytes;
    return (void*)(w + o);
  };
  float* x1 = (float*)take((size_t)n * D64 * 4);
  float* agg = (float*)take((size_t)n * D64 * 4);
  float* stats = (float*)take(256 * 4);
  float* rdst = (float*)take(192 * 4);
  float* T = (float*)take((size_t)3 * (KTAB + 1) * D64 * 4);
  int* deg = (int*)take((size_t)n * 4);
  int* rp = (int*)take((size_t)(n + 1) * 4);
  int* cur = (int*)take((size_t)n * 4);
  int2* ep = (int2*)take((size_t)E * 8);

  hipMemsetAsync(deg, 0, (size_t)n * 4, stream);
  k_init<<<(n * D64 + 255) / 256, 256, 0, stream>>>(z, emb, feat, n * D64);
  k_hist<<<1024, 256, 0, stream>>>(dst, deg, E);
  k_scan<<<1, 1024, 0, stream>>>(deg, rp, cur, n);
  k_scatter<<<1024, 256, 0, stream>>>(src, dst, rij, cur, ep, E, (float)KTAB / 5.0f);
  k_tables<<<(3 * (KTAB + 1) + 3) / 4, 256, 0, stream>>>(Wf1, bf1, Wf2, bf2, T);

  for (int l = 0; l < 3; ++l) {
    k_x1<<<512, 256, 0, stream>>>(feat, Win + (size_t)l * D64 * D64, x1, n);
    hipMemsetAsync(stats, 0, 256 * 4, stream);
    k_gather<<<2048, 256, 0, stream>>>(x1, T + (size_t)l * (KTAB + 1) * D64, ep, rp, agg, n);
    k_out<<<1024, 256, 0, stream>>>(agg, Wo1 + (size_t)l * D64 * D64, bo1 + l * D64,
                                    Wo2 + (size_t)l * D64 * D64, bo2 + l * D64, feat, stats, n);
    k_nfin<<<1, 64, 0, stream>>>(stats, gal + l * D64, gga + l * D64, gbe + l * D64, n);
    k_napp<<<(n * D64 + 255) / 256, 256, 0, stream>>>(feat, stats, n * D64);
  }

  hipMemsetAsync(rdst, 0, 192 * 4, stream);
  k_colmax<<<512, 256, 0, stream>>>(feat, (unsigned*)rdst, n);
  k_colsum<<<512, 256, 0, stream>>>(feat, rdst, n);
  k_pooled<<<1, 64, 0, stream>>>(rdst, pooled);
}

// Round 2
// 1080.191 us; speedup vs baseline: 1.1609x; 1.1609x over previous
//
#include <hip/hip_runtime.h>
#include <math.h>

#define D64 64
#define KTAB 2048   // lerp table intervals over r in [0,5]

// ---------------- helpers ----------------
__device__ __forceinline__ void atomAddF(float* p, float v) {
  __hip_atomic_fetch_add(p, v, __ATOMIC_RELAXED, __HIP_MEMORY_SCOPE_AGENT);
}
__device__ __forceinline__ unsigned fkey(float f) {
  unsigned u = __float_as_uint(f);
  return (u & 0x80000000u) ? ~u : (u | 0x80000000u);
}
__device__ __forceinline__ float funkey(unsigned k) {
  return __uint_as_float((k & 0x80000000u) ? (k & 0x7fffffffu) : ~k);
}
__device__ __forceinline__ float swishf(float x) { return x / (1.0f + expf(-x)); }

// feat[i,d] = emb[z[i],d]
__global__ void k_init(const int* __restrict__ z, const float* __restrict__ emb,
                       float* __restrict__ feat, int total) {
  int idx = blockIdx.x * 256 + threadIdx.x;
  if (idx < total) feat[idx] = emb[z[idx >> 6] * D64 + (idx & 63)];
}

__global__ void k_hist(const int* __restrict__ dst, int* __restrict__ deg, int E) {
  for (int i = blockIdx.x * blockDim.x + threadIdx.x; i < E; i += gridDim.x * blockDim.x)
    atomicAdd(&deg[dst[i]], 1);
}

// single-block exclusive scan over deg[0..n) -> rp[0..n], also copies into cur
__global__ void k_scan(const int* __restrict__ deg, int* __restrict__ rp,
                       int* __restrict__ cur, int n) {
  __shared__ int sb[1024];
  __shared__ int carry_s;
  const int tid = threadIdx.x;
  if (tid == 0) carry_s = 0;
  __syncthreads();
  for (int base = 0; base < n; base += 4096) {
    int i0 = base + tid * 4;
    int v[4];
#pragma unroll
    for (int q = 0; q < 4; ++q) { int i = i0 + q; v[q] = (i < n) ? deg[i] : 0; }
    int s = v[0] + v[1] + v[2] + v[3];
    sb[tid] = s;
    __syncthreads();
    for (int o = 1; o < 1024; o <<= 1) {
      int t = (tid >= o) ? sb[tid - o] : 0;
      __syncthreads();
      sb[tid] += t;
      __syncthreads();
    }
    int incl = sb[tid];
    int carry = carry_s;
    int excl = carry + incl - s;
#pragma unroll
    for (int q = 0; q < 4; ++q) {
      int i = i0 + q;
      if (i < n) { rp[i] = excl; cur[i] = excl; }
      excl += v[q];
    }
    __syncthreads();
    if (tid == 1023) carry_s = carry + incl;
    __syncthreads();
  }
  if (tid == 0) rp[n] = carry_s;
}

// bucket edges by dst: ep[pos] = {src, float_bits(r * KTAB/5)}
__global__ void k_scatter(const int* __restrict__ src, const int* __restrict__ dst,
                          const float* __restrict__ rij, int* __restrict__ cur,
                          int2* __restrict__ ep, int E, float ks) {
  for (int i = blockIdx.x * blockDim.x + threadIdx.x; i < E; i += gridDim.x * blockDim.x) {
    int nd = dst[i];
    int pos = atomicAdd(&cur[nd], 1);
    ep[pos] = make_int2(src[i], __float_as_int(rij[i] * ks));
  }
}

// Paired table: T2[l][g][d] = { W(r_g)[d]*C(r_g), W(r_{g+1})[d]*C(r_{g+1}) }
// built by computing the value at each grid point and writing .x of row g and
// .y of row g-1.
__global__ __launch_bounds__(256) void k_tables(const float* __restrict__ Wf1,
                                                const float* __restrict__ bf1,
                                                const float* __restrict__ Wf2,
                                                const float* __restrict__ bf2,
                                                float* __restrict__ T2) {
  __shared__ __align__(16) float rb[4][D64];
  const int lane = threadIdx.x & 63;
  const int wsl = threadIdx.x >> 6;
  const int wid = blockIdx.x * 4 + wsl;
  if (wid >= 3 * (KTAB + 1)) return;
  const int l = wid / (KTAB + 1);
  const int g = wid - l * (KTAB + 1);
  const float r = (float)g * (5.0f / KTAB);
  const float width = 5.0f / 24.0f;
  const float coeff = -0.5f / (width * width);
  float fv = 0.0f;
  if (lane < 25) { float dd = r - (float)lane * width; fv = expf(coeff * dd * dd); }
  rb[wsl][lane] = fv;
  float a1 = bf1[l * D64 + lane];
#pragma unroll
  for (int b = 0; b < 25; ++b)
    a1 = fmaf(rb[wsl][b], Wf1[(l * 25 + b) * D64 + lane], a1);
  float sw = swishf(a1);
  rb[wsl][lane] = sw;   // same-wave reuse; program order preserves DS deps
  float a2 = bf2[l * D64 + lane];
#pragma unroll
  for (int k = 0; k < D64; ++k)
    a2 = fmaf(rb[wsl][k], Wf2[l * D64 * D64 + k * D64 + lane], a2);
  float C = (r < 5.0f) ? 0.5f * (cosf(r * 0.62831853f) + 1.0f) : 0.0f;
  const float val = a2 * C;
  float* base = T2 + (size_t)l * KTAB * D64 * 2;
  if (g < KTAB) base[((size_t)g * D64 + lane) * 2] = val;
  if (g > 0)    base[((size_t)(g - 1) * D64 + lane) * 2 + 1] = val;
}

// x1 = feat @ Win  (wave per row; Win column in VGPRs; row broadcast via LDS)
__global__ __launch_bounds__(256) void k_x1(const float* __restrict__ feat,
                                            const float* __restrict__ Win,
                                            float* __restrict__ x1, int n) {
  __shared__ __align__(16) float rb[4][D64];
  const int lane = threadIdx.x & 63;
  const int wsl = threadIdx.x >> 6;
  float wcol[D64];
#pragma unroll
  for (int k = 0; k < D64; ++k) wcol[k] = Win[k * D64 + lane];
  const int wid = blockIdx.x * 4 + wsl;
  const int nw = gridDim.x * 4;
  for (int row = wid; row < n; row += nw) {
    rb[wsl][lane] = feat[(size_t)row * D64 + lane];
    float acc = 0.0f;
#pragma unroll
    for (int k4 = 0; k4 < 16; ++k4) {
      float4 f4 = *(const float4*)&rb[wsl][k4 * 4];
      acc = fmaf(f4.x, wcol[k4 * 4 + 0], acc);
      acc = fmaf(f4.y, wcol[k4 * 4 + 1], acc);
      acc = fmaf(f4.z, wcol[k4 * 4 + 2], acc);
      acc = fmaf(f4.w, wcol[k4 * 4 + 3], acc);
    }
    x1[(size_t)row * D64 + lane] = acc;
  }
}

// agg[nd] = sum over incoming edges of x1[src] * lerp(T2, r)
// 4-way unrolled: all loads for 4 edges are issued before any consumption,
// giving ~9 outstanding VMEM ops per wave instead of ~2.
__global__ __launch_bounds__(256) void k_gather(const float* __restrict__ x1,
                                                const float2* __restrict__ T2,
                                                const int2* __restrict__ ep,
                                                const int* __restrict__ rp,
                                                float* __restrict__ agg, int n) {
  const int lane = threadIdx.x & 63;
  const int wid = (blockIdx.x * blockDim.x + threadIdx.x) >> 6;
  const int nw = (gridDim.x * blockDim.x) >> 6;
  for (int nd = wid; nd < n; nd += nw) {
    const int j0 = rp[nd], j1 = rp[nd + 1];
    float acc = 0.0f;
    int j = j0;
    for (; j + 4 <= j1; j += 4) {
      const int2 e0 = ep[j + 0];
      const int2 e1 = ep[j + 1];
      const int2 e2 = ep[j + 2];
      const int2 e3 = ep[j + 3];
      const float p0 = __int_as_float(e0.y);
      const float p1 = __int_as_float(e1.y);
      const float p2 = __int_as_float(e2.y);
      const float p3 = __int_as_float(e3.y);
      int k0 = (int)p0; k0 = (k0 > KTAB - 1) ? (KTAB - 1) : k0;
      int k1 = (int)p1; k1 = (k1 > KTAB - 1) ? (KTAB - 1) : k1;
      int k2 = (int)p2; k2 = (k2 > KTAB - 1) ? (KTAB - 1) : k2;
      int k3 = (int)p3; k3 = (k3 > KTAB - 1) ? (KTAB - 1) : k3;
      const float2 w0 = T2[(size_t)k0 * D64 + lane];
      const float2 w1 = T2[(size_t)k1 * D64 + lane];
      const float2 w2 = T2[(size_t)k2 * D64 + lane];
      const float2 w3 = T2[(size_t)k3 * D64 + lane];
      const float x0 = x1[(size_t)e0.x * D64 + lane];
      const float xa = x1[(size_t)e1.x * D64 + lane];
      const float xb = x1[(size_t)e2.x * D64 + lane];
      const float xc = x1[(size_t)e3.x * D64 + lane];
      const float t0 = p0 - (float)k0;
      const float t1 = p1 - (float)k1;
      const float t2 = p2 - (float)k2;
      const float t3 = p3 - (float)k3;
      acc = fmaf(x0, fmaf(t0, w0.y - w0.x, w0.x), acc);
      acc = fmaf(xa, fmaf(t1, w1.y - w1.x, w1.x), acc);
      acc = fmaf(xb, fmaf(t2, w2.y - w2.x, w2.x), acc);
      acc = fmaf(xc, fmaf(t3, w3.y - w3.x, w3.x), acc);
    }
    for (; j < j1; ++j) {
      const int2 e = ep[j];
      const float p = __int_as_float(e.y);
      int k = (int)p;
      k = (k > KTAB - 1) ? (KTAB - 1) : k;
      const float t = p - (float)k;
      const float2 w = T2[(size_t)k * D64 + lane];
      acc = fmaf(x1[(size_t)e.x * D64 + lane], fmaf(t, w.y - w.x, w.x), acc);
    }
    agg[(size_t)nd * D64 + lane] = acc;
  }
}

// y = swish(agg@Wo1+bo1)@Wo2+bo2; feat += y; accumulate sum(f), sum(f^2)
__global__ __launch_bounds__(256) void k_out(const float* __restrict__ agg,
                                             const float* __restrict__ Wo1,
                                             const float* __restrict__ bo1,
                                             const float* __restrict__ Wo2,
                                             const float* __restrict__ bo2,
                                             float* __restrict__ feat,
                                             float* __restrict__ stats, int n) {
  __shared__ __align__(16) float rb[4][D64];
  const int lane = threadIdx.x & 63;
  const int wsl = threadIdx.x >> 6;
  float w1c[D64], w2c[D64];
#pragma unroll
  for (int k = 0; k < D64; ++k) w1c[k] = Wo1[k * D64 + lane];
#pragma unroll
  for (int k = 0; k < D64; ++k) w2c[k] = Wo2[k * D64 + lane];
  const float b1 = bo1[lane], b2 = bo2[lane];
  float sf = 0.0f, sf2 = 0.0f;
  const int wid = blockIdx.x * 4 + wsl;
  const int nw = gridDim.x * 4;
  for (int row = wid; row < n; row += nw) {
    rb[wsl][lane] = agg[(size_t)row * D64 + lane];
    float a1 = b1;
#pragma unroll
    for (int k4 = 0; k4 < 16; ++k4) {
      float4 f4 = *(const float4*)&rb[wsl][k4 * 4];
      a1 = fmaf(f4.x, w1c[k4 * 4 + 0], a1);
      a1 = fmaf(f4.y, w1c[k4 * 4 + 1], a1);
      a1 = fmaf(f4.z, w1c[k4 * 4 + 2], a1);
      a1 = fmaf(f4.w, w1c[k4 * 4 + 3], a1);
    }
    float sw = swishf(a1);
    rb[wsl][lane] = sw;   // reuse: program-order DS dependence keeps this safe in-wave
    float a2 = b2;
#pragma unroll
    for (int k4 = 0; k4 < 16; ++k4) {
      float4 f4 = *(const float4*)&rb[wsl][k4 * 4];
      a2 = fmaf(f4.x, w2c[k4 * 4 + 0], a2);
      a2 = fmaf(f4.y, w2c[k4 * 4 + 1], a2);
      a2 = fmaf(f4.z, w2c[k4 * 4 + 2], a2);
      a2 = fmaf(f4.w, w2c[k4 * 4 + 3], a2);
    }
    float fn = feat[(size_t)row * D64 + lane] + a2;
    feat[(size_t)row * D64 + lane] = fn;
    sf += fn;
    sf2 += fn * fn;
  }
  atomAddF(&stats[lane], sf);
  atomAddF(&stats[64 + lane], sf2);
}

// per-feature: scale/shift for GraphNorm. var = E[f^2] - (2a - a^2) mu^2
__global__ void k_nfin(float* __restrict__ stats, const float* __restrict__ al,
                       const float* __restrict__ ga, const float* __restrict__ be, int n) {
  int d = threadIdx.x;
  if (d >= D64) return;
  float invN = 1.0f / (float)n;
  float mu = stats[d] * invN;
  float ex2 = stats[64 + d] * invN;
  float a = al[d];
  float var = ex2 - (2.0f * a - a * a) * mu * mu;
  float sc = ga[d] * rsqrtf(var + 1e-5f);
  stats[128 + d] = sc;
  stats[192 + d] = be[d] - sc * a * mu;
}

__global__ void k_napp(float* __restrict__ feat, const float* __restrict__ stats, int total) {
  int idx = blockIdx.x * 256 + threadIdx.x;
  if (idx < total) {
    int d = idx & 63;
    feat[idx] = fmaf(feat[idx], stats[128 + d], stats[192 + d]);
  }
}

__global__ __launch_bounds__(256) void k_colmax(const float* __restrict__ feat,
                                                unsigned* __restrict__ um, int n) {
  const int lane = threadIdx.x & 63;
  const int wid = (blockIdx.x * blockDim.x + threadIdx.x) >> 6;
  const int nw = (gridDim.x * blockDim.x) >> 6;
  float m = -3.402823e38f;
  for (int r = wid; r < n; r += nw) m = fmaxf(m, feat[(size_t)r * D64 + lane]);
  atomicMax(&um[lane], fkey(m));
}

__global__ __launch_bounds__(256) void k_colsum(const float* __restrict__ feat,
                                                float* __restrict__ rd, int n) {
  const unsigned* um = (const unsigned*)rd;
  const int lane = threadIdx.x & 63;
  const int wid = (blockIdx.x * blockDim.x + threadIdx.x) >> 6;
  const int nw = (gridDim.x * blockDim.x) >> 6;
  const float mx = funkey(um[lane]);
  float s1 = 0.0f, s2 = 0.0f;
  for (int r = wid; r < n; r += nw) {
    float f = feat[(size_t)r * D64 + lane];
    float e = expf(f - mx);
    s1 += e;
    s2 += e * f;
  }
  atomAddF(&rd[64 + lane], s1);
  atomAddF(&rd[128 + lane], s2);
}

__global__ void k_pooled(const float* __restrict__ rd, float* __restrict__ out) {
  int d = threadIdx.x;
  if (d < D64) out[d] = rd[128 + d] / rd[64 + d];
}

extern "C" void kernel_launch(void* const* d_in, const int* in_sizes, int n_in,
                              void* d_out, int out_size, void* d_ws, size_t ws_size,
                              hipStream_t stream) {
  const int* z = (const int*)d_in[0];
  const int* src = (const int*)d_in[1];
  const int* dst = (const int*)d_in[2];
  const float* rij = (const float*)d_in[3];
  const float* emb = (const float*)d_in[4];
  const float* Win = (const float*)d_in[5];
  const float* Wf1 = (const float*)d_in[6];
  const float* bf1 = (const float*)d_in[7];
  const float* Wf2 = (const float*)d_in[8];
  const float* bf2 = (const float*)d_in[9];
  const float* Wo1 = (const float*)d_in[10];
  const float* bo1 = (const float*)d_in[11];
  const float* Wo2 = (const float*)d_in[12];
  const float* bo2 = (const float*)d_in[13];
  const float* gal = (const float*)d_in[14];
  const float* gga = (const float*)d_in[15];
  const float* gbe = (const float*)d_in[16];
  const int n = in_sizes[0];
  const int E = in_sizes[1];
  (void)n_in; (void)out_size; (void)ws_size;

  float* feat = (float*)d_out;                 // [n,64] lives in d_out
  float* pooled = feat + (size_t)n * D64;      // [64]

  char* w = (char*)d_ws;
  size_t off = 0;
  auto take = [&](size_t bytes) {
    size_t o = (off + 255) & ~(size_t)255;
    off = o + bytes;
    return (void*)(w + o);
  };
  float* x1 = (float*)take((size_t)n * D64 * 4);
  float* agg = (float*)take((size_t)n * D64 * 4);
  float* stats = (float*)take(256 * 4);
  float* rdst = (float*)take(192 * 4);
  float* T2 = (float*)take((size_t)3 * KTAB * D64 * 2 * 4);
  int* deg = (int*)take((size_t)n * 4);
  int* rp = (int*)take((size_t)(n + 1) * 4);
  int* cur = (int*)take((size_t)n * 4);
  int2* ep = (int2*)take((size_t)E * 8);

  hipMemsetAsync(deg, 0, (size_t)n * 4, stream);
  k_init<<<(n * D64 + 255) / 256, 256, 0, stream>>>(z, emb, feat, n * D64);
  k_hist<<<1024, 256, 0, stream>>>(dst, deg, E);
  k_scan<<<1, 1024, 0, stream>>>(deg, rp, cur, n);
  k_scatter<<<1024, 256, 0, stream>>>(src, dst, rij, cur, ep, E, (float)KTAB / 5.0f);
  k_tables<<<(3 * (KTAB + 1) + 3) / 4, 256, 0, stream>>>(Wf1, bf1, Wf2, bf2, T2);

  for (int l = 0; l < 3; ++l) {
    k_x1<<<512, 256, 0, stream>>>(feat, Win + (size_t)l * D64 * D64, x1, n);
    hipMemsetAsync(stats, 0, 256 * 4, stream);
    k_gather<<<2048, 256, 0, stream>>>(x1, (const float2*)(T2 + (size_t)l * KTAB * D64 * 2),
                                       ep, rp, agg, n);
    k_out<<<1024, 256, 0, stream>>>(agg, Wo1 + (size_t)l * D64 * D64, bo1 + l * D64,
                                    Wo2 + (size_t)l * D64 * D64, bo2 + l * D64, feat, stats, n);
    k_nfin<<<1, 64, 0, stream>>>(stats, gal + l * D64, gga + l * D64, gbe + l * D64, n);
    k_napp<<<(n * D64 + 255) / 256, 256, 0, stream>>>(feat, stats, n * D64);
  }

  hipMemsetAsync(rdst, 0, 192 * 4, stream);
  k_colmax<<<512, 256, 0, stream>>>(feat, (unsigned*)rdst, n);
  k_colsum<<<512, 256, 0, stream>>>(feat, rdst, n);
  k_pooled<<<1, 64, 0, stream>>>(rdst, pooled);
}

// Round 3
// 1079.043 us; speedup vs baseline: 1.1621x; 1.0011x over previous
//
#include <hip/hip_runtime.h>
#include <math.h>

#define D64 64
#define KTAB 2048   // lerp table intervals over r in [0,5]

// ---------------- helpers ----------------
__device__ __forceinline__ void atomAddF(float* p, float v) {
  __hip_atomic_fetch_add(p, v, __ATOMIC_RELAXED, __HIP_MEMORY_SCOPE_AGENT);
}
__device__ __forceinline__ unsigned fkey(float f) {
  unsigned u = __float_as_uint(f);
  return (u & 0x80000000u) ? ~u : (u | 0x80000000u);
}
__device__ __forceinline__ float funkey(unsigned k) {
  return __uint_as_float((k & 0x80000000u) ? (k & 0x7fffffffu) : ~k);
}
__device__ __forceinline__ float swishf(float x) { return x / (1.0f + expf(-x)); }

// feat[i,d] = emb[z[i],d]
__global__ void k_init(const int* __restrict__ z, const float* __restrict__ emb,
                       float* __restrict__ feat, int total) {
  int idx = blockIdx.x * 256 + threadIdx.x;
  if (idx < total) feat[idx] = emb[z[idx >> 6] * D64 + (idx & 63)];
}

__global__ void k_hist(const int* __restrict__ dst, int* __restrict__ deg, int E) {
  for (int i = blockIdx.x * blockDim.x + threadIdx.x; i < E; i += gridDim.x * blockDim.x)
    atomicAdd(&deg[dst[i]], 1);
}

// single-block exclusive scan over deg[0..n) -> rp[0..n], also copies into cur
__global__ void k_scan(const int* __restrict__ deg, int* __restrict__ rp,
                       int* __restrict__ cur, int n) {
  __shared__ int sb[1024];
  __shared__ int carry_s;
  const int tid = threadIdx.x;
  if (tid == 0) carry_s = 0;
  __syncthreads();
  for (int base = 0; base < n; base += 4096) {
    int i0 = base + tid * 4;
    int v[4];
#pragma unroll
    for (int q = 0; q < 4; ++q) { int i = i0 + q; v[q] = (i < n) ? deg[i] : 0; }
    int s = v[0] + v[1] + v[2] + v[3];
    sb[tid] = s;
    __syncthreads();
    for (int o = 1; o < 1024; o <<= 1) {
      int t = (tid >= o) ? sb[tid - o] : 0;
      __syncthreads();
      sb[tid] += t;
      __syncthreads();
    }
    int incl = sb[tid];
    int carry = carry_s;
    int excl = carry + incl - s;
#pragma unroll
    for (int q = 0; q < 4; ++q) {
      int i = i0 + q;
      if (i < n) { rp[i] = excl; cur[i] = excl; }
      excl += v[q];
    }
    __syncthreads();
    if (tid == 1023) carry_s = carry + incl;
    __syncthreads();
  }
  if (tid == 0) rp[n] = carry_s;
}

// bucket edges by dst: ep[pos] = {src, float_bits(r * KTAB/5)}
__global__ void k_scatter(const int* __restrict__ src, const int* __restrict__ dst,
                          const float* __restrict__ rij, int* __restrict__ cur,
                          int2* __restrict__ ep, int E, float ks) {
  for (int i = blockIdx.x * blockDim.x + threadIdx.x; i < E; i += gridDim.x * blockDim.x) {
    int nd = dst[i];
    int pos = atomicAdd(&cur[nd], 1);
    ep[pos] = make_int2(src[i], __float_as_int(rij[i] * ks));
  }
}

// Paired table: T2[l][g][d] = { W(r_g)[d]*C(r_g), W(r_{g+1})[d]*C(r_{g+1}) }
__global__ __launch_bounds__(256) void k_tables(const float* __restrict__ Wf1,
                                                const float* __restrict__ bf1,
                                                const float* __restrict__ Wf2,
                                                const float* __restrict__ bf2,
                                                float* __restrict__ T2) {
  __shared__ __align__(16) float rb[4][D64];
  const int lane = threadIdx.x & 63;
  const int wsl = threadIdx.x >> 6;
  const int wid = blockIdx.x * 4 + wsl;
  if (wid >= 3 * (KTAB + 1)) return;
  const int l = wid / (KTAB + 1);
  const int g = wid - l * (KTAB + 1);
  const float r = (float)g * (5.0f / KTAB);
  const float width = 5.0f / 24.0f;
  const float coeff = -0.5f / (width * width);
  float fv = 0.0f;
  if (lane < 25) { float dd = r - (float)lane * width; fv = expf(coeff * dd * dd); }
  rb[wsl][lane] = fv;
  float a1 = bf1[l * D64 + lane];
#pragma unroll
  for (int b = 0; b < 25; ++b)
    a1 = fmaf(rb[wsl][b], Wf1[(l * 25 + b) * D64 + lane], a1);
  float sw = swishf(a1);
  rb[wsl][lane] = sw;   // same-wave reuse; program order preserves DS deps
  float a2 = bf2[l * D64 + lane];
#pragma unroll
  for (int k = 0; k < D64; ++k)
    a2 = fmaf(rb[wsl][k], Wf2[l * D64 * D64 + k * D64 + lane], a2);
  float C = (r < 5.0f) ? 0.5f * (cosf(r * 0.62831853f) + 1.0f) : 0.0f;
  const float val = a2 * C;
  float* base = T2 + (size_t)l * KTAB * D64 * 2;
  if (g < KTAB) base[((size_t)g * D64 + lane) * 2] = val;
  if (g > 0)    base[((size_t)(g - 1) * D64 + lane) * 2 + 1] = val;
}

// x1 = feat @ Win.  Wave per row; Win column resident in VGPRs (launch_bounds
// (256,1) lifts the VGPR cap so the 64-float array is NOT spilled); 4 partial
// accumulators cut the FMA dependency chain to 16.
__global__ __launch_bounds__(256, 1) void k_x1(const float* __restrict__ feat,
                                               const float* __restrict__ Win,
                                               float* __restrict__ x1, int n) {
  __shared__ __align__(16) float rb[4][D64];
  const int lane = threadIdx.x & 63;
  const int wsl = threadIdx.x >> 6;
  float wcol[D64];
#pragma unroll
  for (int k = 0; k < D64; ++k) wcol[k] = Win[k * D64 + lane];
  const int wid = blockIdx.x * 4 + wsl;
  const int nw = gridDim.x * 4;
  for (int row = wid; row < n; row += nw) {
    rb[wsl][lane] = feat[(size_t)row * D64 + lane];
    float a0 = 0.0f, a1 = 0.0f, a2 = 0.0f, a3 = 0.0f;
#pragma unroll
    for (int k4 = 0; k4 < 16; ++k4) {
      float4 f4 = *(const float4*)&rb[wsl][k4 * 4];
      a0 = fmaf(f4.x, wcol[k4 * 4 + 0], a0);
      a1 = fmaf(f4.y, wcol[k4 * 4 + 1], a1);
      a2 = fmaf(f4.z, wcol[k4 * 4 + 2], a2);
      a3 = fmaf(f4.w, wcol[k4 * 4 + 3], a3);
    }
    x1[(size_t)row * D64 + lane] = (a0 + a1) + (a2 + a3);
  }
}

// agg[nd] = sum over incoming edges of x1[src] * lerp(T2, r); 4-way unrolled
__global__ __launch_bounds__(256) void k_gather(const float* __restrict__ x1,
                                                const float2* __restrict__ T2,
                                                const int2* __restrict__ ep,
                                                const int* __restrict__ rp,
                                                float* __restrict__ agg, int n) {
  const int lane = threadIdx.x & 63;
  const int wid = (blockIdx.x * blockDim.x + threadIdx.x) >> 6;
  const int nw = (gridDim.x * blockDim.x) >> 6;
  for (int nd = wid; nd < n; nd += nw) {
    const int j0 = rp[nd], j1 = rp[nd + 1];
    float acc = 0.0f;
    int j = j0;
    for (; j + 4 <= j1; j += 4) {
      const int2 e0 = ep[j + 0];
      const int2 e1 = ep[j + 1];
      const int2 e2 = ep[j + 2];
      const int2 e3 = ep[j + 3];
      const float p0 = __int_as_float(e0.y);
      const float p1 = __int_as_float(e1.y);
      const float p2 = __int_as_float(e2.y);
      const float p3 = __int_as_float(e3.y);
      int k0 = (int)p0; k0 = (k0 > KTAB - 1) ? (KTAB - 1) : k0;
      int k1 = (int)p1; k1 = (k1 > KTAB - 1) ? (KTAB - 1) : k1;
      int k2 = (int)p2; k2 = (k2 > KTAB - 1) ? (KTAB - 1) : k2;
      int k3 = (int)p3; k3 = (k3 > KTAB - 1) ? (KTAB - 1) : k3;
      const float2 w0 = T2[(size_t)k0 * D64 + lane];
      const float2 w1 = T2[(size_t)k1 * D64 + lane];
      const float2 w2 = T2[(size_t)k2 * D64 + lane];
      const float2 w3 = T2[(size_t)k3 * D64 + lane];
      const float x0 = x1[(size_t)e0.x * D64 + lane];
      const float xa = x1[(size_t)e1.x * D64 + lane];
      const float xb = x1[(size_t)e2.x * D64 + lane];
      const float xc = x1[(size_t)e3.x * D64 + lane];
      const float t0 = p0 - (float)k0;
      const float t1 = p1 - (float)k1;
      const float t2 = p2 - (float)k2;
      const float t3 = p3 - (float)k3;
      acc = fmaf(x0, fmaf(t0, w0.y - w0.x, w0.x), acc);
      acc = fmaf(xa, fmaf(t1, w1.y - w1.x, w1.x), acc);
      acc = fmaf(xb, fmaf(t2, w2.y - w2.x, w2.x), acc);
      acc = fmaf(xc, fmaf(t3, w3.y - w3.x, w3.x), acc);
    }
    for (; j < j1; ++j) {
      const int2 e = ep[j];
      const float p = __int_as_float(e.y);
      int k = (int)p;
      k = (k > KTAB - 1) ? (KTAB - 1) : k;
      const float t = p - (float)k;
      const float2 w = T2[(size_t)k * D64 + lane];
      acc = fmaf(x1[(size_t)e.x * D64 + lane], fmaf(t, w.y - w.x, w.x), acc);
    }
    agg[(size_t)nd * D64 + lane] = acc;
  }
}

// y = swish(agg@Wo1+bo1)@Wo2+bo2; feat += y; accumulate sum(f), sum(f^2).
// launch_bounds(256,1): both 64-float weight-column arrays live in VGPRs
// (~160 total) instead of being spilled at the default occupancy target.
__global__ __launch_bounds__(256, 1) void k_out(const float* __restrict__ agg,
                                                const float* __restrict__ Wo1,
                                                const float* __restrict__ bo1,
                                                const float* __restrict__ Wo2,
                                                const float* __restrict__ bo2,
                                                float* __restrict__ feat,
                                                float* __restrict__ stats, int n) {
  __shared__ __align__(16) float rb[4][D64];
  const int lane = threadIdx.x & 63;
  const int wsl = threadIdx.x >> 6;
  float w1c[D64], w2c[D64];
#pragma unroll
  for (int k = 0; k < D64; ++k) w1c[k] = Wo1[k * D64 + lane];
#pragma unroll
  for (int k = 0; k < D64; ++k) w2c[k] = Wo2[k * D64 + lane];
  const float b1 = bo1[lane], b2 = bo2[lane];
  float sf = 0.0f, sf2 = 0.0f;
  const int wid = blockIdx.x * 4 + wsl;
  const int nw = gridDim.x * 4;
  for (int row = wid; row < n; row += nw) {
    rb[wsl][lane] = agg[(size_t)row * D64 + lane];
    float p0 = b1, p1 = 0.0f, p2 = 0.0f, p3 = 0.0f;
#pragma unroll
    for (int k4 = 0; k4 < 16; ++k4) {
      float4 f4 = *(const float4*)&rb[wsl][k4 * 4];
      p0 = fmaf(f4.x, w1c[k4 * 4 + 0], p0);
      p1 = fmaf(f4.y, w1c[k4 * 4 + 1], p1);
      p2 = fmaf(f4.z, w1c[k4 * 4 + 2], p2);
      p3 = fmaf(f4.w, w1c[k4 * 4 + 3], p3);
    }
    float sw = swishf((p0 + p1) + (p2 + p3));
    rb[wsl][lane] = sw;   // reuse: program-order DS dependence keeps this safe in-wave
    float q0 = b2, q1 = 0.0f, q2 = 0.0f, q3 = 0.0f;
#pragma unroll
    for (int k4 = 0; k4 < 16; ++k4) {
      float4 f4 = *(const float4*)&rb[wsl][k4 * 4];
      q0 = fmaf(f4.x, w2c[k4 * 4 + 0], q0);
      q1 = fmaf(f4.y, w2c[k4 * 4 + 1], q1);
      q2 = fmaf(f4.z, w2c[k4 * 4 + 2], q2);
      q3 = fmaf(f4.w, w2c[k4 * 4 + 3], q3);
    }
    float fn = feat[(size_t)row * D64 + lane] + ((q0 + q1) + (q2 + q3));
    feat[(size_t)row * D64 + lane] = fn;
    sf += fn;
    sf2 += fn * fn;
  }
  atomAddF(&stats[lane], sf);
  atomAddF(&stats[64 + lane], sf2);
}

// per-feature: scale/shift for GraphNorm. var = E[f^2] - (2a - a^2) mu^2
__global__ void k_nfin(float* __restrict__ stats, const float* __restrict__ al,
                       const float* __restrict__ ga, const float* __restrict__ be, int n) {
  int d = threadIdx.x;
  if (d >= D64) return;
  float invN = 1.0f / (float)n;
  float mu = stats[d] * invN;
  float ex2 = stats[64 + d] * invN;
  float a = al[d];
  float var = ex2 - (2.0f * a - a * a) * mu * mu;
  float sc = ga[d] * rsqrtf(var + 1e-5f);
  stats[128 + d] = sc;
  stats[192 + d] = be[d] - sc * a * mu;
}

__global__ void k_napp(float* __restrict__ feat, const float* __restrict__ stats, int total) {
  int idx = blockIdx.x * 256 + threadIdx.x;
  if (idx < total) {
    int d = idx & 63;
    feat[idx] = fmaf(feat[idx], stats[128 + d], stats[192 + d]);
  }
}

__global__ __launch_bounds__(256) void k_colmax(const float* __restrict__ feat,
                                                unsigned* __restrict__ um, int n) {
  const int lane = threadIdx.x & 63;
  const int wid = (blockIdx.x * blockDim.x + threadIdx.x) >> 6;
  const int nw = (gridDim.x * blockDim.x) >> 6;
  float m = -3.402823e38f;
  for (int r = wid; r < n; r += nw) m = fmaxf(m, feat[(size_t)r * D64 + lane]);
  atomicMax(&um[lane], fkey(m));
}

__global__ __launch_bounds__(256) void k_colsum(const float* __restrict__ feat,
                                                float* __restrict__ rd, int n) {
  const unsigned* um = (const unsigned*)rd;
  const int lane = threadIdx.x & 63;
  const int wid = (blockIdx.x * blockDim.x + threadIdx.x) >> 6;
  const int nw = (gridDim.x * blockDim.x) >> 6;
  const float mx = funkey(um[lane]);
  float s1 = 0.0f, s2 = 0.0f;
  for (int r = wid; r < n; r += nw) {
    float f = feat[(size_t)r * D64 + lane];
    float e = expf(f - mx);
    s1 += e;
    s2 += e * f;
  }
  atomAddF(&rd[64 + lane], s1);
  atomAddF(&rd[128 + lane], s2);
}

__global__ void k_pooled(const float* __restrict__ rd, float* __restrict__ out) {
  int d = threadIdx.x;
  if (d < D64) out[d] = rd[128 + d] / rd[64 + d];
}

extern "C" void kernel_launch(void* const* d_in, const int* in_sizes, int n_in,
                              void* d_out, int out_size, void* d_ws, size_t ws_size,
                              hipStream_t stream) {
  const int* z = (const int*)d_in[0];
  const int* src = (const int*)d_in[1];
  const int* dst = (const int*)d_in[2];
  const float* rij = (const float*)d_in[3];
  const float* emb = (const float*)d_in[4];
  const float* Win = (const float*)d_in[5];
  const float* Wf1 = (const float*)d_in[6];
  const float* bf1 = (const float*)d_in[7];
  const float* Wf2 = (const float*)d_in[8];
  const float* bf2 = (const float*)d_in[9];
  const float* Wo1 = (const float*)d_in[10];
  const float* bo1 = (const float*)d_in[11];
  const float* Wo2 = (const float*)d_in[12];
  const float* bo2 = (const float*)d_in[13];
  const float* gal = (const float*)d_in[14];
  const float* gga = (const float*)d_in[15];
  const float* gbe = (const float*)d_in[16];
  const int n = in_sizes[0];
  const int E = in_sizes[1];
  (void)n_in; (void)out_size; (void)ws_size;

  float* feat = (float*)d_out;                 // [n,64] lives in d_out
  float* pooled = feat + (size_t)n * D64;      // [64]

  char* w = (char*)d_ws;
  size_t off = 0;
  auto take = [&](size_t bytes) {
    size_t o = (off + 255) & ~(size_t)255;
    off = o + bytes;
    return (void*)(w + o);
  };
  float* x1 = (float*)take((size_t)n * D64 * 4);
  float* agg = (float*)take((size_t)n * D64 * 4);
  float* stats = (float*)take(256 * 4);
  float* rdst = (float*)take(192 * 4);
  float* T2 = (float*)take((size_t)3 * KTAB * D64 * 2 * 4);
  int* deg = (int*)take((size_t)n * 4);
  int* rp = (int*)take((size_t)(n + 1) * 4);
  int* cur = (int*)take((size_t)n * 4);
  int2* ep = (int2*)take((size_t)E * 8);

  hipMemsetAsync(deg, 0, (size_t)n * 4, stream);
  k_init<<<(n * D64 + 255) / 256, 256, 0, stream>>>(z, emb, feat, n * D64);
  k_hist<<<1024, 256, 0, stream>>>(dst, deg, E);
  k_scan<<<1, 1024, 0, stream>>>(deg, rp, cur, n);
  k_scatter<<<1024, 256, 0, stream>>>(src, dst, rij, cur, ep, E, (float)KTAB / 5.0f);
  k_tables<<<(3 * (KTAB + 1) + 3) / 4, 256, 0, stream>>>(Wf1, bf1, Wf2, bf2, T2);

  for (int l = 0; l < 3; ++l) {
    k_x1<<<1024, 256, 0, stream>>>(feat, Win + (size_t)l * D64 * D64, x1, n);
    hipMemsetAsync(stats, 0, 256 * 4, stream);
    k_gather<<<2048, 256, 0, stream>>>(x1, (const float2*)(T2 + (size_t)l * KTAB * D64 * 2),
                                       ep, rp, agg, n);
    k_out<<<1024, 256, 0, stream>>>(agg, Wo1 + (size_t)l * D64 * D64, bo1 + l * D64,
                                    Wo2 + (size_t)l * D64 * D64, bo2 + l * D64, feat, stats, n);
    k_nfin<<<1, 64, 0, stream>>>(stats, gal + l * D64, gga + l * D64, gbe + l * D64, n);
    k_napp<<<(n * D64 + 255) / 256, 256, 0, stream>>>(feat, stats, n * D64);
  }

  hipMemsetAsync(rdst, 0, 192 * 4, stream);
  k_colmax<<<512, 256, 0, stream>>>(feat, (unsigned*)rdst, n);
  k_colsum<<<512, 256, 0, stream>>>(feat, rdst, n);
  k_pooled<<<1, 64, 0, stream>>>(rdst, pooled);
}

// Round 4
// 1046.082 us; speedup vs baseline: 1.1988x; 1.0315x over previous
//
#include <hip/hip_runtime.h>
#include <hip/hip_bf16.h>
#include <math.h>

#define D64 64
#define KTAB 2048   // lerp table intervals over r in [0,5]

// ---------------- helpers ----------------
__device__ __forceinline__ void atomAddF(float* p, float v) {
  __hip_atomic_fetch_add(p, v, __ATOMIC_RELAXED, __HIP_MEMORY_SCOPE_AGENT);
}
__device__ __forceinline__ unsigned fkey(float f) {
  unsigned u = __float_as_uint(f);
  return (u & 0x80000000u) ? ~u : (u | 0x80000000u);
}
__device__ __forceinline__ float funkey(unsigned k) {
  return __uint_as_float((k & 0x80000000u) ? (k & 0x7fffffffu) : ~k);
}
__device__ __forceinline__ float swishf(float x) { return x / (1.0f + expf(-x)); }

// feat[i,d] = emb[z[i],d]
__global__ void k_init(const int* __restrict__ z, const float* __restrict__ emb,
                       float* __restrict__ feat, int total) {
  int idx = blockIdx.x * 256 + threadIdx.x;
  if (idx < total) feat[idx] = emb[z[idx >> 6] * D64 + (idx & 63)];
}

__global__ void k_hist(const int* __restrict__ dst, int* __restrict__ deg, int E) {
  for (int i = blockIdx.x * blockDim.x + threadIdx.x; i < E; i += gridDim.x * blockDim.x)
    atomicAdd(&deg[dst[i]], 1);
}

// single-block exclusive scan over deg[0..n) -> rp[0..n], also copies into cur
__global__ void k_scan(const int* __restrict__ deg, int* __restrict__ rp,
                       int* __restrict__ cur, int n) {
  __shared__ int sb[1024];
  __shared__ int carry_s;
  const int tid = threadIdx.x;
  if (tid == 0) carry_s = 0;
  __syncthreads();
  for (int base = 0; base < n; base += 4096) {
    int i0 = base + tid * 4;
    int v[4];
#pragma unroll
    for (int q = 0; q < 4; ++q) { int i = i0 + q; v[q] = (i < n) ? deg[i] : 0; }
    int s = v[0] + v[1] + v[2] + v[3];
    sb[tid] = s;
    __syncthreads();
    for (int o = 1; o < 1024; o <<= 1) {
      int t = (tid >= o) ? sb[tid - o] : 0;
      __syncthreads();
      sb[tid] += t;
      __syncthreads();
    }
    int incl = sb[tid];
    int carry = carry_s;
    int excl = carry + incl - s;
#pragma unroll
    for (int q = 0; q < 4; ++q) {
      int i = i0 + q;
      if (i < n) { rp[i] = excl; cur[i] = excl; }
      excl += v[q];
    }
    __syncthreads();
    if (tid == 1023) carry_s = carry + incl;
    __syncthreads();
  }
  if (tid == 0) rp[n] = carry_s;
}

// Slice-partitioned bucket-by-dst. slice = blockIdx&7 matches the round-robin
// block->XCD dispatch, so each XCD's L2 write-set is ~0.8MB (fits 4MB L2) and
// partial-line thrash (101MB writeback for a 6.4MB buffer) disappears.
// ep entry: src<<16 | fixed-point(r * KTAB*32/5) (k:11b, frac:5b).
__global__ void k_scatter(const int* __restrict__ src, const int* __restrict__ dst,
                          const float* __restrict__ rij, int* __restrict__ cur,
                          unsigned* __restrict__ ep, int E, int n) {
  const int slice = blockIdx.x & 7;
  const int lo = (int)(((long long)n * slice) >> 3);
  const int hi = (int)(((long long)n * (slice + 1)) >> 3);
  const int sub = blockIdx.x >> 3;
  const int nsub = gridDim.x >> 3;
  for (int i = sub * blockDim.x + threadIdx.x; i < E; i += nsub * blockDim.x) {
    int nd = dst[i];
    if (nd >= lo && nd < hi) {
      float p = rij[i] * (float)(KTAB * 32) * 0.2f;  // r * KTAB*32/5
      int pf = (int)p;
      if (pf > 65535) pf = 65535;
      int pos = atomicAdd(&cur[nd], 1);
      ep[pos] = ((unsigned)src[i] << 16) | (unsigned)pf;
    }
  }
}

// Paired table: T2[l][g][d] = { W(r_g)[d]*C(r_g), W(r_{g+1})[d]*C(r_{g+1}) }
__global__ __launch_bounds__(256) void k_tables(const float* __restrict__ Wf1,
                                                const float* __restrict__ bf1,
                                                const float* __restrict__ Wf2,
                                                const float* __restrict__ bf2,
                                                float* __restrict__ T2) {
  __shared__ __align__(16) float rb[4][D64];
  const int lane = threadIdx.x & 63;
  const int wsl = threadIdx.x >> 6;
  const int wid = blockIdx.x * 4 + wsl;
  if (wid >= 3 * (KTAB + 1)) return;
  const int l = wid / (KTAB + 1);
  const int g = wid - l * (KTAB + 1);
  const float r = (float)g * (5.0f / KTAB);
  const float width = 5.0f / 24.0f;
  const float coeff = -0.5f / (width * width);
  float fv = 0.0f;
  if (lane < 25) { float dd = r - (float)lane * width; fv = expf(coeff * dd * dd); }
  rb[wsl][lane] = fv;
  float a1 = bf1[l * D64 + lane];
#pragma unroll
  for (int b = 0; b < 25; ++b)
    a1 = fmaf(rb[wsl][b], Wf1[(l * 25 + b) * D64 + lane], a1);
  float sw = swishf(a1);
  rb[wsl][lane] = sw;   // same-wave reuse; program order preserves DS deps
  float a2 = bf2[l * D64 + lane];
#pragma unroll
  for (int k = 0; k < D64; ++k)
    a2 = fmaf(rb[wsl][k], Wf2[l * D64 * D64 + k * D64 + lane], a2);
  float C = (r < 5.0f) ? 0.5f * (cosf(r * 0.62831853f) + 1.0f) : 0.0f;
  const float val = a2 * C;
  float* base = T2 + (size_t)l * KTAB * D64 * 2;
  if (g < KTAB) base[((size_t)g * D64 + lane) * 2] = val;
  if (g > 0)    base[((size_t)(g - 1) * D64 + lane) * 2 + 1] = val;
}

// x1 = bf16(feat @ Win).  Weights transposed in LDS, rows padded to 65 floats:
// lane reads wlds[lane*65+k] -> bank (lane+k)%32 -> 2 lanes/bank = conflict-free.
// No per-lane weight arrays -> no spill (the R2/R3 k_out failure mode).
__global__ __launch_bounds__(256) void k_x1(const float* __restrict__ feat,
                                            const float* __restrict__ Win,
                                            __hip_bfloat16* __restrict__ x1, int n) {
  __shared__ float wlds[D64 * 65];
  __shared__ __align__(16) float rb[4][D64];
  const int lane = threadIdx.x & 63;
  const int wsl = threadIdx.x >> 6;
  for (int i = threadIdx.x; i < D64 * D64; i += 256) {
    int kk = i >> 6, d = i & 63;               // coalesced read, conflict-free write
    wlds[d * 65 + kk] = Win[i];
  }
  __syncthreads();
  const float* wl = &wlds[lane * 65];
  const int wid = blockIdx.x * 4 + wsl;
  const int nw = gridDim.x * 4;
  for (int row = wid; row < n; row += nw) {
    rb[wsl][lane] = feat[(size_t)row * D64 + lane];
    float a0 = 0.0f, a1 = 0.0f, a2 = 0.0f, a3 = 0.0f;
#pragma unroll
    for (int k4 = 0; k4 < 16; ++k4) {
      float4 f4 = *(const float4*)&rb[wsl][k4 * 4];
      a0 = fmaf(f4.x, wl[k4 * 4 + 0], a0);
      a1 = fmaf(f4.y, wl[k4 * 4 + 1], a1);
      a2 = fmaf(f4.z, wl[k4 * 4 + 2], a2);
      a3 = fmaf(f4.w, wl[k4 * 4 + 3], a3);
    }
    x1[(size_t)row * D64 + lane] = __float2bfloat16((a0 + a1) + (a2 + a3));
  }
}

// agg[nd] = sum over incoming edges of x1[src] * lerp(T2, r); 4-way unrolled.
// x1 is bf16 (halves the random-gather bytes), ep is 4B packed.
__global__ __launch_bounds__(256) void k_gather(const __hip_bfloat16* __restrict__ x1,
                                                const float2* __restrict__ T2,
                                                const unsigned* __restrict__ ep,
                                                const int* __restrict__ rp,
                                                float* __restrict__ agg, int n) {
  const int lane = threadIdx.x & 63;
  const int wid = (blockIdx.x * blockDim.x + threadIdx.x) >> 6;
  const int nw = (gridDim.x * blockDim.x) >> 6;
  for (int nd = wid; nd < n; nd += nw) {
    const int j0 = rp[nd], j1 = rp[nd + 1];
    float acc = 0.0f;
    int j = j0;
    for (; j + 4 <= j1; j += 4) {
      const unsigned u0 = ep[j + 0];
      const unsigned u1 = ep[j + 1];
      const unsigned u2 = ep[j + 2];
      const unsigned u3 = ep[j + 3];
      const float2 w0 = T2[(size_t)((u0 & 0xffffu) >> 5) * D64 + lane];
      const float2 w1 = T2[(size_t)((u1 & 0xffffu) >> 5) * D64 + lane];
      const float2 w2 = T2[(size_t)((u2 & 0xffffu) >> 5) * D64 + lane];
      const float2 w3 = T2[(size_t)((u3 & 0xffffu) >> 5) * D64 + lane];
      const float x0 = __bfloat162float(x1[(size_t)(u0 >> 16) * D64 + lane]);
      const float xa = __bfloat162float(x1[(size_t)(u1 >> 16) * D64 + lane]);
      const float xb = __bfloat162float(x1[(size_t)(u2 >> 16) * D64 + lane]);
      const float xc = __bfloat162float(x1[(size_t)(u3 >> 16) * D64 + lane]);
      const float t0 = (float)(u0 & 31u) * 0.03125f;
      const float t1 = (float)(u1 & 31u) * 0.03125f;
      const float t2 = (float)(u2 & 31u) * 0.03125f;
      const float t3 = (float)(u3 & 31u) * 0.03125f;
      acc = fmaf(x0, fmaf(t0, w0.y - w0.x, w0.x), acc);
      acc = fmaf(xa, fmaf(t1, w1.y - w1.x, w1.x), acc);
      acc = fmaf(xb, fmaf(t2, w2.y - w2.x, w2.x), acc);
      acc = fmaf(xc, fmaf(t3, w3.y - w3.x, w3.x), acc);
    }
    for (; j < j1; ++j) {
      const unsigned u = ep[j];
      const float2 w = T2[(size_t)((u & 0xffffu) >> 5) * D64 + lane];
      const float t = (float)(u & 31u) * 0.03125f;
      const float x = __bfloat162float(x1[(size_t)(u >> 16) * D64 + lane]);
      acc = fmaf(x, fmaf(t, w.y - w.x, w.x), acc);
    }
    agg[(size_t)nd * D64 + lane] = acc;
  }
}

// y = swish(agg@Wo1+bo1)@Wo2+bo2; feat += y; accumulate sum(f), sum(f^2).
// Both weight matrices transposed in LDS (65-float pitch, conflict-free).
__global__ __launch_bounds__(256) void k_out(const float* __restrict__ agg,
                                             const float* __restrict__ Wo1,
                                             const float* __restrict__ bo1,
                                             const float* __restrict__ Wo2,
                                             const float* __restrict__ bo2,
                                             float* __restrict__ feat,
                                             float* __restrict__ stats, int n) {
  __shared__ float w1t[D64 * 65];
  __shared__ float w2t[D64 * 65];
  __shared__ __align__(16) float rb[4][D64];
  const int lane = threadIdx.x & 63;
  const int wsl = threadIdx.x >> 6;
  for (int i = threadIdx.x; i < D64 * D64; i += 256) {
    int kk = i >> 6, d = i & 63;
    w1t[d * 65 + kk] = Wo1[i];
    w2t[d * 65 + kk] = Wo2[i];
  }
  __syncthreads();
  const float* wl1 = &w1t[lane * 65];
  const float* wl2 = &w2t[lane * 65];
  const float b1 = bo1[lane], b2 = bo2[lane];
  float sf = 0.0f, sf2 = 0.0f;
  const int wid = blockIdx.x * 4 + wsl;
  const int nw = gridDim.x * 4;
  for (int row = wid; row < n; row += nw) {
    rb[wsl][lane] = agg[(size_t)row * D64 + lane];
    float p0 = b1, p1 = 0.0f, p2 = 0.0f, p3 = 0.0f;
#pragma unroll
    for (int k4 = 0; k4 < 16; ++k4) {
      float4 f4 = *(const float4*)&rb[wsl][k4 * 4];
      p0 = fmaf(f4.x, wl1[k4 * 4 + 0], p0);
      p1 = fmaf(f4.y, wl1[k4 * 4 + 1], p1);
      p2 = fmaf(f4.z, wl1[k4 * 4 + 2], p2);
      p3 = fmaf(f4.w, wl1[k4 * 4 + 3], p3);
    }
    float sw = swishf((p0 + p1) + (p2 + p3));
    rb[wsl][lane] = sw;   // same-wave reuse; program order preserves DS deps
    float q0 = b2, q1 = 0.0f, q2 = 0.0f, q3 = 0.0f;
#pragma unroll
    for (int k4 = 0; k4 < 16; ++k4) {
      float4 f4 = *(const float4*)&rb[wsl][k4 * 4];
      q0 = fmaf(f4.x, wl2[k4 * 4 + 0], q0);
      q1 = fmaf(f4.y, wl2[k4 * 4 + 1], q1);
      q2 = fmaf(f4.z, wl2[k4 * 4 + 2], q2);
      q3 = fmaf(f4.w, wl2[k4 * 4 + 3], q3);
    }
    float fn = feat[(size_t)row * D64 + lane] + ((q0 + q1) + (q2 + q3));
    feat[(size_t)row * D64 + lane] = fn;
    sf += fn;
    sf2 += fn * fn;
  }
  atomAddF(&stats[lane], sf);
  atomAddF(&stats[64 + lane], sf2);
}

// per-feature: scale/shift for GraphNorm. var = E[f^2] - (2a - a^2) mu^2
__global__ void k_nfin(float* __restrict__ stats, const float* __restrict__ al,
                       const float* __restrict__ ga, const float* __restrict__ be, int n) {
  int d = threadIdx.x;
  if (d >= D64) return;
  float invN = 1.0f / (float)n;
  float mu = stats[d] * invN;
  float ex2 = stats[64 + d] * invN;
  float a = al[d];
  float var = ex2 - (2.0f * a - a * a) * mu * mu;
  float sc = ga[d] * rsqrtf(var + 1e-5f);
  stats[128 + d] = sc;
  stats[192 + d] = be[d] - sc * a * mu;
}

__global__ void k_napp(float* __restrict__ feat, const float* __restrict__ stats, int total) {
  int idx = blockIdx.x * 256 + threadIdx.x;
  if (idx < total) {
    int d = idx & 63;
    feat[idx] = fmaf(feat[idx], stats[128 + d], stats[192 + d]);
  }
}

__global__ __launch_bounds__(256) void k_colmax(const float* __restrict__ feat,
                                                unsigned* __restrict__ um, int n) {
  const int lane = threadIdx.x & 63;
  const int wid = (blockIdx.x * blockDim.x + threadIdx.x) >> 6;
  const int nw = (gridDim.x * blockDim.x) >> 6;
  float m = -3.402823e38f;
  for (int r = wid; r < n; r += nw) m = fmaxf(m, feat[(size_t)r * D64 + lane]);
  atomicMax(&um[lane], fkey(m));
}

__global__ __launch_bounds__(256) void k_colsum(const float* __restrict__ feat,
                                                float* __restrict__ rd, int n) {
  const unsigned* um = (const unsigned*)rd;
  const int lane = threadIdx.x & 63;
  const int wid = (blockIdx.x * blockDim.x + threadIdx.x) >> 6;
  const int nw = (gridDim.x * blockDim.x) >> 6;
  const float mx = funkey(um[lane]);
  float s1 = 0.0f, s2 = 0.0f;
  for (int r = wid; r < n; r += nw) {
    float f = feat[(size_t)r * D64 + lane];
    float e = expf(f - mx);
    s1 += e;
    s2 += e * f;
  }
  atomAddF(&rd[64 + lane], s1);
  atomAddF(&rd[128 + lane], s2);
}

__global__ void k_pooled(const float* __restrict__ rd, float* __restrict__ out) {
  int d = threadIdx.x;
  if (d < D64) out[d] = rd[128 + d] / rd[64 + d];
}

extern "C" void kernel_launch(void* const* d_in, const int* in_sizes, int n_in,
                              void* d_out, int out_size, void* d_ws, size_t ws_size,
                              hipStream_t stream) {
  const int* z = (const int*)d_in[0];
  const int* src = (const int*)d_in[1];
  const int* dst = (const int*)d_in[2];
  const float* rij = (const float*)d_in[3];
  const float* emb = (const float*)d_in[4];
  const float* Win = (const float*)d_in[5];
  const float* Wf1 = (const float*)d_in[6];
  const float* bf1 = (const float*)d_in[7];
  const float* Wf2 = (const float*)d_in[8];
  const float* bf2 = (const float*)d_in[9];
  const float* Wo1 = (const float*)d_in[10];
  const float* bo1 = (const float*)d_in[11];
  const float* Wo2 = (const float*)d_in[12];
  const float* bo2 = (const float*)d_in[13];
  const float* gal = (const float*)d_in[14];
  const float* gga = (const float*)d_in[15];
  const float* gbe = (const float*)d_in[16];
  const int n = in_sizes[0];
  const int E = in_sizes[1];
  (void)n_in; (void)out_size; (void)ws_size;

  float* feat = (float*)d_out;                 // [n,64] lives in d_out
  float* pooled = feat + (size_t)n * D64;      // [64]

  char* w = (char*)d_ws;
  size_t off = 0;
  auto take = [&](size_t bytes) {
    size_t o = (off + 255) & ~(size_t)255;
    off = o + bytes;
    return (void*)(w + o);
  };
  __hip_bfloat16* x1 = (__hip_bfloat16*)take((size_t)n * D64 * 2);
  float* agg = (float*)take((size_t)n * D64 * 4);
  float* stats = (float*)take(256 * 4);
  float* rdst = (float*)take(192 * 4);
  float* T2 = (float*)take((size_t)3 * KTAB * D64 * 2 * 4);
  int* deg = (int*)take((size_t)n * 4);
  int* rp = (int*)take((size_t)(n + 1) * 4);
  int* cur = (int*)take((size_t)n * 4);
  unsigned* ep = (unsigned*)take((size_t)E * 4);

  hipMemsetAsync(deg, 0, (size_t)n * 4, stream);
  k_init<<<(n * D64 + 255) / 256, 256, 0, stream>>>(z, emb, feat, n * D64);
  k_hist<<<1024, 256, 0, stream>>>(dst, deg, E);
  k_scan<<<1, 1024, 0, stream>>>(deg, rp, cur, n);
  k_scatter<<<1024, 256, 0, stream>>>(src, dst, rij, cur, ep, E, n);
  k_tables<<<(3 * (KTAB + 1) + 3) / 4, 256, 0, stream>>>(Wf1, bf1, Wf2, bf2, T2);

  for (int l = 0; l < 3; ++l) {
    k_x1<<<1024, 256, 0, stream>>>(feat, Win + (size_t)l * D64 * D64, x1, n);
    hipMemsetAsync(stats, 0, 256 * 4, stream);
    k_gather<<<2048, 256, 0, stream>>>(x1, (const float2*)(T2 + (size_t)l * KTAB * D64 * 2),
                                       ep, rp, agg, n);
    k_out<<<1024, 256, 0, stream>>>(agg, Wo1 + (size_t)l * D64 * D64, bo1 + l * D64,
                                    Wo2 + (size_t)l * D64 * D64, bo2 + l * D64, feat, stats, n);
    k_nfin<<<1, 64, 0, stream>>>(stats, gal + l * D64, gga + l * D64, gbe + l * D64, n);
    k_napp<<<(n * D64 + 255) / 256, 256, 0, stream>>>(feat, stats, n * D64);
  }

  hipMemsetAsync(rdst, 0, 192 * 4, stream);
  k_colmax<<<512, 256, 0, stream>>>(feat, (unsigned*)rdst, n);
  k_colsum<<<512, 256, 0, stream>>>(feat, rdst, n);
  k_pooled<<<1, 64, 0, stream>>>(rdst, pooled);
}

// Round 5
// 908.723 us; speedup vs baseline: 1.3800x; 1.1512x over previous
//
#include <hip/hip_runtime.h>
#include <hip/hip_bf16.h>
#include <math.h>

#define D64 64
#define KTAB 2048   // lerp table intervals over r in [0,5]

// ---------------- helpers ----------------
__device__ __forceinline__ void atomAddF(float* p, float v) {
  __hip_atomic_fetch_add(p, v, __ATOMIC_RELAXED, __HIP_MEMORY_SCOPE_AGENT);
}
__device__ __forceinline__ unsigned fkey(float f) {
  unsigned u = __float_as_uint(f);
  return (u & 0x80000000u) ? ~u : (u | 0x80000000u);
}
__device__ __forceinline__ float funkey(unsigned k) {
  return __uint_as_float((k & 0x80000000u) ? (k & 0x7fffffffu) : ~k);
}
__device__ __forceinline__ float swishf(float x) { return x / (1.0f + expf(-x)); }

// feat[i,d] = emb[z[i],d]
__global__ void k_init(const int* __restrict__ z, const float* __restrict__ emb,
                       float* __restrict__ feat, int total) {
  int idx = blockIdx.x * 256 + threadIdx.x;
  if (idx < total) feat[idx] = emb[z[idx >> 6] * D64 + (idx & 63)];
}

__global__ void k_hist(const int* __restrict__ dst, int* __restrict__ deg, int E) {
  for (int i = blockIdx.x * blockDim.x + threadIdx.x; i < E; i += gridDim.x * blockDim.x)
    atomicAdd(&deg[dst[i]], 1);
}

// single-block exclusive scan over deg[0..n) -> rp[0..n], also copies into cur
__global__ void k_scan(const int* __restrict__ deg, int* __restrict__ rp,
                       int* __restrict__ cur, int n) {
  __shared__ int sb[1024];
  __shared__ int carry_s;
  const int tid = threadIdx.x;
  if (tid == 0) carry_s = 0;
  __syncthreads();
  for (int base = 0; base < n; base += 4096) {
    int i0 = base + tid * 4;
    int v[4];
#pragma unroll
    for (int q = 0; q < 4; ++q) { int i = i0 + q; v[q] = (i < n) ? deg[i] : 0; }
    int s = v[0] + v[1] + v[2] + v[3];
    sb[tid] = s;
    __syncthreads();
    for (int o = 1; o < 1024; o <<= 1) {
      int t = (tid >= o) ? sb[tid - o] : 0;
      __syncthreads();
      sb[tid] += t;
      __syncthreads();
    }
    int incl = sb[tid];
    int carry = carry_s;
    int excl = carry + incl - s;
#pragma unroll
    for (int q = 0; q < 4; ++q) {
      int i = i0 + q;
      if (i < n) { rp[i] = excl; cur[i] = excl; }
      excl += v[q];
    }
    __syncthreads();
    if (tid == 1023) carry_s = carry + incl;
    __syncthreads();
  }
  if (tid == 0) rp[n] = carry_s;
}

// Slice-partitioned bucket-by-dst (keeps each XCD's write set L2-resident).
// ep entry: src<<16 | fixed-point(r * KTAB*32/5) (k:11b, frac:5b).
__global__ void k_scatter(const int* __restrict__ src, const int* __restrict__ dst,
                          const float* __restrict__ rij, int* __restrict__ cur,
                          unsigned* __restrict__ ep, int E, int n) {
  const int slice = blockIdx.x & 7;
  const int lo = (int)(((long long)n * slice) >> 3);
  const int hi = (int)(((long long)n * (slice + 1)) >> 3);
  const int sub = blockIdx.x >> 3;
  const int nsub = gridDim.x >> 3;
  for (int i = sub * blockDim.x + threadIdx.x; i < E; i += nsub * blockDim.x) {
    int nd = dst[i];
    if (nd >= lo && nd < hi) {
      float p = rij[i] * (float)(KTAB * 32) * 0.2f;  // r * KTAB*32/5
      int pf = (int)p;
      if (pf > 65535) pf = 65535;
      int pos = atomicAdd(&cur[nd], 1);
      ep[pos] = ((unsigned)src[i] << 16) | (unsigned)pf;
    }
  }
}

// Paired table: T2[l][g][d] = { W(r_g)[d]*C(r_g), W(r_{g+1})[d]*C(r_{g+1}) }
__global__ __launch_bounds__(256) void k_tables(const float* __restrict__ Wf1,
                                                const float* __restrict__ bf1,
                                                const float* __restrict__ Wf2,
                                                const float* __restrict__ bf2,
                                                float* __restrict__ T2) {
  __shared__ __align__(16) float rb[4][D64];
  const int lane = threadIdx.x & 63;
  const int wsl = threadIdx.x >> 6;
  const int wid = blockIdx.x * 4 + wsl;
  if (wid >= 3 * (KTAB + 1)) return;
  const int l = wid / (KTAB + 1);
  const int g = wid - l * (KTAB + 1);
  const float r = (float)g * (5.0f / KTAB);
  const float width = 5.0f / 24.0f;
  const float coeff = -0.5f / (width * width);
  float fv = 0.0f;
  if (lane < 25) { float dd = r - (float)lane * width; fv = expf(coeff * dd * dd); }
  rb[wsl][lane] = fv;
  float a1 = bf1[l * D64 + lane];
#pragma unroll
  for (int b = 0; b < 25; ++b)
    a1 = fmaf(rb[wsl][b], Wf1[(l * 25 + b) * D64 + lane], a1);
  float sw = swishf(a1);
  rb[wsl][lane] = sw;   // same-wave reuse; program order preserves DS deps
  float a2 = bf2[l * D64 + lane];
#pragma unroll
  for (int k = 0; k < D64; ++k)
    a2 = fmaf(rb[wsl][k], Wf2[l * D64 * D64 + k * D64 + lane], a2);
  float C = (r < 5.0f) ? 0.5f * (cosf(r * 0.62831853f) + 1.0f) : 0.0f;
  const float val = a2 * C;
  float* base = T2 + (size_t)l * KTAB * D64 * 2;
  if (g < KTAB) base[((size_t)g * D64 + lane) * 2] = val;
  if (g > 0)    base[((size_t)(g - 1) * D64 + lane) * 2 + 1] = val;
}

// x1 = bf16(feat @ Win).  4-row chunks per wave: 4 independent load->LDS->FMA
// chains in flight (the R4 k_out counters showed 1-chain waves = latency-bound:
// VALUBusy 13%, HBM 2.5%).  Weight columns in LDS (65-float pitch, conflict-
// free); activation reads are wave-uniform broadcasts.
__global__ __launch_bounds__(256) void k_x1(const float* __restrict__ feat,
                                            const float* __restrict__ Win,
                                            __hip_bfloat16* __restrict__ x1, int n) {
  __shared__ float wlds[D64 * 65];
  __shared__ __align__(16) float rb[4][4][D64];
  const int lane = threadIdx.x & 63;
  const int wsl = threadIdx.x >> 6;
  for (int i = threadIdx.x; i < D64 * D64; i += 256) {
    int kk = i >> 6, d = i & 63;
    wlds[d * 65 + kk] = Win[i];
  }
  __syncthreads();
  const float* wl = &wlds[lane * 65];
  const int wid = blockIdx.x * 4 + wsl;
  const int nw = gridDim.x * 4;
  int base = wid * 4;
  for (; base + 4 <= n; base += nw * 4) {
#pragma unroll
    for (int q = 0; q < 4; ++q)
      rb[wsl][q][lane] = feat[(size_t)(base + q) * D64 + lane];
    float p[4][4];
#pragma unroll
    for (int q = 0; q < 4; ++q) { p[q][0] = 0; p[q][1] = 0; p[q][2] = 0; p[q][3] = 0; }
#pragma unroll
    for (int k4 = 0; k4 < 16; ++k4) {
      float4 w4 = *(const float4*)&wl[k4 * 4];
#pragma unroll
      for (int q = 0; q < 4; ++q) {
        float4 a4 = *(const float4*)&rb[wsl][q][k4 * 4];
        p[q][0] = fmaf(a4.x, w4.x, p[q][0]);
        p[q][1] = fmaf(a4.y, w4.y, p[q][1]);
        p[q][2] = fmaf(a4.z, w4.z, p[q][2]);
        p[q][3] = fmaf(a4.w, w4.w, p[q][3]);
      }
    }
#pragma unroll
    for (int q = 0; q < 4; ++q)
      x1[(size_t)(base + q) * D64 + lane] =
          __float2bfloat16((p[q][0] + p[q][1]) + (p[q][2] + p[q][3]));
  }
  // tail (n%4 != 0 or stray chunk crossing n)
  for (int row = base; row < n; ++row) {
    rb[wsl][0][lane] = feat[(size_t)row * D64 + lane];
    float a0 = 0, a1 = 0, a2 = 0, a3 = 0;
#pragma unroll
    for (int k4 = 0; k4 < 16; ++k4) {
      float4 f4 = *(const float4*)&rb[wsl][0][k4 * 4];
      a0 = fmaf(f4.x, wl[k4 * 4 + 0], a0);
      a1 = fmaf(f4.y, wl[k4 * 4 + 1], a1);
      a2 = fmaf(f4.z, wl[k4 * 4 + 2], a2);
      a3 = fmaf(f4.w, wl[k4 * 4 + 3], a3);
    }
    x1[(size_t)row * D64 + lane] = __float2bfloat16((a0 + a1) + (a2 + a3));
  }
}

// agg[nd] = sum over incoming edges of x1[src] * lerp(T2, r); 4-way unrolled.
__global__ __launch_bounds__(256) void k_gather(const __hip_bfloat16* __restrict__ x1,
                                                const float2* __restrict__ T2,
                                                const unsigned* __restrict__ ep,
                                                const int* __restrict__ rp,
                                                float* __restrict__ agg, int n) {
  const int lane = threadIdx.x & 63;
  const int wid = (blockIdx.x * blockDim.x + threadIdx.x) >> 6;
  const int nw = (gridDim.x * blockDim.x) >> 6;
  for (int nd = wid; nd < n; nd += nw) {
    const int j0 = rp[nd], j1 = rp[nd + 1];
    float acc = 0.0f;
    int j = j0;
    for (; j + 4 <= j1; j += 4) {
      const unsigned u0 = ep[j + 0];
      const unsigned u1 = ep[j + 1];
      const unsigned u2 = ep[j + 2];
      const unsigned u3 = ep[j + 3];
      const float2 w0 = T2[(size_t)((u0 & 0xffffu) >> 5) * D64 + lane];
      const float2 w1 = T2[(size_t)((u1 & 0xffffu) >> 5) * D64 + lane];
      const float2 w2 = T2[(size_t)((u2 & 0xffffu) >> 5) * D64 + lane];
      const float2 w3 = T2[(size_t)((u3 & 0xffffu) >> 5) * D64 + lane];
      const float x0 = __bfloat162float(x1[(size_t)(u0 >> 16) * D64 + lane]);
      const float xa = __bfloat162float(x1[(size_t)(u1 >> 16) * D64 + lane]);
      const float xb = __bfloat162float(x1[(size_t)(u2 >> 16) * D64 + lane]);
      const float xc = __bfloat162float(x1[(size_t)(u3 >> 16) * D64 + lane]);
      const float t0 = (float)(u0 & 31u) * 0.03125f;
      const float t1 = (float)(u1 & 31u) * 0.03125f;
      const float t2 = (float)(u2 & 31u) * 0.03125f;
      const float t3 = (float)(u3 & 31u) * 0.03125f;
      acc = fmaf(x0, fmaf(t0, w0.y - w0.x, w0.x), acc);
      acc = fmaf(xa, fmaf(t1, w1.y - w1.x, w1.x), acc);
      acc = fmaf(xb, fmaf(t2, w2.y - w2.x, w2.x), acc);
      acc = fmaf(xc, fmaf(t3, w3.y - w3.x, w3.x), acc);
    }
    for (; j < j1; ++j) {
      const unsigned u = ep[j];
      const float2 w = T2[(size_t)((u & 0xffffu) >> 5) * D64 + lane];
      const float t = (float)(u & 31u) * 0.03125f;
      const float x = __bfloat162float(x1[(size_t)(u >> 16) * D64 + lane]);
      acc = fmaf(x, fmaf(t, w.y - w.x, w.x), acc);
    }
    agg[(size_t)nd * D64 + lane] = acc;
  }
}

// y = swish(agg@Wo1+bo1)@Wo2+bo2; feat += y; per-feature sums into striped
// partials.  4-row chunks per wave (16 independent FMA chains), feat prefetched
// early, weight reads shared across the 4 rows.
__global__ __launch_bounds__(256) void k_out(const float* __restrict__ agg,
                                             const float* __restrict__ Wo1,
                                             const float* __restrict__ bo1,
                                             const float* __restrict__ Wo2,
                                             const float* __restrict__ bo2,
                                             float* __restrict__ feat,
                                             float* __restrict__ part, int n) {
  __shared__ float w1t[D64 * 65];
  __shared__ float w2t[D64 * 65];
  __shared__ __align__(16) float rb[4][4][D64];
  const int lane = threadIdx.x & 63;
  const int wsl = threadIdx.x >> 6;
  for (int i = threadIdx.x; i < D64 * D64; i += 256) {
    int kk = i >> 6, d = i & 63;
    w1t[d * 65 + kk] = Wo1[i];
    w2t[d * 65 + kk] = Wo2[i];
  }
  __syncthreads();
  const float* wl1 = &w1t[lane * 65];
  const float* wl2 = &w2t[lane * 65];
  const float b1 = bo1[lane], b2 = bo2[lane];
  float sf = 0.0f, sf2 = 0.0f;
  const int wid = blockIdx.x * 4 + wsl;
  const int nw = gridDim.x * 4;
  int base = wid * 4;
  for (; base + 4 <= n; base += nw * 4) {
    float fv[4];
#pragma unroll
    for (int q = 0; q < 4; ++q) fv[q] = feat[(size_t)(base + q) * D64 + lane];
#pragma unroll
    for (int q = 0; q < 4; ++q)
      rb[wsl][q][lane] = agg[(size_t)(base + q) * D64 + lane];
    float p[4][4];
#pragma unroll
    for (int q = 0; q < 4; ++q) { p[q][0] = b1; p[q][1] = 0; p[q][2] = 0; p[q][3] = 0; }
#pragma unroll
    for (int k4 = 0; k4 < 16; ++k4) {
      float4 w4 = *(const float4*)&wl1[k4 * 4];
#pragma unroll
      for (int q = 0; q < 4; ++q) {
        float4 a4 = *(const float4*)&rb[wsl][q][k4 * 4];
        p[q][0] = fmaf(a4.x, w4.x, p[q][0]);
        p[q][1] = fmaf(a4.y, w4.y, p[q][1]);
        p[q][2] = fmaf(a4.z, w4.z, p[q][2]);
        p[q][3] = fmaf(a4.w, w4.w, p[q][3]);
      }
    }
#pragma unroll
    for (int q = 0; q < 4; ++q)
      rb[wsl][q][lane] = swishf((p[q][0] + p[q][1]) + (p[q][2] + p[q][3]));
#pragma unroll
    for (int q = 0; q < 4; ++q) { p[q][0] = b2; p[q][1] = 0; p[q][2] = 0; p[q][3] = 0; }
#pragma unroll
    for (int k4 = 0; k4 < 16; ++k4) {
      float4 w4 = *(const float4*)&wl2[k4 * 4];
#pragma unroll
      for (int q = 0; q < 4; ++q) {
        float4 a4 = *(const float4*)&rb[wsl][q][k4 * 4];
        p[q][0] = fmaf(a4.x, w4.x, p[q][0]);
        p[q][1] = fmaf(a4.y, w4.y, p[q][1]);
        p[q][2] = fmaf(a4.z, w4.z, p[q][2]);
        p[q][3] = fmaf(a4.w, w4.w, p[q][3]);
      }
    }
#pragma unroll
    for (int q = 0; q < 4; ++q) {
      float fn = fv[q] + ((p[q][0] + p[q][1]) + (p[q][2] + p[q][3]));
      feat[(size_t)(base + q) * D64 + lane] = fn;
      sf += fn;
      sf2 += fn * fn;
    }
  }
  // tail
  for (int row = base; row < n; ++row) {
    float fvs = feat[(size_t)row * D64 + lane];
    rb[wsl][0][lane] = agg[(size_t)row * D64 + lane];
    float a0 = b1, a1 = 0, a2 = 0, a3 = 0;
#pragma unroll
    for (int k4 = 0; k4 < 16; ++k4) {
      float4 f4 = *(const float4*)&rb[wsl][0][k4 * 4];
      a0 = fmaf(f4.x, wl1[k4 * 4 + 0], a0);
      a1 = fmaf(f4.y, wl1[k4 * 4 + 1], a1);
      a2 = fmaf(f4.z, wl1[k4 * 4 + 2], a2);
      a3 = fmaf(f4.w, wl1[k4 * 4 + 3], a3);
    }
    rb[wsl][0][lane] = swishf((a0 + a1) + (a2 + a3));
    float q0 = b2, q1 = 0, q2 = 0, q3 = 0;
#pragma unroll
    for (int k4 = 0; k4 < 16; ++k4) {
      float4 f4 = *(const float4*)&rb[wsl][0][k4 * 4];
      q0 = fmaf(f4.x, wl2[k4 * 4 + 0], q0);
      q1 = fmaf(f4.y, wl2[k4 * 4 + 1], q1);
      q2 = fmaf(f4.z, wl2[k4 * 4 + 2], q2);
      q3 = fmaf(f4.w, wl2[k4 * 4 + 3], q3);
    }
    float fn = fvs + ((q0 + q1) + (q2 + q3));
    feat[(size_t)row * D64 + lane] = fn;
    sf += fn;
    sf2 += fn * fn;
  }
  const int slot = blockIdx.x & 63;
  atomAddF(&part[slot * 128 + lane], sf);
  atomAddF(&part[slot * 128 + 64 + lane], sf2);
}

// reduce striped partials; compute scale/shift. var = E[f^2] - (2a - a^2) mu^2
__global__ void k_nfin(const float* __restrict__ part, float* __restrict__ stats,
                       const float* __restrict__ al, const float* __restrict__ ga,
                       const float* __restrict__ be, int n) {
  __shared__ float red[128];
  const int t = threadIdx.x;  // 128 threads
  float s = 0.0f;
#pragma unroll 8
  for (int b = 0; b < 64; ++b) s += part[b * 128 + t];
  red[t] = s;
  __syncthreads();
  if (t < 64) {
    float invN = 1.0f / (float)n;
    float mu = red[t] * invN;
    float ex2 = red[64 + t] * invN;
    float a = al[t];
    float var = ex2 - (2.0f * a - a * a) * mu * mu;
    float sc = ga[t] * rsqrtf(var + 1e-5f);
    stats[128 + t] = sc;
    stats[192 + t] = be[t] - sc * a * mu;
  }
}

__global__ void k_napp(float* __restrict__ feat, const float* __restrict__ stats, int total) {
  int idx = blockIdx.x * 256 + threadIdx.x;
  if (idx < total) {
    int d = idx & 63;
    feat[idx] = fmaf(feat[idx], stats[128 + d], stats[192 + d]);
  }
}

__global__ __launch_bounds__(256) void k_colmax(const float* __restrict__ feat,
                                                unsigned* __restrict__ um, int n) {
  const int lane = threadIdx.x & 63;
  const int wid = (blockIdx.x * blockDim.x + threadIdx.x) >> 6;
  const int nw = (gridDim.x * blockDim.x) >> 6;
  float m = -3.402823e38f;
  for (int r = wid; r < n; r += nw) m = fmaxf(m, feat[(size_t)r * D64 + lane]);
  atomicMax(&um[lane], fkey(m));
}

__global__ __launch_bounds__(256) void k_colsum(const float* __restrict__ feat,
                                                float* __restrict__ rd, int n) {
  const unsigned* um = (const unsigned*)rd;
  const int lane = threadIdx.x & 63;
  const int wid = (blockIdx.x * blockDim.x + threadIdx.x) >> 6;
  const int nw = (gridDim.x * blockDim.x) >> 6;
  const float mx = funkey(um[lane]);
  float s1 = 0.0f, s2 = 0.0f;
  for (int r = wid; r < n; r += nw) {
    float f = feat[(size_t)r * D64 + lane];
    float e = expf(f - mx);
    s1 += e;
    s2 += e * f;
  }
  atomAddF(&rd[64 + lane], s1);
  atomAddF(&rd[128 + lane], s2);
}

__global__ void k_pooled(const float* __restrict__ rd, float* __restrict__ out) {
  int d = threadIdx.x;
  if (d < D64) out[d] = rd[128 + d] / rd[64 + d];
}

extern "C" void kernel_launch(void* const* d_in, const int* in_sizes, int n_in,
                              void* d_out, int out_size, void* d_ws, size_t ws_size,
                              hipStream_t stream) {
  const int* z = (const int*)d_in[0];
  const int* src = (const int*)d_in[1];
  const int* dst = (const int*)d_in[2];
  const float* rij = (const float*)d_in[3];
  const float* emb = (const float*)d_in[4];
  const float* Win = (const float*)d_in[5];
  const float* Wf1 = (const float*)d_in[6];
  const float* bf1 = (const float*)d_in[7];
  const float* Wf2 = (const float*)d_in[8];
  const float* bf2 = (const float*)d_in[9];
  const float* Wo1 = (const float*)d_in[10];
  const float* bo1 = (const float*)d_in[11];
  const float* Wo2 = (const float*)d_in[12];
  const float* bo2 = (const float*)d_in[13];
  const float* gal = (const float*)d_in[14];
  const float* gga = (const float*)d_in[15];
  const float* gbe = (const float*)d_in[16];
  const int n = in_sizes[0];
  const int E = in_sizes[1];
  (void)n_in; (void)out_size; (void)ws_size;

  float* feat = (float*)d_out;                 // [n,64] lives in d_out
  float* pooled = feat + (size_t)n * D64;      // [64]

  char* w = (char*)d_ws;
  size_t off = 0;
  auto take = [&](size_t bytes) {
    size_t o = (off + 255) & ~(size_t)255;
    off = o + bytes;
    return (void*)(w + o);
  };
  __hip_bfloat16* x1 = (__hip_bfloat16*)take((size_t)n * D64 * 2);
  float* agg = (float*)take((size_t)n * D64 * 4);
  float* stats = (float*)take(256 * 4);
  float* part = (float*)take(64 * 128 * 4);
  float* rdst = (float*)take(192 * 4);
  float* T2 = (float*)take((size_t)3 * KTAB * D64 * 2 * 4);
  int* deg = (int*)take((size_t)n * 4);
  int* rp = (int*)take((size_t)(n + 1) * 4);
  int* cur = (int*)take((size_t)n * 4);
  unsigned* ep = (unsigned*)take((size_t)E * 4);

  hipMemsetAsync(deg, 0, (size_t)n * 4, stream);
  k_init<<<(n * D64 + 255) / 256, 256, 0, stream>>>(z, emb, feat, n * D64);
  k_hist<<<1024, 256, 0, stream>>>(dst, deg, E);
  k_scan<<<1, 1024, 0, stream>>>(deg, rp, cur, n);
  k_scatter<<<1024, 256, 0, stream>>>(src, dst, rij, cur, ep, E, n);
  k_tables<<<(3 * (KTAB + 1) + 3) / 4, 256, 0, stream>>>(Wf1, bf1, Wf2, bf2, T2);

  for (int l = 0; l < 3; ++l) {
    k_x1<<<2048, 256, 0, stream>>>(feat, Win + (size_t)l * D64 * D64, x1, n);
    hipMemsetAsync(part, 0, 64 * 128 * 4, stream);
    k_gather<<<2048, 256, 0, stream>>>(x1, (const float2*)(T2 + (size_t)l * KTAB * D64 * 2),
                                       ep, rp, agg, n);
    k_out<<<2048, 256, 0, stream>>>(agg, Wo1 + (size_t)l * D64 * D64, bo1 + l * D64,
                                    Wo2 + (size_t)l * D64 * D64, bo2 + l * D64, feat, part, n);
    k_nfin<<<1, 128, 0, stream>>>(part, stats, gal + l * D64, gga + l * D64, gbe + l * D64, n);
    k_napp<<<(n * D64 + 255) / 256, 256, 0, stream>>>(feat, stats, n * D64);
  }

  hipMemsetAsync(rdst, 0, 192 * 4, stream);
  k_colmax<<<512, 256, 0, stream>>>(feat, (unsigned*)rdst, n);
  k_colsum<<<512, 256, 0, stream>>>(feat, rdst, n);
  k_pooled<<<1, 64, 0, stream>>>(rdst, pooled);
}

// Round 6
// 822.376 us; speedup vs baseline: 1.5248x; 1.1050x over previous
//
#include <hip/hip_runtime.h>
#include <hip/hip_bf16.h>
#include <math.h>

#define D64 64
#define KTAB 2048   // lerp table intervals over r in [0,5]

// ---------------- helpers ----------------
__device__ __forceinline__ void atomAddF(float* p, float v) {
  __hip_atomic_fetch_add(p, v, __ATOMIC_RELAXED, __HIP_MEMORY_SCOPE_AGENT);
}
__device__ __forceinline__ unsigned fkey(float f) {
  unsigned u = __float_as_uint(f);
  return (u & 0x80000000u) ? ~u : (u | 0x80000000u);
}
__device__ __forceinline__ float funkey(unsigned k) {
  return __uint_as_float((k & 0x80000000u) ? (k & 0x7fffffffu) : ~k);
}
__device__ __forceinline__ float swishf(float x) { return x / (1.0f + expf(-x)); }

// feat[i,d] = emb[z[i],d]
__global__ void k_init(const int* __restrict__ z, const float* __restrict__ emb,
                       float* __restrict__ feat, int total) {
  int idx = blockIdx.x * 256 + threadIdx.x;
  if (idx < total) feat[idx] = emb[z[idx >> 6] * D64 + (idx & 63)];
}

__global__ void k_hist(const int* __restrict__ dst, int* __restrict__ deg, int E) {
  for (int i = blockIdx.x * blockDim.x + threadIdx.x; i < E; i += gridDim.x * blockDim.x)
    atomicAdd(&deg[dst[i]], 1);
}

// single-block exclusive scan over deg[0..n) -> rp[0..n], also copies into cur
__global__ void k_scan(const int* __restrict__ deg, int* __restrict__ rp,
                       int* __restrict__ cur, int n) {
  __shared__ int sb[1024];
  __shared__ int carry_s;
  const int tid = threadIdx.x;
  if (tid == 0) carry_s = 0;
  __syncthreads();
  for (int base = 0; base < n; base += 4096) {
    int i0 = base + tid * 4;
    int v[4];
#pragma unroll
    for (int q = 0; q < 4; ++q) { int i = i0 + q; v[q] = (i < n) ? deg[i] : 0; }
    int s = v[0] + v[1] + v[2] + v[3];
    sb[tid] = s;
    __syncthreads();
    for (int o = 1; o < 1024; o <<= 1) {
      int t = (tid >= o) ? sb[tid - o] : 0;
      __syncthreads();
      sb[tid] += t;
      __syncthreads();
    }
    int incl = sb[tid];
    int carry = carry_s;
    int excl = carry + incl - s;
#pragma unroll
    for (int q = 0; q < 4; ++q) {
      int i = i0 + q;
      if (i < n) { rp[i] = excl; cur[i] = excl; }
      excl += v[q];
    }
    __syncthreads();
    if (tid == 1023) carry_s = carry + incl;
    __syncthreads();
  }
  if (tid == 0) rp[n] = carry_s;
}

// Slice-partitioned bucket-by-dst (keeps each XCD's write set L2-resident).
// ep entry: src<<16 | fixed-point(r * KTAB*32/5) (k:11b, frac:5b).
__global__ void k_scatter(const int* __restrict__ src, const int* __restrict__ dst,
                          const float* __restrict__ rij, int* __restrict__ cur,
                          unsigned* __restrict__ ep, int E, int n) {
  const int slice = blockIdx.x & 7;
  const int lo = (int)(((long long)n * slice) >> 3);
  const int hi = (int)(((long long)n * (slice + 1)) >> 3);
  const int sub = blockIdx.x >> 3;
  const int nsub = gridDim.x >> 3;
  for (int i = sub * blockDim.x + threadIdx.x; i < E; i += nsub * blockDim.x) {
    int nd = dst[i];
    if (nd >= lo && nd < hi) {
      float p = rij[i] * (float)(KTAB * 32) * 0.2f;  // r * KTAB*32/5
      int pf = (int)p;
      if (pf > 65535) pf = 65535;
      int pos = atomicAdd(&cur[nd], 1);
      ep[pos] = ((unsigned)src[i] << 16) | (unsigned)pf;
    }
  }
}

// Paired table: T2[l][g][d] = { W(r_g)[d]*C(r_g), W(r_{g+1})[d]*C(r_{g+1}) }
__global__ __launch_bounds__(256) void k_tables(const float* __restrict__ Wf1,
                                                const float* __restrict__ bf1,
                                                const float* __restrict__ Wf2,
                                                const float* __restrict__ bf2,
                                                float* __restrict__ T2) {
  __shared__ __align__(16) float rb[4][D64];
  const int lane = threadIdx.x & 63;
  const int wsl = threadIdx.x >> 6;
  const int wid = blockIdx.x * 4 + wsl;
  if (wid >= 3 * (KTAB + 1)) return;
  const int l = wid / (KTAB + 1);
  const int g = wid - l * (KTAB + 1);
  const float r = (float)g * (5.0f / KTAB);
  const float width = 5.0f / 24.0f;
  const float coeff = -0.5f / (width * width);
  float fv = 0.0f;
  if (lane < 25) { float dd = r - (float)lane * width; fv = expf(coeff * dd * dd); }
  rb[wsl][lane] = fv;
  float a1 = bf1[l * D64 + lane];
#pragma unroll
  for (int b = 0; b < 25; ++b)
    a1 = fmaf(rb[wsl][b], Wf1[(l * 25 + b) * D64 + lane], a1);
  float sw = swishf(a1);
  rb[wsl][lane] = sw;   // same-wave reuse; program order preserves DS deps
  float a2 = bf2[l * D64 + lane];
#pragma unroll
  for (int k = 0; k < D64; ++k)
    a2 = fmaf(rb[wsl][k], Wf2[l * D64 * D64 + k * D64 + lane], a2);
  float C = (r < 5.0f) ? 0.5f * (cosf(r * 0.62831853f) + 1.0f) : 0.0f;
  const float val = a2 * C;
  float* base = T2 + (size_t)l * KTAB * D64 * 2;
  if (g < KTAB) base[((size_t)g * D64 + lane) * 2] = val;
  if (g > 0)    base[((size_t)(g - 1) * D64 + lane) * 2 + 1] = val;
}

// x1 = bf16(feat @ Win).  4-row chunks per wave; weight columns in LDS
// (65-float pitch, conflict-free); activation reads are broadcasts.
__global__ __launch_bounds__(256) void k_x1(const float* __restrict__ feat,
                                            const float* __restrict__ Win,
                                            __hip_bfloat16* __restrict__ x1, int n) {
  __shared__ float wlds[D64 * 65];
  __shared__ __align__(16) float rb[4][4][D64];
  const int lane = threadIdx.x & 63;
  const int wsl = threadIdx.x >> 6;
  for (int i = threadIdx.x; i < D64 * D64; i += 256) {
    int kk = i >> 6, d = i & 63;
    wlds[d * 65 + kk] = Win[i];
  }
  __syncthreads();
  const float* wl = &wlds[lane * 65];
  const int wid = blockIdx.x * 4 + wsl;
  const int nw = gridDim.x * 4;
  int base = wid * 4;
  for (; base + 4 <= n; base += nw * 4) {
#pragma unroll
    for (int q = 0; q < 4; ++q)
      rb[wsl][q][lane] = feat[(size_t)(base + q) * D64 + lane];
    float p[4][4];
#pragma unroll
    for (int q = 0; q < 4; ++q) { p[q][0] = 0; p[q][1] = 0; p[q][2] = 0; p[q][3] = 0; }
#pragma unroll
    for (int k4 = 0; k4 < 16; ++k4) {
      float4 w4 = *(const float4*)&wl[k4 * 4];
#pragma unroll
      for (int q = 0; q < 4; ++q) {
        float4 a4 = *(const float4*)&rb[wsl][q][k4 * 4];
        p[q][0] = fmaf(a4.x, w4.x, p[q][0]);
        p[q][1] = fmaf(a4.y, w4.y, p[q][1]);
        p[q][2] = fmaf(a4.z, w4.z, p[q][2]);
        p[q][3] = fmaf(a4.w, w4.w, p[q][3]);
      }
    }
#pragma unroll
    for (int q = 0; q < 4; ++q)
      x1[(size_t)(base + q) * D64 + lane] =
          __float2bfloat16((p[q][0] + p[q][1]) + (p[q][2] + p[q][3]));
  }
  for (int row = base; row < n; ++row) {
    rb[wsl][0][lane] = feat[(size_t)row * D64 + lane];
    float a0 = 0, a1 = 0, a2 = 0, a3 = 0;
#pragma unroll
    for (int k4 = 0; k4 < 16; ++k4) {
      float4 f4 = *(const float4*)&rb[wsl][0][k4 * 4];
      a0 = fmaf(f4.x, wl[k4 * 4 + 0], a0);
      a1 = fmaf(f4.y, wl[k4 * 4 + 1], a1);
      a2 = fmaf(f4.z, wl[k4 * 4 + 2], a2);
      a3 = fmaf(f4.w, wl[k4 * 4 + 3], a3);
    }
    x1[(size_t)row * D64 + lane] = __float2bfloat16((a0 + a1) + (a2 + a3));
  }
}

// agg[nd] = sum over incoming edges of x1[src] * lerp(T2, r).
// Half-wave edge pairing: lanes 0-31 = edge j, lanes 32-63 = edge j+1; each
// lane covers 2 features (ushort2 x1 read, float4 paired-table read).  Per 2
// edges: 3 memory instrs (was 6) and ~half the VALU.  Cross-half combine via
// one shfl_xor pair per node.  8 edges in flight per iteration.
__global__ __launch_bounds__(256) void k_gather(const __hip_bfloat16* __restrict__ x1,
                                                const float2* __restrict__ T2,
                                                const unsigned* __restrict__ ep,
                                                const int* __restrict__ rp,
                                                float* __restrict__ agg, int n) {
  const int lane = threadIdx.x & 63;
  const int half = lane >> 5;
  const int fl = lane & 31;            // features 2*fl, 2*fl+1
  const unsigned short* __restrict__ x1u = (const unsigned short*)x1;
  const int wid = (blockIdx.x * blockDim.x + threadIdx.x) >> 6;
  const int nw = (gridDim.x * blockDim.x) >> 6;
  for (int nd = wid; nd < n; nd += nw) {
    const int j0 = rp[nd], j1 = rp[nd + 1];
    float axA = 0.0f, ayA = 0.0f, axB = 0.0f, ayB = 0.0f;
    int j = j0;
    for (; j + 8 <= j1; j += 8) {
      const unsigned u0 = ep[j + 0 + half];
      const unsigned u1 = ep[j + 2 + half];
      const unsigned u2 = ep[j + 4 + half];
      const unsigned u3 = ep[j + 6 + half];
      const ushort2 x0 = *(const ushort2*)&x1u[(size_t)(u0 >> 16) * D64 + fl * 2];
      const ushort2 xa = *(const ushort2*)&x1u[(size_t)(u1 >> 16) * D64 + fl * 2];
      const ushort2 xb = *(const ushort2*)&x1u[(size_t)(u2 >> 16) * D64 + fl * 2];
      const ushort2 xc = *(const ushort2*)&x1u[(size_t)(u3 >> 16) * D64 + fl * 2];
      const float4 w0 = *(const float4*)&T2[(size_t)((u0 & 0xffffu) >> 5) * D64 + fl * 2];
      const float4 w1 = *(const float4*)&T2[(size_t)((u1 & 0xffffu) >> 5) * D64 + fl * 2];
      const float4 w2 = *(const float4*)&T2[(size_t)((u2 & 0xffffu) >> 5) * D64 + fl * 2];
      const float4 w3 = *(const float4*)&T2[(size_t)((u3 & 0xffffu) >> 5) * D64 + fl * 2];
      const float t0 = (float)(u0 & 31u) * 0.03125f;
      const float t1 = (float)(u1 & 31u) * 0.03125f;
      const float t2 = (float)(u2 & 31u) * 0.03125f;
      const float t3 = (float)(u3 & 31u) * 0.03125f;
      axA = fmaf(__uint_as_float((unsigned)x0.x << 16), fmaf(t0, w0.y - w0.x, w0.x), axA);
      ayA = fmaf(__uint_as_float((unsigned)x0.y << 16), fmaf(t0, w0.w - w0.z, w0.z), ayA);
      axB = fmaf(__uint_as_float((unsigned)xa.x << 16), fmaf(t1, w1.y - w1.x, w1.x), axB);
      ayB = fmaf(__uint_as_float((unsigned)xa.y << 16), fmaf(t1, w1.w - w1.z, w1.z), ayB);
      axA = fmaf(__uint_as_float((unsigned)xb.x << 16), fmaf(t2, w2.y - w2.x, w2.x), axA);
      ayA = fmaf(__uint_as_float((unsigned)xb.y << 16), fmaf(t2, w2.w - w2.z, w2.z), ayA);
      axB = fmaf(__uint_as_float((unsigned)xc.x << 16), fmaf(t3, w3.y - w3.x, w3.x), axB);
      ayB = fmaf(__uint_as_float((unsigned)xc.y << 16), fmaf(t3, w3.w - w3.z, w3.z), ayB);
    }
    for (; j + 2 <= j1; j += 2) {
      const unsigned u = ep[j + half];
      const ushort2 xr = *(const ushort2*)&x1u[(size_t)(u >> 16) * D64 + fl * 2];
      const float4 w4 = *(const float4*)&T2[(size_t)((u & 0xffffu) >> 5) * D64 + fl * 2];
      const float t = (float)(u & 31u) * 0.03125f;
      axA = fmaf(__uint_as_float((unsigned)xr.x << 16), fmaf(t, w4.y - w4.x, w4.x), axA);
      ayA = fmaf(__uint_as_float((unsigned)xr.y << 16), fmaf(t, w4.w - w4.z, w4.z), ayA);
    }
    if (j < j1 && half == 0) {   // odd leftover edge: half 0 only
      const unsigned u = ep[j];
      const ushort2 xr = *(const ushort2*)&x1u[(size_t)(u >> 16) * D64 + fl * 2];
      const float4 w4 = *(const float4*)&T2[(size_t)((u & 0xffffu) >> 5) * D64 + fl * 2];
      const float t = (float)(u & 31u) * 0.03125f;
      axA = fmaf(__uint_as_float((unsigned)xr.x << 16), fmaf(t, w4.y - w4.x, w4.x), axA);
      ayA = fmaf(__uint_as_float((unsigned)xr.y << 16), fmaf(t, w4.w - w4.z, w4.z), ayA);
    }
    float ax = axA + axB, ay = ayA + ayB;
    ax += __shfl_xor(ax, 32);
    ay += __shfl_xor(ay, 32);
    if (half == 0) {
      float2 o; o.x = ax; o.y = ay;
      *(float2*)&agg[(size_t)nd * D64 + fl * 2] = o;
    }
  }
}

// y = swish(agg@Wo1+bo1)@Wo2+bo2; feat += y; per-feature sums into striped
// partials.  4-row chunks per wave (16 independent FMA chains).
__global__ __launch_bounds__(256) void k_out(const float* __restrict__ agg,
                                             const float* __restrict__ Wo1,
                                             const float* __restrict__ bo1,
                                             const float* __restrict__ Wo2,
                                             const float* __restrict__ bo2,
                                             float* __restrict__ feat,
                                             float* __restrict__ part, int n) {
  __shared__ float w1t[D64 * 65];
  __shared__ float w2t[D64 * 65];
  __shared__ __align__(16) float rb[4][4][D64];
  const int lane = threadIdx.x & 63;
  const int wsl = threadIdx.x >> 6;
  for (int i = threadIdx.x; i < D64 * D64; i += 256) {
    int kk = i >> 6, d = i & 63;
    w1t[d * 65 + kk] = Wo1[i];
    w2t[d * 65 + kk] = Wo2[i];
  }
  __syncthreads();
  const float* wl1 = &w1t[lane * 65];
  const float* wl2 = &w2t[lane * 65];
  const float b1 = bo1[lane], b2 = bo2[lane];
  float sf = 0.0f, sf2 = 0.0f;
  const int wid = blockIdx.x * 4 + wsl;
  const int nw = gridDim.x * 4;
  int base = wid * 4;
  for (; base + 4 <= n; base += nw * 4) {
    float fv[4];
#pragma unroll
    for (int q = 0; q < 4; ++q) fv[q] = feat[(size_t)(base + q) * D64 + lane];
#pragma unroll
    for (int q = 0; q < 4; ++q)
      rb[wsl][q][lane] = agg[(size_t)(base + q) * D64 + lane];
    float p[4][4];
#pragma unroll
    for (int q = 0; q < 4; ++q) { p[q][0] = b1; p[q][1] = 0; p[q][2] = 0; p[q][3] = 0; }
#pragma unroll
    for (int k4 = 0; k4 < 16; ++k4) {
      float4 w4 = *(const float4*)&wl1[k4 * 4];
#pragma unroll
      for (int q = 0; q < 4; ++q) {
        float4 a4 = *(const float4*)&rb[wsl][q][k4 * 4];
        p[q][0] = fmaf(a4.x, w4.x, p[q][0]);
        p[q][1] = fmaf(a4.y, w4.y, p[q][1]);
        p[q][2] = fmaf(a4.z, w4.z, p[q][2]);
        p[q][3] = fmaf(a4.w, w4.w, p[q][3]);
      }
    }
#pragma unroll
    for (int q = 0; q < 4; ++q)
      rb[wsl][q][lane] = swishf((p[q][0] + p[q][1]) + (p[q][2] + p[q][3]));
#pragma unroll
    for (int q = 0; q < 4; ++q) { p[q][0] = b2; p[q][1] = 0; p[q][2] = 0; p[q][3] = 0; }
#pragma unroll
    for (int k4 = 0; k4 < 16; ++k4) {
      float4 w4 = *(const float4*)&wl2[k4 * 4];
#pragma unroll
      for (int q = 0; q < 4; ++q) {
        float4 a4 = *(const float4*)&rb[wsl][q][k4 * 4];
        p[q][0] = fmaf(a4.x, w4.x, p[q][0]);
        p[q][1] = fmaf(a4.y, w4.y, p[q][1]);
        p[q][2] = fmaf(a4.z, w4.z, p[q][2]);
        p[q][3] = fmaf(a4.w, w4.w, p[q][3]);
      }
    }
#pragma unroll
    for (int q = 0; q < 4; ++q) {
      float fn = fv[q] + ((p[q][0] + p[q][1]) + (p[q][2] + p[q][3]));
      feat[(size_t)(base + q) * D64 + lane] = fn;
      sf += fn;
      sf2 += fn * fn;
    }
  }
  for (int row = base; row < n; ++row) {
    float fvs = feat[(size_t)row * D64 + lane];
    rb[wsl][0][lane] = agg[(size_t)row * D64 + lane];
    float a0 = b1, a1 = 0, a2 = 0, a3 = 0;
#pragma unroll
    for (int k4 = 0; k4 < 16; ++k4) {
      float4 f4 = *(const float4*)&rb[wsl][0][k4 * 4];
      a0 = fmaf(f4.x, wl1[k4 * 4 + 0], a0);
      a1 = fmaf(f4.y, wl1[k4 * 4 + 1], a1);
      a2 = fmaf(f4.z, wl1[k4 * 4 + 2], a2);
      a3 = fmaf(f4.w, wl1[k4 * 4 + 3], a3);
    }
    rb[wsl][0][lane] = swishf((a0 + a1) + (a2 + a3));
    float q0 = b2, q1 = 0, q2 = 0, q3 = 0;
#pragma unroll
    for (int k4 = 0; k4 < 16; ++k4) {
      float4 f4 = *(const float4*)&rb[wsl][0][k4 * 4];
      q0 = fmaf(f4.x, wl2[k4 * 4 + 0], q0);
      q1 = fmaf(f4.y, wl2[k4 * 4 + 1], q1);
      q2 = fmaf(f4.z, wl2[k4 * 4 + 2], q2);
      q3 = fmaf(f4.w, wl2[k4 * 4 + 3], q3);
    }
    float fn = fvs + ((q0 + q1) + (q2 + q3));
    feat[(size_t)row * D64 + lane] = fn;
    sf += fn;
    sf2 += fn * fn;
  }
  const int slot = blockIdx.x & 63;
  atomAddF(&part[slot * 128 + lane], sf);
  atomAddF(&part[slot * 128 + 64 + lane], sf2);
}

// reduce striped partials; compute scale/shift. var = E[f^2] - (2a - a^2) mu^2
__global__ void k_nfin(const float* __restrict__ part, float* __restrict__ stats,
                       const float* __restrict__ al, const float* __restrict__ ga,
                       const float* __restrict__ be, int n) {
  __shared__ float red[128];
  const int t = threadIdx.x;  // 128 threads
  float s = 0.0f;
#pragma unroll 8
  for (int b = 0; b < 64; ++b) s += part[b * 128 + t];
  red[t] = s;
  __syncthreads();
  if (t < 64) {
    float invN = 1.0f / (float)n;
    float mu = red[t] * invN;
    float ex2 = red[64 + t] * invN;
    float a = al[t];
    float var = ex2 - (2.0f * a - a * a) * mu * mu;
    float sc = ga[t] * rsqrtf(var + 1e-5f);
    stats[128 + t] = sc;
    stats[192 + t] = be[t] - sc * a * mu;
  }
}

__global__ void k_napp(float* __restrict__ feat, const float* __restrict__ stats, int total) {
  int idx = blockIdx.x * 256 + threadIdx.x;
  if (idx < total) {
    int d = idx & 63;
    feat[idx] = fmaf(feat[idx], stats[128 + d], stats[192 + d]);
  }
}

__global__ __launch_bounds__(256) void k_colmax(const float* __restrict__ feat,
                                                unsigned* __restrict__ um, int n) {
  const int lane = threadIdx.x & 63;
  const int wid = (blockIdx.x * blockDim.x + threadIdx.x) >> 6;
  const int nw = (gridDim.x * blockDim.x) >> 6;
  float m = -3.402823e38f;
  for (int r = wid; r < n; r += nw) m = fmaxf(m, feat[(size_t)r * D64 + lane]);
  atomicMax(&um[lane], fkey(m));
}

__global__ __launch_bounds__(256) void k_colsum(const float* __restrict__ feat,
                                                float* __restrict__ rd, int n) {
  const unsigned* um = (const unsigned*)rd;
  const int lane = threadIdx.x & 63;
  const int wid = (blockIdx.x * blockDim.x + threadIdx.x) >> 6;
  const int nw = (gridDim.x * blockDim.x) >> 6;
  const float mx = funkey(um[lane]);
  float s1 = 0.0f, s2 = 0.0f;
  for (int r = wid; r < n; r += nw) {
    float f = feat[(size_t)r * D64 + lane];
    float e = expf(f - mx);
    s1 += e;
    s2 += e * f;
  }
  atomAddF(&rd[64 + lane], s1);
  atomAddF(&rd[128 + lane], s2);
}

__global__ void k_pooled(const float* __restrict__ rd, float* __restrict__ out) {
  int d = threadIdx.x;
  if (d < D64) out[d] = rd[128 + d] / rd[64 + d];
}

extern "C" void kernel_launch(void* const* d_in, const int* in_sizes, int n_in,
                              void* d_out, int out_size, void* d_ws, size_t ws_size,
                              hipStream_t stream) {
  const int* z = (const int*)d_in[0];
  const int* src = (const int*)d_in[1];
  const int* dst = (const int*)d_in[2];
  const float* rij = (const float*)d_in[3];
  const float* emb = (const float*)d_in[4];
  const float* Win = (const float*)d_in[5];
  const float* Wf1 = (const float*)d_in[6];
  const float* bf1 = (const float*)d_in[7];
  const float* Wf2 = (const float*)d_in[8];
  const float* bf2 = (const float*)d_in[9];
  const float* Wo1 = (const float*)d_in[10];
  const float* bo1 = (const float*)d_in[11];
  const float* Wo2 = (const float*)d_in[12];
  const float* bo2 = (const float*)d_in[13];
  const float* gal = (const float*)d_in[14];
  const float* gga = (const float*)d_in[15];
  const float* gbe = (const float*)d_in[16];
  const int n = in_sizes[0];
  const int E = in_sizes[1];
  (void)n_in; (void)out_size; (void)ws_size;

  float* feat = (float*)d_out;                 // [n,64] lives in d_out
  float* pooled = feat + (size_t)n * D64;      // [64]

  char* w = (char*)d_ws;
  size_t off = 0;
  auto take = [&](size_t bytes) {
    size_t o = (off + 255) & ~(size_t)255;
    off = o + bytes;
    return (void*)(w + o);
  };
  __hip_bfloat16* x1 = (__hip_bfloat16*)take((size_t)n * D64 * 2);
  float* agg = (float*)take((size_t)n * D64 * 4);
  float* stats = (float*)take(256 * 4);
  float* part = (float*)take(64 * 128 * 4);
  float* rdst = (float*)take(192 * 4);
  float* T2 = (float*)take((size_t)3 * KTAB * D64 * 2 * 4);
  int* deg = (int*)take((size_t)n * 4);
  int* rp = (int*)take((size_t)(n + 1) * 4);
  int* cur = (int*)take((size_t)n * 4);
  unsigned* ep = (unsigned*)take((size_t)E * 4);

  hipMemsetAsync(deg, 0, (size_t)n * 4, stream);
  k_init<<<(n * D64 + 255) / 256, 256, 0, stream>>>(z, emb, feat, n * D64);
  k_hist<<<1024, 256, 0, stream>>>(dst, deg, E);
  k_scan<<<1, 1024, 0, stream>>>(deg, rp, cur, n);
  k_scatter<<<1024, 256, 0, stream>>>(src, dst, rij, cur, ep, E, n);
  k_tables<<<(3 * (KTAB + 1) + 3) / 4, 256, 0, stream>>>(Wf1, bf1, Wf2, bf2, T2);

  for (int l = 0; l < 3; ++l) {
    k_x1<<<2048, 256, 0, stream>>>(feat, Win + (size_t)l * D64 * D64, x1, n);
    hipMemsetAsync(part, 0, 64 * 128 * 4, stream);
    k_gather<<<2048, 256, 0, stream>>>(x1, (const float2*)(T2 + (size_t)l * KTAB * D64 * 2),
                                       ep, rp, agg, n);
    k_out<<<2048, 256, 0, stream>>>(agg, Wo1 + (size_t)l * D64 * D64, bo1 + l * D64,
                                    Wo2 + (size_t)l * D64 * D64, bo2 + l * D64, feat, part, n);
    k_nfin<<<1, 128, 0, stream>>>(part, stats, gal + l * D64, gga + l * D64, gbe + l * D64, n);
    k_napp<<<(n * D64 + 255) / 256, 256, 0, stream>>>(feat, stats, n * D64);
  }

  hipMemsetAsync(rdst, 0, 192 * 4, stream);
  k_colmax<<<512, 256, 0, stream>>>(feat, (unsigned*)rdst, n);
  k_colsum<<<512, 256, 0, stream>>>(feat, rdst, n);
  k_pooled<<<1, 64, 0, stream>>>(rdst, pooled);
}

// Round 7
// 810.168 us; speedup vs baseline: 1.5478x; 1.0151x over previous
//
#include <hip/hip_runtime.h>
#include <hip/hip_bf16.h>
#include <math.h>

#define D64 64
#define KTAB 2048   // lerp table intervals over r in [0,5]

typedef unsigned int uint4a __attribute__((ext_vector_type(4), aligned(4)));

// ---------------- helpers ----------------
__device__ __forceinline__ void atomAddF(float* p, float v) {
  __hip_atomic_fetch_add(p, v, __ATOMIC_RELAXED, __HIP_MEMORY_SCOPE_AGENT);
}
__device__ __forceinline__ unsigned fkey(float f) {
  unsigned u = __float_as_uint(f);
  return (u & 0x80000000u) ? ~u : (u | 0x80000000u);
}
__device__ __forceinline__ float funkey(unsigned k) {
  return __uint_as_float((k & 0x80000000u) ? (k & 0x7fffffffu) : ~k);
}
__device__ __forceinline__ float swishf(float x) { return x / (1.0f + expf(-x)); }
__device__ __forceinline__ float bx(unsigned short s) {
  return __uint_as_float((unsigned)s << 16);
}

// feat[i,d] = emb[z[i],d]
__global__ void k_init(const int* __restrict__ z, const float* __restrict__ emb,
                       float* __restrict__ feat, int total) {
  int idx = blockIdx.x * 256 + threadIdx.x;
  if (idx < total) feat[idx] = emb[z[idx >> 6] * D64 + (idx & 63)];
}

__global__ void k_hist(const int* __restrict__ dst, int* __restrict__ deg, int E) {
  for (int i = blockIdx.x * blockDim.x + threadIdx.x; i < E; i += gridDim.x * blockDim.x)
    atomicAdd(&deg[dst[i]], 1);
}

// single-block exclusive scan over deg[0..n) -> rp[0..n], also copies into cur
__global__ void k_scan(const int* __restrict__ deg, int* __restrict__ rp,
                       int* __restrict__ cur, int n) {
  __shared__ int sb[1024];
  __shared__ int carry_s;
  const int tid = threadIdx.x;
  if (tid == 0) carry_s = 0;
  __syncthreads();
  for (int base = 0; base < n; base += 4096) {
    int i0 = base + tid * 4;
    int v[4];
#pragma unroll
    for (int q = 0; q < 4; ++q) { int i = i0 + q; v[q] = (i < n) ? deg[i] : 0; }
    int s = v[0] + v[1] + v[2] + v[3];
    sb[tid] = s;
    __syncthreads();
    for (int o = 1; o < 1024; o <<= 1) {
      int t = (tid >= o) ? sb[tid - o] : 0;
      __syncthreads();
      sb[tid] += t;
      __syncthreads();
    }
    int incl = sb[tid];
    int carry = carry_s;
    int excl = carry + incl - s;
#pragma unroll
    for (int q = 0; q < 4; ++q) {
      int i = i0 + q;
      if (i < n) { rp[i] = excl; cur[i] = excl; }
      excl += v[q];
    }
    __syncthreads();
    if (tid == 1023) carry_s = carry + incl;
    __syncthreads();
  }
  if (tid == 0) rp[n] = carry_s;
}

// Slice-partitioned bucket-by-dst.  Streaming inputs are read NON-TEMPORALLY so
// they don't evict the partially-filled ep write lines from L2 (R6 counters:
// WRITE_SIZE 71MB for a 6.4MB buffer = ~11 writebacks/line caused by the read
// stream thrashing L2, not by the write-set size).
// ep entry: src<<16 | fixed-point(r * KTAB*32/5) (k:11b, frac:5b).
__global__ void k_scatter(const int* __restrict__ src, const int* __restrict__ dst,
                          const float* __restrict__ rij, int* __restrict__ cur,
                          unsigned* __restrict__ ep, int E, int n) {
  const int slice = blockIdx.x & 7;
  const int lo = (int)(((long long)n * slice) >> 3);
  const int hi = (int)(((long long)n * (slice + 1)) >> 3);
  const int sub = blockIdx.x >> 3;
  const int nsub = gridDim.x >> 3;
  for (int i = sub * blockDim.x + threadIdx.x; i < E; i += nsub * blockDim.x) {
    int nd = __builtin_nontemporal_load(&dst[i]);
    if (nd >= lo && nd < hi) {
      float rv = __builtin_nontemporal_load(&rij[i]);
      int sv = __builtin_nontemporal_load(&src[i]);
      float p = rv * (float)(KTAB * 32) * 0.2f;  // r * KTAB*32/5
      int pf = (int)p;
      if (pf > 65535) pf = 65535;
      int pos = atomicAdd(&cur[nd], 1);
      ep[pos] = ((unsigned)sv << 16) | (unsigned)pf;
    }
  }
}

// Paired table: T2[l][g][d] = { W(r_g)[d]*C(r_g), W(r_{g+1})[d]*C(r_{g+1}) }
__global__ __launch_bounds__(256) void k_tables(const float* __restrict__ Wf1,
                                                const float* __restrict__ bf1,
                                                const float* __restrict__ Wf2,
                                                const float* __restrict__ bf2,
                                                float* __restrict__ T2) {
  __shared__ __align__(16) float rb[4][D64];
  const int lane = threadIdx.x & 63;
  const int wsl = threadIdx.x >> 6;
  const int wid = blockIdx.x * 4 + wsl;
  if (wid >= 3 * (KTAB + 1)) return;
  const int l = wid / (KTAB + 1);
  const int g = wid - l * (KTAB + 1);
  const float r = (float)g * (5.0f / KTAB);
  const float width = 5.0f / 24.0f;
  const float coeff = -0.5f / (width * width);
  float fv = 0.0f;
  if (lane < 25) { float dd = r - (float)lane * width; fv = expf(coeff * dd * dd); }
  rb[wsl][lane] = fv;
  float a1 = bf1[l * D64 + lane];
#pragma unroll
  for (int b = 0; b < 25; ++b)
    a1 = fmaf(rb[wsl][b], Wf1[(l * 25 + b) * D64 + lane], a1);
  float sw = swishf(a1);
  rb[wsl][lane] = sw;   // same-wave reuse; program order preserves DS deps
  float a2 = bf2[l * D64 + lane];
#pragma unroll
  for (int k = 0; k < D64; ++k)
    a2 = fmaf(rb[wsl][k], Wf2[l * D64 * D64 + k * D64 + lane], a2);
  float C = (r < 5.0f) ? 0.5f * (cosf(r * 0.62831853f) + 1.0f) : 0.0f;
  const float val = a2 * C;
  float* base = T2 + (size_t)l * KTAB * D64 * 2;
  if (g < KTAB) base[((size_t)g * D64 + lane) * 2] = val;
  if (g > 0)    base[((size_t)(g - 1) * D64 + lane) * 2 + 1] = val;
}

// identity norm for layer 0
__global__ void k_nid(float* __restrict__ stats) {
  int d = threadIdx.x;
  stats[128 + d] = 1.0f;
  stats[192 + d] = 0.0f;
}

// x1 = bf16(norm(feat) @ Win).  Previous layer's GraphNorm affine (stats) is
// applied on the fly (napp fusion).  4-row chunks per wave; weight columns in
// LDS (65-float pitch, conflict-free).
__global__ __launch_bounds__(256) void k_x1(const float* __restrict__ feat,
                                            const float* __restrict__ Win,
                                            const float* __restrict__ stats,
                                            __hip_bfloat16* __restrict__ x1, int n) {
  __shared__ float wlds[D64 * 65];
  __shared__ __align__(16) float rb[4][4][D64];
  const int lane = threadIdx.x & 63;
  const int wsl = threadIdx.x >> 6;
  const float sc = stats[128 + lane], sh = stats[192 + lane];
  for (int i = threadIdx.x; i < D64 * D64; i += 256) {
    int kk = i >> 6, d = i & 63;
    wlds[d * 65 + kk] = Win[i];
  }
  __syncthreads();
  const float* wl = &wlds[lane * 65];
  const int wid = blockIdx.x * 4 + wsl;
  const int nw = gridDim.x * 4;
  int base = wid * 4;
  for (; base + 4 <= n; base += nw * 4) {
#pragma unroll
    for (int q = 0; q < 4; ++q)
      rb[wsl][q][lane] = fmaf(feat[(size_t)(base + q) * D64 + lane], sc, sh);
    float p[4][4];
#pragma unroll
    for (int q = 0; q < 4; ++q) { p[q][0] = 0; p[q][1] = 0; p[q][2] = 0; p[q][3] = 0; }
#pragma unroll
    for (int k4 = 0; k4 < 16; ++k4) {
      float4 w4 = *(const float4*)&wl[k4 * 4];
#pragma unroll
      for (int q = 0; q < 4; ++q) {
        float4 a4 = *(const float4*)&rb[wsl][q][k4 * 4];
        p[q][0] = fmaf(a4.x, w4.x, p[q][0]);
        p[q][1] = fmaf(a4.y, w4.y, p[q][1]);
        p[q][2] = fmaf(a4.z, w4.z, p[q][2]);
        p[q][3] = fmaf(a4.w, w4.w, p[q][3]);
      }
    }
#pragma unroll
    for (int q = 0; q < 4; ++q)
      x1[(size_t)(base + q) * D64 + lane] =
          __float2bfloat16((p[q][0] + p[q][1]) + (p[q][2] + p[q][3]));
  }
  for (int row = base; row < n; ++row) {
    rb[wsl][0][lane] = fmaf(feat[(size_t)row * D64 + lane], sc, sh);
    float a0 = 0, a1 = 0, a2 = 0, a3 = 0;
#pragma unroll
    for (int k4 = 0; k4 < 16; ++k4) {
      float4 f4 = *(const float4*)&rb[wsl][0][k4 * 4];
      a0 = fmaf(f4.x, wl[k4 * 4 + 0], a0);
      a1 = fmaf(f4.y, wl[k4 * 4 + 1], a1);
      a2 = fmaf(f4.z, wl[k4 * 4 + 2], a2);
      a3 = fmaf(f4.w, wl[k4 * 4 + 3], a3);
    }
    x1[(size_t)row * D64 + lane] = __float2bfloat16((a0 + a1) + (a2 + a3));
  }
}

// agg[nd] = sum over incoming edges of x1[src] * lerp(T2, r).
// Half-wave edge pairing; per iteration each half loads 4 packed edges with ONE
// dwordx4 (edges of a node are contiguous in ep), then 4 x1 ushort2 + 4 T2
// float4 gathers.  18 mem instrs / 8 edges (was 24).
__global__ __launch_bounds__(256) void k_gather(const __hip_bfloat16* __restrict__ x1,
                                                const float2* __restrict__ T2,
                                                const unsigned* __restrict__ ep,
                                                const int* __restrict__ rp,
                                                float* __restrict__ agg, int n) {
  const int lane = threadIdx.x & 63;
  const int half = lane >> 5;
  const int fl = lane & 31;            // features 2*fl, 2*fl+1
  const unsigned short* __restrict__ x1u = (const unsigned short*)x1;
  const int wid = (blockIdx.x * blockDim.x + threadIdx.x) >> 6;
  const int nw = (gridDim.x * blockDim.x) >> 6;
  for (int nd = wid; nd < n; nd += nw) {
    const int j0 = rp[nd], j1 = rp[nd + 1];
    float ax0 = 0.0f, ay0 = 0.0f, ax1 = 0.0f, ay1 = 0.0f;
    int j = j0;
    for (; j + 8 <= j1; j += 8) {
      const uint4a uu = *(const uint4a*)(ep + j + 4 * half);
      const unsigned u0 = uu.x, u1 = uu.y, u2 = uu.z, u3 = uu.w;
      const ushort2 x0 = *(const ushort2*)&x1u[(size_t)(u0 >> 16) * D64 + fl * 2];
      const ushort2 xa = *(const ushort2*)&x1u[(size_t)(u1 >> 16) * D64 + fl * 2];
      const ushort2 xb = *(const ushort2*)&x1u[(size_t)(u2 >> 16) * D64 + fl * 2];
      const ushort2 xc = *(const ushort2*)&x1u[(size_t)(u3 >> 16) * D64 + fl * 2];
      const float4 w0 = *(const float4*)&T2[(size_t)((u0 & 0xffffu) >> 5) * D64 + fl * 2];
      const float4 w1 = *(const float4*)&T2[(size_t)((u1 & 0xffffu) >> 5) * D64 + fl * 2];
      const float4 w2 = *(const float4*)&T2[(size_t)((u2 & 0xffffu) >> 5) * D64 + fl * 2];
      const float4 w3 = *(const float4*)&T2[(size_t)((u3 & 0xffffu) >> 5) * D64 + fl * 2];
      const float t0 = (float)(u0 & 31u) * 0.03125f;
      const float t1 = (float)(u1 & 31u) * 0.03125f;
      const float t2 = (float)(u2 & 31u) * 0.03125f;
      const float t3 = (float)(u3 & 31u) * 0.03125f;
      ax0 = fmaf(bx(x0.x), fmaf(t0, w0.y - w0.x, w0.x), ax0);
      ay0 = fmaf(bx(x0.y), fmaf(t0, w0.w - w0.z, w0.z), ay0);
      ax1 = fmaf(bx(xa.x), fmaf(t1, w1.y - w1.x, w1.x), ax1);
      ay1 = fmaf(bx(xa.y), fmaf(t1, w1.w - w1.z, w1.z), ay1);
      ax0 = fmaf(bx(xb.x), fmaf(t2, w2.y - w2.x, w2.x), ax0);
      ay0 = fmaf(bx(xb.y), fmaf(t2, w2.w - w2.z, w2.z), ay0);
      ax1 = fmaf(bx(xc.x), fmaf(t3, w3.y - w3.x, w3.x), ax1);
      ay1 = fmaf(bx(xc.y), fmaf(t3, w3.w - w3.z, w3.z), ay1);
    }
    for (; j + 2 <= j1; j += 2) {
      const unsigned u = ep[j + half];
      const ushort2 xr = *(const ushort2*)&x1u[(size_t)(u >> 16) * D64 + fl * 2];
      const float4 w4 = *(const float4*)&T2[(size_t)((u & 0xffffu) >> 5) * D64 + fl * 2];
      const float t = (float)(u & 31u) * 0.03125f;
      ax0 = fmaf(bx(xr.x), fmaf(t, w4.y - w4.x, w4.x), ax0);
      ay0 = fmaf(bx(xr.y), fmaf(t, w4.w - w4.z, w4.z), ay0);
    }
    if (j < j1 && half == 0) {   // odd leftover edge: half 0 only
      const unsigned u = ep[j];
      const ushort2 xr = *(const ushort2*)&x1u[(size_t)(u >> 16) * D64 + fl * 2];
      const float4 w4 = *(const float4*)&T2[(size_t)((u & 0xffffu) >> 5) * D64 + fl * 2];
      const float t = (float)(u & 31u) * 0.03125f;
      ax0 = fmaf(bx(xr.x), fmaf(t, w4.y - w4.x, w4.x), ax0);
      ay0 = fmaf(bx(xr.y), fmaf(t, w4.w - w4.z, w4.z), ay0);
    }
    float ax = ax0 + ax1, ay = ay0 + ay1;
    ax += __shfl_xor(ax, 32);
    ay += __shfl_xor(ay, 32);
    if (half == 0) {
      float2 o; o.x = ax; o.y = ay;
      *(float2*)&agg[(size_t)nd * D64 + fl * 2] = o;
    }
  }
}

// y = swish(agg@Wo1+bo1)@Wo2+bo2; feat = norm(feat) + y (prev-layer affine
// fused); per-feature sums into striped partials.  4-row chunks per wave.
__global__ __launch_bounds__(256) void k_out(const float* __restrict__ agg,
                                             const float* __restrict__ Wo1,
                                             const float* __restrict__ bo1,
                                             const float* __restrict__ Wo2,
                                             const float* __restrict__ bo2,
                                             const float* __restrict__ nstats,
                                             float* __restrict__ feat,
                                             float* __restrict__ part, int n) {
  __shared__ float w1t[D64 * 65];
  __shared__ float w2t[D64 * 65];
  __shared__ __align__(16) float rb[4][4][D64];
  const int lane = threadIdx.x & 63;
  const int wsl = threadIdx.x >> 6;
  const float sc = nstats[128 + lane], sh = nstats[192 + lane];
  for (int i = threadIdx.x; i < D64 * D64; i += 256) {
    int kk = i >> 6, d = i & 63;
    w1t[d * 65 + kk] = Wo1[i];
    w2t[d * 65 + kk] = Wo2[i];
  }
  __syncthreads();
  const float* wl1 = &w1t[lane * 65];
  const float* wl2 = &w2t[lane * 65];
  const float b1 = bo1[lane], b2 = bo2[lane];
  float sf = 0.0f, sf2 = 0.0f;
  const int wid = blockIdx.x * 4 + wsl;
  const int nw = gridDim.x * 4;
  int base = wid * 4;
  for (; base + 4 <= n; base += nw * 4) {
    float fv[4];
#pragma unroll
    for (int q = 0; q < 4; ++q)
      fv[q] = fmaf(feat[(size_t)(base + q) * D64 + lane], sc, sh);
#pragma unroll
    for (int q = 0; q < 4; ++q)
      rb[wsl][q][lane] = agg[(size_t)(base + q) * D64 + lane];
    float p[4][4];
#pragma unroll
    for (int q = 0; q < 4; ++q) { p[q][0] = b1; p[q][1] = 0; p[q][2] = 0; p[q][3] = 0; }
#pragma unroll
    for (int k4 = 0; k4 < 16; ++k4) {
      float4 w4 = *(const float4*)&wl1[k4 * 4];
#pragma unroll
      for (int q = 0; q < 4; ++q) {
        float4 a4 = *(const float4*)&rb[wsl][q][k4 * 4];
        p[q][0] = fmaf(a4.x, w4.x, p[q][0]);
        p[q][1] = fmaf(a4.y, w4.y, p[q][1]);
        p[q][2] = fmaf(a4.z, w4.z, p[q][2]);
        p[q][3] = fmaf(a4.w, w4.w, p[q][3]);
      }
    }
#pragma unroll
    for (int q = 0; q < 4; ++q)
      rb[wsl][q][lane] = swishf((p[q][0] + p[q][1]) + (p[q][2] + p[q][3]));
#pragma unroll
    for (int q = 0; q < 4; ++q) { p[q][0] = b2; p[q][1] = 0; p[q][2] = 0; p[q][3] = 0; }
#pragma unroll
    for (int k4 = 0; k4 < 16; ++k4) {
      float4 w4 = *(const float4*)&wl2[k4 * 4];
#pragma unroll
      for (int q = 0; q < 4; ++q) {
        float4 a4 = *(const float4*)&rb[wsl][q][k4 * 4];
        p[q][0] = fmaf(a4.x, w4.x, p[q][0]);
        p[q][1] = fmaf(a4.y, w4.y, p[q][1]);
        p[q][2] = fmaf(a4.z, w4.z, p[q][2]);
        p[q][3] = fmaf(a4.w, w4.w, p[q][3]);
      }
    }
#pragma unroll
    for (int q = 0; q < 4; ++q) {
      float fn = fv[q] + ((p[q][0] + p[q][1]) + (p[q][2] + p[q][3]));
      feat[(size_t)(base + q) * D64 + lane] = fn;
      sf += fn;
      sf2 += fn * fn;
    }
  }
  for (int row = base; row < n; ++row) {
    float fvs = fmaf(feat[(size_t)row * D64 + lane], sc, sh);
    rb[wsl][0][lane] = agg[(size_t)row * D64 + lane];
    float a0 = b1, a1 = 0, a2 = 0, a3 = 0;
#pragma unroll
    for (int k4 = 0; k4 < 16; ++k4) {
      float4 f4 = *(const float4*)&rb[wsl][0][k4 * 4];
      a0 = fmaf(f4.x, wl1[k4 * 4 + 0], a0);
      a1 = fmaf(f4.y, wl1[k4 * 4 + 1], a1);
      a2 = fmaf(f4.z, wl1[k4 * 4 + 2], a2);
      a3 = fmaf(f4.w, wl1[k4 * 4 + 3], a3);
    }
    rb[wsl][0][lane] = swishf((a0 + a1) + (a2 + a3));
    float q0 = b2, q1 = 0, q2 = 0, q3 = 0;
#pragma unroll
    for (int k4 = 0; k4 < 16; ++k4) {
      float4 f4 = *(const float4*)&rb[wsl][0][k4 * 4];
      q0 = fmaf(f4.x, wl2[k4 * 4 + 0], q0);
      q1 = fmaf(f4.y, wl2[k4 * 4 + 1], q1);
      q2 = fmaf(f4.z, wl2[k4 * 4 + 2], q2);
      q3 = fmaf(f4.w, wl2[k4 * 4 + 3], q3);
    }
    float fn = fvs + ((q0 + q1) + (q2 + q3));
    feat[(size_t)row * D64 + lane] = fn;
    sf += fn;
    sf2 += fn * fn;
  }
  const int slot = blockIdx.x & 63;
  atomAddF(&part[slot * 128 + lane], sf);
  atomAddF(&part[slot * 128 + 64 + lane], sf2);
}

// reduce striped partials; compute scale/shift. var = E[f^2] - (2a - a^2) mu^2
__global__ void k_nfin(const float* __restrict__ part, float* __restrict__ stats,
                       const float* __restrict__ al, const float* __restrict__ ga,
                       const float* __restrict__ be, int n) {
  __shared__ float red[128];
  const int t = threadIdx.x;  // 128 threads
  float s = 0.0f;
#pragma unroll 8
  for (int b = 0; b < 64; ++b) s += part[b * 128 + t];
  red[t] = s;
  __syncthreads();
  if (t < 64) {
    float invN = 1.0f / (float)n;
    float mu = red[t] * invN;
    float ex2 = red[64 + t] * invN;
    float a = al[t];
    float var = ex2 - (2.0f * a - a * a) * mu * mu;
    float sc = ga[t] * rsqrtf(var + 1e-5f);
    stats[128 + t] = sc;
    stats[192 + t] = be[t] - sc * a * mu;
  }
}

// apply the last layer's norm (materialize normalized feat) + column max
__global__ __launch_bounds__(256) void k_colmax(float* __restrict__ feat,
                                                const float* __restrict__ stats,
                                                unsigned* __restrict__ um, int n) {
  const int lane = threadIdx.x & 63;
  const int wid = (blockIdx.x * blockDim.x + threadIdx.x) >> 6;
  const int nw = (gridDim.x * blockDim.x) >> 6;
  const float sc = stats[128 + lane], sh = stats[192 + lane];
  float m = -3.402823e38f;
  for (int r = wid; r < n; r += nw) {
    float f = fmaf(feat[(size_t)r * D64 + lane], sc, sh);
    feat[(size_t)r * D64 + lane] = f;
    m = fmaxf(m, f);
  }
  atomicMax(&um[lane], fkey(m));
}

__global__ __launch_bounds__(256) void k_colsum(const float* __restrict__ feat,
                                                float* __restrict__ rd, int n) {
  const unsigned* um = (const unsigned*)rd;
  const int lane = threadIdx.x & 63;
  const int wid = (blockIdx.x * blockDim.x + threadIdx.x) >> 6;
  const int nw = (gridDim.x * blockDim.x) >> 6;
  const float mx = funkey(um[lane]);
  float s1 = 0.0f, s2 = 0.0f;
  for (int r = wid; r < n; r += nw) {
    float f = feat[(size_t)r * D64 + lane];
    float e = expf(f - mx);
    s1 += e;
    s2 += e * f;
  }
  atomAddF(&rd[64 + lane], s1);
  atomAddF(&rd[128 + lane], s2);
}

__global__ void k_pooled(const float* __restrict__ rd, float* __restrict__ out) {
  int d = threadIdx.x;
  if (d < D64) out[d] = rd[128 + d] / rd[64 + d];
}

extern "C" void kernel_launch(void* const* d_in, const int* in_sizes, int n_in,
                              void* d_out, int out_size, void* d_ws, size_t ws_size,
                              hipStream_t stream) {
  const int* z = (const int*)d_in[0];
  const int* src = (const int*)d_in[1];
  const int* dst = (const int*)d_in[2];
  const float* rij = (const float*)d_in[3];
  const float* emb = (const float*)d_in[4];
  const float* Win = (const float*)d_in[5];
  const float* Wf1 = (const float*)d_in[6];
  const float* bf1 = (const float*)d_in[7];
  const float* Wf2 = (const float*)d_in[8];
  const float* bf2 = (const float*)d_in[9];
  const float* Wo1 = (const float*)d_in[10];
  const float* bo1 = (const float*)d_in[11];
  const float* Wo2 = (const float*)d_in[12];
  const float* bo2 = (const float*)d_in[13];
  const float* gal = (const float*)d_in[14];
  const float* gga = (const float*)d_in[15];
  const float* gbe = (const float*)d_in[16];
  const int n = in_sizes[0];
  const int E = in_sizes[1];
  (void)n_in; (void)out_size; (void)ws_size;

  float* feat = (float*)d_out;                 // [n,64] lives in d_out
  float* pooled = feat + (size_t)n * D64;      // [64]

  char* w = (char*)d_ws;
  size_t off = 0;
  auto take = [&](size_t bytes) {
    size_t o = (off + 255) & ~(size_t)255;
    off = o + bytes;
    return (void*)(w + o);
  };
  __hip_bfloat16* x1 = (__hip_bfloat16*)take((size_t)n * D64 * 2);
  float* agg = (float*)take((size_t)n * D64 * 4);
  float* stats = (float*)take(256 * 4);
  float* part = (float*)take(64 * 128 * 4);
  float* rdst = (float*)take(192 * 4);
  float* T2 = (float*)take((size_t)3 * KTAB * D64 * 2 * 4);
  int* deg = (int*)take((size_t)n * 4);
  int* rp = (int*)take((size_t)(n + 1) * 4);
  int* cur = (int*)take((size_t)n * 4);
  unsigned* ep = (unsigned*)take((size_t)E * 4);

  hipMemsetAsync(deg, 0, (size_t)n * 4, stream);
  k_init<<<(n * D64 + 255) / 256, 256, 0, stream>>>(z, emb, feat, n * D64);
  k_hist<<<1024, 256, 0, stream>>>(dst, deg, E);
  k_scan<<<1, 1024, 0, stream>>>(deg, rp, cur, n);
  k_scatter<<<1024, 256, 0, stream>>>(src, dst, rij, cur, ep, E, n);
  k_tables<<<(3 * (KTAB + 1) + 3) / 4, 256, 0, stream>>>(Wf1, bf1, Wf2, bf2, T2);
  k_nid<<<1, 64, 0, stream>>>(stats);

  for (int l = 0; l < 3; ++l) {
    k_x1<<<2048, 256, 0, stream>>>(feat, Win + (size_t)l * D64 * D64, stats, x1, n);
    hipMemsetAsync(part, 0, 64 * 128 * 4, stream);
    k_gather<<<2048, 256, 0, stream>>>(x1, (const float2*)(T2 + (size_t)l * KTAB * D64 * 2),
                                       ep, rp, agg, n);
    k_out<<<2048, 256, 0, stream>>>(agg, Wo1 + (size_t)l * D64 * D64, bo1 + l * D64,
                                    Wo2 + (size_t)l * D64 * D64, bo2 + l * D64, stats,
                                    feat, part, n);
    k_nfin<<<1, 128, 0, stream>>>(part, stats, gal + l * D64, gga + l * D64, gbe + l * D64, n);
  }

  hipMemsetAsync(rdst, 0, 192 * 4, stream);
  k_colmax<<<512, 256, 0, stream>>>(feat, stats, (unsigned*)rdst, n);
  k_colsum<<<512, 256, 0, stream>>>(feat, rdst, n);
  k_pooled<<<1, 64, 0, stream>>>(rdst, pooled);
}

// Round 8
// 748.240 us; speedup vs baseline: 1.6759x; 1.0828x over previous
//
#include <hip/hip_runtime.h>
#include <hip/hip_bf16.h>
#include <math.h>

#define D64 64
#define KTAB 4096          // nearest-neighbor table intervals over r in [0,5]
#define TROWS (KTAB + 1)   // 4097 rows

typedef unsigned int uint4a __attribute__((ext_vector_type(4), aligned(4)));

// ---------------- helpers ----------------
__device__ __forceinline__ void atomAddF(float* p, float v) {
  __hip_atomic_fetch_add(p, v, __ATOMIC_RELAXED, __HIP_MEMORY_SCOPE_AGENT);
}
__device__ __forceinline__ unsigned fkey(float f) {
  unsigned u = __float_as_uint(f);
  return (u & 0x80000000u) ? ~u : (u | 0x80000000u);
}
__device__ __forceinline__ float funkey(unsigned k) {
  return __uint_as_float((k & 0x80000000u) ? (k & 0x7fffffffu) : ~k);
}
__device__ __forceinline__ float swishf(float x) { return x / (1.0f + expf(-x)); }
__device__ __forceinline__ float bx(unsigned short s) {
  return __uint_as_float((unsigned)s << 16);
}

// feat[i,d] = emb[z[i],d]
__global__ void k_init(const int* __restrict__ z, const float* __restrict__ emb,
                       float* __restrict__ feat, int total) {
  int idx = blockIdx.x * 256 + threadIdx.x;
  if (idx < total) feat[idx] = emb[z[idx >> 6] * D64 + (idx & 63)];
}

__global__ void k_hist(const int* __restrict__ dst, int* __restrict__ deg, int E) {
  for (int i = blockIdx.x * blockDim.x + threadIdx.x; i < E; i += gridDim.x * blockDim.x)
    atomicAdd(&deg[dst[i]], 1);
}

// single-block exclusive scan over deg[0..n) -> rp[0..n], also copies into cur
__global__ void k_scan(const int* __restrict__ deg, int* __restrict__ rp,
                       int* __restrict__ cur, int n) {
  __shared__ int sb[1024];
  __shared__ int carry_s;
  const int tid = threadIdx.x;
  if (tid == 0) carry_s = 0;
  __syncthreads();
  for (int base = 0; base < n; base += 4096) {
    int i0 = base + tid * 4;
    int v[4];
#pragma unroll
    for (int q = 0; q < 4; ++q) { int i = i0 + q; v[q] = (i < n) ? deg[i] : 0; }
    int s = v[0] + v[1] + v[2] + v[3];
    sb[tid] = s;
    __syncthreads();
    for (int o = 1; o < 1024; o <<= 1) {
      int t = (tid >= o) ? sb[tid - o] : 0;
      __syncthreads();
      sb[tid] += t;
      __syncthreads();
    }
    int incl = sb[tid];
    int carry = carry_s;
    int excl = carry + incl - s;
#pragma unroll
    for (int q = 0; q < 4; ++q) {
      int i = i0 + q;
      if (i < n) { rp[i] = excl; cur[i] = excl; }
      excl += v[q];
    }
    __syncthreads();
    if (tid == 1023) carry_s = carry + incl;
    __syncthreads();
  }
  if (tid == 0) rp[n] = carry_s;
}

// bucket b covers nodes [b*1024, (b+1)*1024); bases come free from rp.
__global__ void k_bbase(const int* __restrict__ rp, int* __restrict__ bbase,
                        int* __restrict__ gcur, int n) {
  int b = threadIdx.x;
  if (b <= 64) {
    int node = b << 10;
    if (node > n) node = n;
    int v = rp[node];
    bbase[b] = v;
    if (b < 64) gcur[b] = v;
  }
}

// Phase 1 of the CSR build: partition edges into 64 dst-range buckets with
// LDS counting-sort per 2048-edge chunk, then contiguous chunked copy-out
// (avg ~42-entry runs = full-line writes; no partial-line thrash).
// rec = {dst, src<<16 | k13} where k13 = round(r * KTAB/5).
__global__ __launch_bounds__(256) void k_part(const int* __restrict__ src,
                                              const int* __restrict__ dst,
                                              const float* __restrict__ rij,
                                              int* __restrict__ gcur,
                                              uint2* __restrict__ rec, int E) {
  __shared__ uint2 ord[2048];
  __shared__ unsigned char obk[2048];
  __shared__ int cnt[64], cbase[64], cpos[64], gpos[64];
  __shared__ int tot_s;
  const int tid = threadIdx.x;
  for (int c = blockIdx.x; c * 2048 < E; c += gridDim.x) {
    const int s0 = c * 2048;
    if (tid < 64) cnt[tid] = 0;
    __syncthreads();
    const int i0 = s0 + tid * 8;
    int dd[8], ss[8];
    float rr[8];
    bool val[8];
    if (i0 + 8 <= E) {
      int4 d0 = *(const int4*)&dst[i0];
      int4 d1 = *(const int4*)&dst[i0 + 4];
      int4 sa = *(const int4*)&src[i0];
      int4 sb2 = *(const int4*)&src[i0 + 4];
      float4 r0 = *(const float4*)&rij[i0];
      float4 r1 = *(const float4*)&rij[i0 + 4];
      dd[0] = d0.x; dd[1] = d0.y; dd[2] = d0.z; dd[3] = d0.w;
      dd[4] = d1.x; dd[5] = d1.y; dd[6] = d1.z; dd[7] = d1.w;
      ss[0] = sa.x; ss[1] = sa.y; ss[2] = sa.z; ss[3] = sa.w;
      ss[4] = sb2.x; ss[5] = sb2.y; ss[6] = sb2.z; ss[7] = sb2.w;
      rr[0] = r0.x; rr[1] = r0.y; rr[2] = r0.z; rr[3] = r0.w;
      rr[4] = r1.x; rr[5] = r1.y; rr[6] = r1.z; rr[7] = r1.w;
#pragma unroll
      for (int q = 0; q < 8; ++q) val[q] = true;
    } else {
#pragma unroll
      for (int q = 0; q < 8; ++q) {
        int i = i0 + q;
        val[q] = (i < E);
        if (val[q]) { dd[q] = dst[i]; ss[q] = src[i]; rr[q] = rij[i]; }
        else { dd[q] = 0; ss[q] = 0; rr[q] = 0.0f; }
      }
    }
    int bk[8];
    unsigned ry[8];
#pragma unroll
    for (int q = 0; q < 8; ++q) {
      bk[q] = dd[q] >> 10;
      int k = (int)(rr[q] * ((float)KTAB * 0.2f) + 0.5f);
      if (k > KTAB) k = KTAB;
      ry[q] = ((unsigned)ss[q] << 16) | (unsigned)k;
      if (val[q]) atomicAdd(&cnt[bk[q]], 1);
    }
    __syncthreads();
    if (tid < 64) {
      int v = cnt[tid];
      int x = v;
      for (int o = 1; o < 64; o <<= 1) {
        int y = __shfl_up(x, o);
        if (tid >= o) x += y;
      }
      cbase[tid] = x - v;
      cpos[tid] = x - v;
      if (tid == 63) tot_s = x;
    }
    __syncthreads();
#pragma unroll
    for (int q = 0; q < 8; ++q) {
      if (val[q]) {
        int slot = atomicAdd(&cpos[bk[q]], 1);
        ord[slot] = make_uint2((unsigned)dd[q], ry[q]);
        obk[slot] = (unsigned char)bk[q];
      }
    }
    __syncthreads();
    if (tid < 64 && cnt[tid] > 0) gpos[tid] = atomicAdd(&gcur[tid], cnt[tid]);
    __syncthreads();
    const int tot = tot_s;
    for (int t = tid; t < tot; t += 256) {
      int b2 = obk[t];
      rec[gpos[b2] + (t - cbase[b2])] = ord[t];
    }
    __syncthreads();
  }
}

// Phase 2: per bucket (8 blocks, all on one XCD since blockIdx%8 == b%8),
// sequential-read the bucket's records and place ep entries in a ~130KB
// L2-resident window.
__global__ __launch_bounds__(256) void k_place(const uint2* __restrict__ rec,
                                               const int* __restrict__ bbase,
                                               int* __restrict__ cur,
                                               unsigned* __restrict__ ep) {
  const int b = blockIdx.x & 63;
  const int sub = blockIdx.x >> 6;
  const int lo = bbase[b], hi = bbase[b + 1];
  for (int i = lo + sub * 256 + threadIdx.x; i < hi; i += 8 * 256) {
    uint2 e = rec[i];
    int pos = atomicAdd(&cur[e.x], 1);
    ep[pos] = e.y;
  }
}

// bf16 nearest-neighbor table: Tb[l][g][d] = bf16(W(r_g)[d] * C(r_g)).
// Weights staged in LDS once per block; each block covers 32 grid points.
__global__ __launch_bounds__(256) void k_tables(const float* __restrict__ Wf1,
                                                const float* __restrict__ bf1,
                                                const float* __restrict__ Wf2,
                                                const float* __restrict__ bf2,
                                                __hip_bfloat16* __restrict__ Tb) {
  __shared__ float w1[25 * D64];
  __shared__ float w2[D64 * D64];
  __shared__ float rb[4][D64];
  const int lane = threadIdx.x & 63;
  const int wsl = threadIdx.x >> 6;
  const int l = blockIdx.x / 129;
  const int gb = blockIdx.x % 129;
  for (int i = threadIdx.x; i < 25 * D64; i += 256) w1[i] = Wf1[l * 25 * D64 + i];
  for (int i = threadIdx.x; i < D64 * D64; i += 256) w2[i] = Wf2[l * D64 * D64 + i];
  __syncthreads();
  const float bias1 = bf1[l * D64 + lane];
  const float bias2 = bf2[l * D64 + lane];
  const float width = 5.0f / 24.0f;
  const float coeff = -0.5f / (width * width);
  for (int gi = 0; gi < 8; ++gi) {
    const int g = gb * 32 + wsl * 8 + gi;
    if (g >= TROWS) break;
    const float r = (float)g * (5.0f / KTAB);
    float fv = 0.0f;
    if (lane < 25) { float ddv = r - (float)lane * width; fv = expf(coeff * ddv * ddv); }
    rb[wsl][lane] = fv;   // same-wave LDS reuse; program order preserves deps
    float a1 = bias1;
#pragma unroll
    for (int b = 0; b < 25; ++b)
      a1 = fmaf(rb[wsl][b], w1[b * D64 + lane], a1);
    float sw = swishf(a1);
    rb[wsl][lane] = sw;
    float a2 = bias2;
#pragma unroll
    for (int k = 0; k < D64; ++k)
      a2 = fmaf(rb[wsl][k], w2[k * D64 + lane], a2);
    float C = (r < 5.0f) ? 0.5f * (cosf(r * 0.62831853f) + 1.0f) : 0.0f;
    Tb[(size_t)(l * TROWS + g) * D64 + lane] = __float2bfloat16(a2 * C);
  }
}

// identity norm for layer 0
__global__ void k_nid(float* __restrict__ stats) {
  int d = threadIdx.x;
  stats[128 + d] = 1.0f;
  stats[192 + d] = 0.0f;
}

// x1 = bf16(norm(feat) @ Win).  napp fused; 4-row chunks per wave; weight
// columns in LDS (65-float pitch, conflict-free).
__global__ __launch_bounds__(256) void k_x1(const float* __restrict__ feat,
                                            const float* __restrict__ Win,
                                            const float* __restrict__ stats,
                                            __hip_bfloat16* __restrict__ x1, int n) {
  __shared__ float wlds[D64 * 65];
  __shared__ __align__(16) float rb[4][4][D64];
  const int lane = threadIdx.x & 63;
  const int wsl = threadIdx.x >> 6;
  const float sc = stats[128 + lane], sh = stats[192 + lane];
  for (int i = threadIdx.x; i < D64 * D64; i += 256) {
    int kk = i >> 6, d = i & 63;
    wlds[d * 65 + kk] = Win[i];
  }
  __syncthreads();
  const float* wl = &wlds[lane * 65];
  const int wid = blockIdx.x * 4 + wsl;
  const int nw = gridDim.x * 4;
  int base = wid * 4;
  for (; base + 4 <= n; base += nw * 4) {
#pragma unroll
    for (int q = 0; q < 4; ++q)
      rb[wsl][q][lane] = fmaf(feat[(size_t)(base + q) * D64 + lane], sc, sh);
    float p[4][4];
#pragma unroll
    for (int q = 0; q < 4; ++q) { p[q][0] = 0; p[q][1] = 0; p[q][2] = 0; p[q][3] = 0; }
#pragma unroll
    for (int k4 = 0; k4 < 16; ++k4) {
      float4 w4 = *(const float4*)&wl[k4 * 4];
#pragma unroll
      for (int q = 0; q < 4; ++q) {
        float4 a4 = *(const float4*)&rb[wsl][q][k4 * 4];
        p[q][0] = fmaf(a4.x, w4.x, p[q][0]);
        p[q][1] = fmaf(a4.y, w4.y, p[q][1]);
        p[q][2] = fmaf(a4.z, w4.z, p[q][2]);
        p[q][3] = fmaf(a4.w, w4.w, p[q][3]);
      }
    }
#pragma unroll
    for (int q = 0; q < 4; ++q)
      x1[(size_t)(base + q) * D64 + lane] =
          __float2bfloat16((p[q][0] + p[q][1]) + (p[q][2] + p[q][3]));
  }
  for (int row = base; row < n; ++row) {
    rb[wsl][0][lane] = fmaf(feat[(size_t)row * D64 + lane], sc, sh);
    float a0 = 0, a1 = 0, a2 = 0, a3 = 0;
#pragma unroll
    for (int k4 = 0; k4 < 16; ++k4) {
      float4 f4 = *(const float4*)&rb[wsl][0][k4 * 4];
      a0 = fmaf(f4.x, wl[k4 * 4 + 0], a0);
      a1 = fmaf(f4.y, wl[k4 * 4 + 1], a1);
      a2 = fmaf(f4.z, wl[k4 * 4 + 2], a2);
      a3 = fmaf(f4.w, wl[k4 * 4 + 3], a3);
    }
    x1[(size_t)row * D64 + lane] = __float2bfloat16((a0 + a1) + (a2 + a3));
  }
}

// agg[nd] = sum over incoming edges of x1[src] * Tb[k].
// Half-wave edge pairing + dwordx4 ep loads + NEAREST bf16 table: per edge
// only 128B x1 + 128B T from L2 (was 128+512 with fp32 lerp pairs).
__global__ __launch_bounds__(256) void k_gather(const __hip_bfloat16* __restrict__ x1,
                                                const __hip_bfloat16* __restrict__ Tb,
                                                const unsigned* __restrict__ ep,
                                                const int* __restrict__ rp,
                                                float* __restrict__ agg, int n) {
  const int lane = threadIdx.x & 63;
  const int half = lane >> 5;
  const int fl = lane & 31;            // features 2*fl, 2*fl+1
  const unsigned short* __restrict__ x1u = (const unsigned short*)x1;
  const unsigned short* __restrict__ Tu = (const unsigned short*)Tb;
  const int wid = (blockIdx.x * blockDim.x + threadIdx.x) >> 6;
  const int nw = (gridDim.x * blockDim.x) >> 6;
  for (int nd = wid; nd < n; nd += nw) {
    const int j0 = rp[nd], j1 = rp[nd + 1];
    float ax0 = 0.0f, ay0 = 0.0f, ax1 = 0.0f, ay1 = 0.0f;
    int j = j0;
    for (; j + 8 <= j1; j += 8) {
      const uint4a uu = *(const uint4a*)(ep + j + 4 * half);
      const unsigned u0 = uu.x, u1 = uu.y, u2 = uu.z, u3 = uu.w;
      const ushort2 xA = *(const ushort2*)&x1u[(size_t)(u0 >> 16) * D64 + fl * 2];
      const ushort2 xB = *(const ushort2*)&x1u[(size_t)(u1 >> 16) * D64 + fl * 2];
      const ushort2 xC = *(const ushort2*)&x1u[(size_t)(u2 >> 16) * D64 + fl * 2];
      const ushort2 xD = *(const ushort2*)&x1u[(size_t)(u3 >> 16) * D64 + fl * 2];
      const ushort2 tA = *(const ushort2*)&Tu[(size_t)(u0 & 0x1FFFu) * D64 + fl * 2];
      const ushort2 tB = *(const ushort2*)&Tu[(size_t)(u1 & 0x1FFFu) * D64 + fl * 2];
      const ushort2 tC = *(const ushort2*)&Tu[(size_t)(u2 & 0x1FFFu) * D64 + fl * 2];
      const ushort2 tD = *(const ushort2*)&Tu[(size_t)(u3 & 0x1FFFu) * D64 + fl * 2];
      ax0 = fmaf(bx(xA.x), bx(tA.x), ax0);
      ay0 = fmaf(bx(xA.y), bx(tA.y), ay0);
      ax1 = fmaf(bx(xB.x), bx(tB.x), ax1);
      ay1 = fmaf(bx(xB.y), bx(tB.y), ay1);
      ax0 = fmaf(bx(xC.x), bx(tC.x), ax0);
      ay0 = fmaf(bx(xC.y), bx(tC.y), ay0);
      ax1 = fmaf(bx(xD.x), bx(tD.x), ax1);
      ay1 = fmaf(bx(xD.y), bx(tD.y), ay1);
    }
    for (; j + 2 <= j1; j += 2) {
      const unsigned u = ep[j + half];
      const ushort2 xr = *(const ushort2*)&x1u[(size_t)(u >> 16) * D64 + fl * 2];
      const ushort2 tw = *(const ushort2*)&Tu[(size_t)(u & 0x1FFFu) * D64 + fl * 2];
      ax0 = fmaf(bx(xr.x), bx(tw.x), ax0);
      ay0 = fmaf(bx(xr.y), bx(tw.y), ay0);
    }
    if (j < j1 && half == 0) {   // odd leftover edge: half 0 only
      const unsigned u = ep[j];
      const ushort2 xr = *(const ushort2*)&x1u[(size_t)(u >> 16) * D64 + fl * 2];
      const ushort2 tw = *(const ushort2*)&Tu[(size_t)(u & 0x1FFFu) * D64 + fl * 2];
      ax0 = fmaf(bx(xr.x), bx(tw.x), ax0);
      ay0 = fmaf(bx(xr.y), bx(tw.y), ay0);
    }
    float ax = ax0 + ax1, ay = ay0 + ay1;
    ax += __shfl_xor(ax, 32);
    ay += __shfl_xor(ay, 32);
    if (half == 0) {
      float2 o; o.x = ax; o.y = ay;
      *(float2*)&agg[(size_t)nd * D64 + fl * 2] = o;
    }
  }
}

// y = swish(agg@Wo1+bo1)@Wo2+bo2; feat = norm(feat) + y (prev-layer affine
// fused); per-feature sums into striped partials.  4-row chunks per wave.
__global__ __launch_bounds__(256) void k_out(const float* __restrict__ agg,
                                             const float* __restrict__ Wo1,
                                             const float* __restrict__ bo1,
                                             const float* __restrict__ Wo2,
                                             const float* __restrict__ bo2,
                                             const float* __restrict__ nstats,
                                             float* __restrict__ feat,
                                             float* __restrict__ part, int n) {
  __shared__ float w1t[D64 * 65];
  __shared__ float w2t[D64 * 65];
  __shared__ __align__(16) float rb[4][4][D64];
  const int lane = threadIdx.x & 63;
  const int wsl = threadIdx.x >> 6;
  const float sc = nstats[128 + lane], sh = nstats[192 + lane];
  for (int i = threadIdx.x; i < D64 * D64; i += 256) {
    int kk = i >> 6, d = i & 63;
    w1t[d * 65 + kk] = Wo1[i];
    w2t[d * 65 + kk] = Wo2[i];
  }
  __syncthreads();
  const float* wl1 = &w1t[lane * 65];
  const float* wl2 = &w2t[lane * 65];
  const float b1 = bo1[lane], b2 = bo2[lane];
  float sf = 0.0f, sf2 = 0.0f;
  const int wid = blockIdx.x * 4 + wsl;
  const int nw = gridDim.x * 4;
  int base = wid * 4;
  for (; base + 4 <= n; base += nw * 4) {
    float fv[4];
#pragma unroll
    for (int q = 0; q < 4; ++q)
      fv[q] = fmaf(feat[(size_t)(base + q) * D64 + lane], sc, sh);
#pragma unroll
    for (int q = 0; q < 4; ++q)
      rb[wsl][q][lane] = agg[(size_t)(base + q) * D64 + lane];
    float p[4][4];
#pragma unroll
    for (int q = 0; q < 4; ++q) { p[q][0] = b1; p[q][1] = 0; p[q][2] = 0; p[q][3] = 0; }
#pragma unroll
    for (int k4 = 0; k4 < 16; ++k4) {
      float4 w4 = *(const float4*)&wl1[k4 * 4];
#pragma unroll
      for (int q = 0; q < 4; ++q) {
        float4 a4 = *(const float4*)&rb[wsl][q][k4 * 4];
        p[q][0] = fmaf(a4.x, w4.x, p[q][0]);
        p[q][1] = fmaf(a4.y, w4.y, p[q][1]);
        p[q][2] = fmaf(a4.z, w4.z, p[q][2]);
        p[q][3] = fmaf(a4.w, w4.w, p[q][3]);
      }
    }
#pragma unroll
    for (int q = 0; q < 4; ++q)
      rb[wsl][q][lane] = swishf((p[q][0] + p[q][1]) + (p[q][2] + p[q][3]));
#pragma unroll
    for (int q = 0; q < 4; ++q) { p[q][0] = b2; p[q][1] = 0; p[q][2] = 0; p[q][3] = 0; }
#pragma unroll
    for (int k4 = 0; k4 < 16; ++k4) {
      float4 w4 = *(const float4*)&wl2[k4 * 4];
#pragma unroll
      for (int q = 0; q < 4; ++q) {
        float4 a4 = *(const float4*)&rb[wsl][q][k4 * 4];
        p[q][0] = fmaf(a4.x, w4.x, p[q][0]);
        p[q][1] = fmaf(a4.y, w4.y, p[q][1]);
        p[q][2] = fmaf(a4.z, w4.z, p[q][2]);
        p[q][3] = fmaf(a4.w, w4.w, p[q][3]);
      }
    }
#pragma unroll
    for (int q = 0; q < 4; ++q) {
      float fn = fv[q] + ((p[q][0] + p[q][1]) + (p[q][2] + p[q][3]));
      feat[(size_t)(base + q) * D64 + lane] = fn;
      sf += fn;
      sf2 += fn * fn;
    }
  }
  for (int row = base; row < n; ++row) {
    float fvs = fmaf(feat[(size_t)row * D64 + lane], sc, sh);
    rb[wsl][0][lane] = agg[(size_t)row * D64 + lane];
    float a0 = b1, a1 = 0, a2 = 0, a3 = 0;
#pragma unroll
    for (int k4 = 0; k4 < 16; ++k4) {
      float4 f4 = *(const float4*)&rb[wsl][0][k4 * 4];
      a0 = fmaf(f4.x, wl1[k4 * 4 + 0], a0);
      a1 = fmaf(f4.y, wl1[k4 * 4 + 1], a1);
      a2 = fmaf(f4.z, wl1[k4 * 4 + 2], a2);
      a3 = fmaf(f4.w, wl1[k4 * 4 + 3], a3);
    }
    rb[wsl][0][lane] = swishf((a0 + a1) + (a2 + a3));
    float q0 = b2, q1 = 0, q2 = 0, q3 = 0;
#pragma unroll
    for (int k4 = 0; k4 < 16; ++k4) {
      float4 f4 = *(const float4*)&rb[wsl][0][k4 * 4];
      q0 = fmaf(f4.x, wl2[k4 * 4 + 0], q0);
      q1 = fmaf(f4.y, wl2[k4 * 4 + 1], q1);
      q2 = fmaf(f4.z, wl2[k4 * 4 + 2], q2);
      q3 = fmaf(f4.w, wl2[k4 * 4 + 3], q3);
    }
    float fn = fvs + ((q0 + q1) + (q2 + q3));
    feat[(size_t)row * D64 + lane] = fn;
    sf += fn;
    sf2 += fn * fn;
  }
  const int slot = blockIdx.x & 63;
  atomAddF(&part[slot * 128 + lane], sf);
  atomAddF(&part[slot * 128 + 64 + lane], sf2);
}

// reduce striped partials; compute scale/shift. var = E[f^2] - (2a - a^2) mu^2
__global__ void k_nfin(const float* __restrict__ part, float* __restrict__ stats,
                       const float* __restrict__ al, const float* __restrict__ ga,
                       const float* __restrict__ be, int n) {
  __shared__ float red[128];
  const int t = threadIdx.x;  // 128 threads
  float s = 0.0f;
#pragma unroll 8
  for (int b = 0; b < 64; ++b) s += part[b * 128 + t];
  red[t] = s;
  __syncthreads();
  if (t < 64) {
    float invN = 1.0f / (float)n;
    float mu = red[t] * invN;
    float ex2 = red[64 + t] * invN;
    float a = al[t];
    float var = ex2 - (2.0f * a - a * a) * mu * mu;
    float sc = ga[t] * rsqrtf(var + 1e-5f);
    stats[128 + t] = sc;
    stats[192 + t] = be[t] - sc * a * mu;
  }
}

// apply the last layer's norm (materialize normalized feat) + column max
__global__ __launch_bounds__(256) void k_colmax(float* __restrict__ feat,
                                                const float* __restrict__ stats,
                                                unsigned* __restrict__ um, int n) {
  const int lane = threadIdx.x & 63;
  const int wid = (blockIdx.x * blockDim.x + threadIdx.x) >> 6;
  const int nw = (gridDim.x * blockDim.x) >> 6;
  const float sc = stats[128 + lane], sh = stats[192 + lane];
  float m = -3.402823e38f;
  for (int r = wid; r < n; r += nw) {
    float f = fmaf(feat[(size_t)r * D64 + lane], sc, sh);
    feat[(size_t)r * D64 + lane] = f;
    m = fmaxf(m, f);
  }
  atomicMax(&um[lane], fkey(m));
}

__global__ __launch_bounds__(256) void k_colsum(const float* __restrict__ feat,
                                                float* __restrict__ rd, int n) {
  const unsigned* um = (const unsigned*)rd;
  const int lane = threadIdx.x & 63;
  const int wid = (blockIdx.x * blockDim.x + threadIdx.x) >> 6;
  const int nw = (gridDim.x * blockDim.x) >> 6;
  const float mx = funkey(um[lane]);
  float s1 = 0.0f, s2 = 0.0f;
  for (int r = wid; r < n; r += nw) {
    float f = feat[(size_t)r * D64 + lane];
    float e = expf(f - mx);
    s1 += e;
    s2 += e * f;
  }
  atomAddF(&rd[64 + lane], s1);
  atomAddF(&rd[128 + lane], s2);
}

__global__ void k_pooled(const float* __restrict__ rd, float* __restrict__ out) {
  int d = threadIdx.x;
  if (d < D64) out[d] = rd[128 + d] / rd[64 + d];
}

extern "C" void kernel_launch(void* const* d_in, const int* in_sizes, int n_in,
                              void* d_out, int out_size, void* d_ws, size_t ws_size,
                              hipStream_t stream) {
  const int* z = (const int*)d_in[0];
  const int* src = (const int*)d_in[1];
  const int* dst = (const int*)d_in[2];
  const float* rij = (const float*)d_in[3];
  const float* emb = (const float*)d_in[4];
  const float* Win = (const float*)d_in[5];
  const float* Wf1 = (const float*)d_in[6];
  const float* bf1 = (const float*)d_in[7];
  const float* Wf2 = (const float*)d_in[8];
  const float* bf2 = (const float*)d_in[9];
  const float* Wo1 = (const float*)d_in[10];
  const float* bo1 = (const float*)d_in[11];
  const float* Wo2 = (const float*)d_in[12];
  const float* bo2 = (const float*)d_in[13];
  const float* gal = (const float*)d_in[14];
  const float* gga = (const float*)d_in[15];
  const float* gbe = (const float*)d_in[16];
  const int n = in_sizes[0];
  const int E = in_sizes[1];
  (void)n_in; (void)out_size; (void)ws_size;

  float* feat = (float*)d_out;                 // [n,64] lives in d_out
  float* pooled = feat + (size_t)n * D64;      // [64]

  char* w = (char*)d_ws;
  size_t off = 0;
  auto take = [&](size_t bytes) {
    size_t o = (off + 255) & ~(size_t)255;
    off = o + bytes;
    return (void*)(w + o);
  };
  __hip_bfloat16* x1 = (__hip_bfloat16*)take((size_t)n * D64 * 2);
  size_t aggrec = ((size_t)n * D64 * 4 > (size_t)E * 8) ? (size_t)n * D64 * 4
                                                        : (size_t)E * 8;
  float* agg = (float*)take(aggrec);           // aliased with rec (disjoint lifetimes)
  uint2* rec = (uint2*)agg;
  float* stats = (float*)take(256 * 4);
  float* part = (float*)take(64 * 128 * 4);
  float* rdst = (float*)take(192 * 4);
  __hip_bfloat16* Tb = (__hip_bfloat16*)take((size_t)3 * TROWS * D64 * 2);
  int* deg = (int*)take((size_t)n * 4);
  int* rp = (int*)take((size_t)(n + 1) * 4);
  int* cur = (int*)take((size_t)n * 4);
  unsigned* ep = (unsigned*)take((size_t)E * 4);
  int* bbase = (int*)take(65 * 4);
  int* gcur = (int*)take(64 * 4);

  hipMemsetAsync(deg, 0, (size_t)n * 4, stream);
  k_init<<<(n * D64 + 255) / 256, 256, 0, stream>>>(z, emb, feat, n * D64);
  k_hist<<<1024, 256, 0, stream>>>(dst, deg, E);
  k_scan<<<1, 1024, 0, stream>>>(deg, rp, cur, n);
  k_bbase<<<1, 128, 0, stream>>>(rp, bbase, gcur, n);
  k_part<<<784, 256, 0, stream>>>(src, dst, rij, gcur, rec, E);
  k_place<<<512, 256, 0, stream>>>(rec, bbase, cur, ep);
  k_tables<<<3 * 129, 256, 0, stream>>>(Wf1, bf1, Wf2, bf2, Tb);
  k_nid<<<1, 64, 0, stream>>>(stats);

  for (int l = 0; l < 3; ++l) {
    k_x1<<<2048, 256, 0, stream>>>(feat, Win + (size_t)l * D64 * D64, stats, x1, n);
    hipMemsetAsync(part, 0, 64 * 128 * 4, stream);
    k_gather<<<2048, 256, 0, stream>>>(x1, Tb + (size_t)l * TROWS * D64,
                                       ep, rp, agg, n);
    k_out<<<2048, 256, 0, stream>>>(agg, Wo1 + (size_t)l * D64 * D64, bo1 + l * D64,
                                    Wo2 + (size_t)l * D64 * D64, bo2 + l * D64, stats,
                                    feat, part, n);
    k_nfin<<<1, 128, 0, stream>>>(part, stats, gal + l * D64, gga + l * D64, gbe + l * D64, n);
  }

  hipMemsetAsync(rdst, 0, 192 * 4, stream);
  k_colmax<<<512, 256, 0, stream>>>(feat, stats, (unsigned*)rdst, n);
  k_colsum<<<512, 256, 0, stream>>>(feat, rdst, n);
  k_pooled<<<1, 64, 0, stream>>>(rdst, pooled);
}

// Round 9
// 563.982 us; speedup vs baseline: 2.2235x; 1.3267x over previous
//
#include <hip/hip_runtime.h>
#include <hip/hip_bf16.h>
#include <math.h>

#define D64 64
#define KTAB 4096          // nearest-neighbor table intervals over r in [0,5]
#define TROWS (KTAB + 1)   // 4097 rows

typedef unsigned int uint4a __attribute__((ext_vector_type(4), aligned(4)));
typedef __attribute__((ext_vector_type(8))) short bf16x8;   // 8 bf16 (4 VGPRs)
typedef __attribute__((ext_vector_type(4))) float f32x4;    // MFMA C/D frag

// ---------------- helpers ----------------
__device__ __forceinline__ void atomAddF(float* p, float v) {
  __hip_atomic_fetch_add(p, v, __ATOMIC_RELAXED, __HIP_MEMORY_SCOPE_AGENT);
}
__device__ __forceinline__ unsigned fkey(float f) {
  unsigned u = __float_as_uint(f);
  return (u & 0x80000000u) ? ~u : (u | 0x80000000u);
}
__device__ __forceinline__ float funkey(unsigned k) {
  return __uint_as_float((k & 0x80000000u) ? (k & 0x7fffffffu) : ~k);
}
__device__ __forceinline__ float swishf(float x) { return x / (1.0f + expf(-x)); }
__device__ __forceinline__ float bx(unsigned short s) {
  return __uint_as_float((unsigned)s << 16);
}
// fp32 -> bf16 bits, round-to-nearest-even (finite inputs)
__device__ __forceinline__ unsigned short f2b(float f) {
  unsigned u = __float_as_uint(f);
  return (unsigned short)((u + 0x7FFFu + ((u >> 16) & 1u)) >> 16);
}

// feat[i,d] = emb[z[i],d]
__global__ void k_init(const int* __restrict__ z, const float* __restrict__ emb,
                       float* __restrict__ feat, int total) {
  int idx = blockIdx.x * 256 + threadIdx.x;
  if (idx < total) feat[idx] = emb[z[idx >> 6] * D64 + (idx & 63)];
}

__global__ void k_hist(const int* __restrict__ dst, int* __restrict__ deg, int E) {
  for (int i = blockIdx.x * blockDim.x + threadIdx.x; i < E; i += gridDim.x * blockDim.x)
    atomicAdd(&deg[dst[i]], 1);
}

// single-block exclusive scan over deg[0..n) -> rp[0..n], also copies into cur
__global__ void k_scan(const int* __restrict__ deg, int* __restrict__ rp,
                       int* __restrict__ cur, int n) {
  __shared__ int sb[1024];
  __shared__ int carry_s;
  const int tid = threadIdx.x;
  if (tid == 0) carry_s = 0;
  __syncthreads();
  for (int base = 0; base < n; base += 4096) {
    int i0 = base + tid * 4;
    int v[4];
#pragma unroll
    for (int q = 0; q < 4; ++q) { int i = i0 + q; v[q] = (i < n) ? deg[i] : 0; }
    int s = v[0] + v[1] + v[2] + v[3];
    sb[tid] = s;
    __syncthreads();
    for (int o = 1; o < 1024; o <<= 1) {
      int t = (tid >= o) ? sb[tid - o] : 0;
      __syncthreads();
      sb[tid] += t;
      __syncthreads();
    }
    int incl = sb[tid];
    int carry = carry_s;
    int excl = carry + incl - s;
#pragma unroll
    for (int q = 0; q < 4; ++q) {
      int i = i0 + q;
      if (i < n) { rp[i] = excl; cur[i] = excl; }
      excl += v[q];
    }
    __syncthreads();
    if (tid == 1023) carry_s = carry + incl;
    __syncthreads();
  }
  if (tid == 0) rp[n] = carry_s;
}

// bucket b covers nodes [b*1024, (b+1)*1024); bases come free from rp.
__global__ void k_bbase(const int* __restrict__ rp, int* __restrict__ bbase,
                        int* __restrict__ gcur, int n) {
  int b = threadIdx.x;
  if (b <= 64) {
    int node = b << 10;
    if (node > n) node = n;
    int v = rp[node];
    bbase[b] = v;
    if (b < 64) gcur[b] = v;
  }
}

// Phase 1 of CSR build: LDS counting-sort per 2048-edge chunk into 64 dst-range
// buckets, contiguous chunked copy-out (full-line writes).
__global__ __launch_bounds__(256) void k_part(const int* __restrict__ src,
                                              const int* __restrict__ dst,
                                              const float* __restrict__ rij,
                                              int* __restrict__ gcur,
                                              uint2* __restrict__ rec, int E) {
  __shared__ uint2 ord[2048];
  __shared__ unsigned char obk[2048];
  __shared__ int cnt[64], cbase[64], cpos[64], gpos[64];
  __shared__ int tot_s;
  const int tid = threadIdx.x;
  for (int c = blockIdx.x; c * 2048 < E; c += gridDim.x) {
    const int s0 = c * 2048;
    if (tid < 64) cnt[tid] = 0;
    __syncthreads();
    const int i0 = s0 + tid * 8;
    int dd[8], ss[8];
    float rr[8];
    bool val[8];
    if (i0 + 8 <= E) {
      int4 d0 = *(const int4*)&dst[i0];
      int4 d1 = *(const int4*)&dst[i0 + 4];
      int4 sa = *(const int4*)&src[i0];
      int4 sb2 = *(const int4*)&src[i0 + 4];
      float4 r0 = *(const float4*)&rij[i0];
      float4 r1 = *(const float4*)&rij[i0 + 4];
      dd[0] = d0.x; dd[1] = d0.y; dd[2] = d0.z; dd[3] = d0.w;
      dd[4] = d1.x; dd[5] = d1.y; dd[6] = d1.z; dd[7] = d1.w;
      ss[0] = sa.x; ss[1] = sa.y; ss[2] = sa.z; ss[3] = sa.w;
      ss[4] = sb2.x; ss[5] = sb2.y; ss[6] = sb2.z; ss[7] = sb2.w;
      rr[0] = r0.x; rr[1] = r0.y; rr[2] = r0.z; rr[3] = r0.w;
      rr[4] = r1.x; rr[5] = r1.y; rr[6] = r1.z; rr[7] = r1.w;
#pragma unroll
      for (int q = 0; q < 8; ++q) val[q] = true;
    } else {
#pragma unroll
      for (int q = 0; q < 8; ++q) {
        int i = i0 + q;
        val[q] = (i < E);
        if (val[q]) { dd[q] = dst[i]; ss[q] = src[i]; rr[q] = rij[i]; }
        else { dd[q] = 0; ss[q] = 0; rr[q] = 0.0f; }
      }
    }
    int bk[8];
    unsigned ry[8];
#pragma unroll
    for (int q = 0; q < 8; ++q) {
      bk[q] = dd[q] >> 10;
      int k = (int)(rr[q] * ((float)KTAB * 0.2f) + 0.5f);
      if (k > KTAB) k = KTAB;
      ry[q] = ((unsigned)ss[q] << 16) | (unsigned)k;
      if (val[q]) atomicAdd(&cnt[bk[q]], 1);
    }
    __syncthreads();
    if (tid < 64) {
      int v = cnt[tid];
      int x = v;
      for (int o = 1; o < 64; o <<= 1) {
        int y = __shfl_up(x, o);
        if (tid >= o) x += y;
      }
      cbase[tid] = x - v;
      cpos[tid] = x - v;
      if (tid == 63) tot_s = x;
    }
    __syncthreads();
#pragma unroll
    for (int q = 0; q < 8; ++q) {
      if (val[q]) {
        int slot = atomicAdd(&cpos[bk[q]], 1);
        ord[slot] = make_uint2((unsigned)dd[q], ry[q]);
        obk[slot] = (unsigned char)bk[q];
      }
    }
    __syncthreads();
    if (tid < 64 && cnt[tid] > 0) gpos[tid] = atomicAdd(&gcur[tid], cnt[tid]);
    __syncthreads();
    const int tot = tot_s;
    for (int t = tid; t < tot; t += 256) {
      int b2 = obk[t];
      rec[gpos[b2] + (t - cbase[b2])] = ord[t];
    }
    __syncthreads();
  }
}

// Phase 2: per bucket, sequential-read records, place ep into L2-resident window.
__global__ __launch_bounds__(256) void k_place(const uint2* __restrict__ rec,
                                               const int* __restrict__ bbase,
                                               int* __restrict__ cur,
                                               unsigned* __restrict__ ep) {
  const int b = blockIdx.x & 63;
  const int sub = blockIdx.x >> 6;
  const int lo = bbase[b], hi = bbase[b + 1];
  for (int i = lo + sub * 256 + threadIdx.x; i < hi; i += 8 * 256) {
    uint2 e = rec[i];
    int pos = atomicAdd(&cur[e.x], 1);
    ep[pos] = e.y;
  }
}

// bf16 nearest-neighbor table: Tb[l][g][d] = bf16(W(r_g)[d] * C(r_g)).
__global__ __launch_bounds__(256) void k_tables(const float* __restrict__ Wf1,
                                                const float* __restrict__ bf1,
                                                const float* __restrict__ Wf2,
                                                const float* __restrict__ bf2,
                                                __hip_bfloat16* __restrict__ Tb) {
  __shared__ float w1[25 * D64];
  __shared__ float w2[D64 * D64];
  __shared__ float rb[4][D64];
  const int lane = threadIdx.x & 63;
  const int wsl = threadIdx.x >> 6;
  const int l = blockIdx.x / 129;
  const int gb = blockIdx.x % 129;
  for (int i = threadIdx.x; i < 25 * D64; i += 256) w1[i] = Wf1[l * 25 * D64 + i];
  for (int i = threadIdx.x; i < D64 * D64; i += 256) w2[i] = Wf2[l * D64 * D64 + i];
  __syncthreads();
  const float bias1 = bf1[l * D64 + lane];
  const float bias2 = bf2[l * D64 + lane];
  const float width = 5.0f / 24.0f;
  const float coeff = -0.5f / (width * width);
  for (int gi = 0; gi < 8; ++gi) {
    const int g = gb * 32 + wsl * 8 + gi;
    if (g >= TROWS) break;
    const float r = (float)g * (5.0f / KTAB);
    float fv = 0.0f;
    if (lane < 25) { float ddv = r - (float)lane * width; fv = expf(coeff * ddv * ddv); }
    rb[wsl][lane] = fv;   // same-wave LDS reuse; program order preserves deps
    float a1 = bias1;
#pragma unroll
    for (int b = 0; b < 25; ++b)
      a1 = fmaf(rb[wsl][b], w1[b * D64 + lane], a1);
    float sw = swishf(a1);
    rb[wsl][lane] = sw;
    float a2 = bias2;
#pragma unroll
    for (int k = 0; k < D64; ++k)
      a2 = fmaf(rb[wsl][k], w2[k * D64 + lane], a2);
    float C = (r < 5.0f) ? 0.5f * (cosf(r * 0.62831853f) + 1.0f) : 0.0f;
    Tb[(size_t)(l * TROWS + g) * D64 + lane] = __float2bfloat16(a2 * C);
  }
}

// identity norm for layer 0
__global__ void k_nid(float* __restrict__ stats) {
  int d = threadIdx.x;
  stats[128 + d] = 1.0f;
  stats[192 + d] = 0.0f;
}

// x1 = bf16(norm(feat) @ Win) via MFMA.  One wave computes a 16x64 output tile:
// A row = lane&15, k = (lane>>4)*8+j (identical k-map for A and B so any
// within-group permutation cancels); C/D: col=lane&15, row=(lane>>4)*4+reg.
// Win fragments live in registers; NO LDS at all.
__global__ __launch_bounds__(256) void k_x1(const float* __restrict__ feat,
                                            const float* __restrict__ Win,
                                            const float* __restrict__ stats,
                                            __hip_bfloat16* __restrict__ x1, int n) {
  const int lane = threadIdx.x & 63;
  const int r16 = lane & 15;
  const int kg = lane >> 4;
  unsigned short* __restrict__ x1u = (unsigned short*)x1;
  bf16x8 bw[4][2];
#pragma unroll
  for (int ct = 0; ct < 4; ++ct)
#pragma unroll
    for (int ks = 0; ks < 2; ++ks) {
      const int c = ct * 16 + r16;
      const int k0 = ks * 32 + kg * 8;
      bf16x8 v;
#pragma unroll
      for (int j = 0; j < 8; ++j) v[j] = (short)f2b(Win[(k0 + j) * D64 + c]);
      bw[ct][ks] = v;
    }
  float sca[2][8], sha[2][8];
#pragma unroll
  for (int ks = 0; ks < 2; ++ks) {
    const int k0 = ks * 32 + kg * 8;
#pragma unroll
    for (int j = 0; j < 8; ++j) {
      sca[ks][j] = stats[128 + k0 + j];
      sha[ks][j] = stats[192 + k0 + j];
    }
  }
  const int ntile = (n + 15) >> 4;
  const int wid = (blockIdx.x * blockDim.x + threadIdx.x) >> 6;
  const int nw = (gridDim.x * blockDim.x) >> 6;
  for (int t = wid; t < ntile; t += nw) {
    const int base = t * 16;
    int ra = base + r16; if (ra > n - 1) ra = n - 1;
    bf16x8 a[2];
#pragma unroll
    for (int ks = 0; ks < 2; ++ks) {
      const float* p = &feat[(size_t)ra * D64 + ks * 32 + kg * 8];
      bf16x8 v;
#pragma unroll
      for (int j = 0; j < 8; ++j) v[j] = (short)f2b(fmaf(p[j], sca[ks][j], sha[ks][j]));
      a[ks] = v;
    }
    f32x4 acc[4];
#pragma unroll
    for (int ct = 0; ct < 4; ++ct) {
      f32x4 z = {0.0f, 0.0f, 0.0f, 0.0f};
      z = __builtin_amdgcn_mfma_f32_16x16x32_bf16(a[0], bw[ct][0], z, 0, 0, 0);
      z = __builtin_amdgcn_mfma_f32_16x16x32_bf16(a[1], bw[ct][1], z, 0, 0, 0);
      acc[ct] = z;
    }
#pragma unroll
    for (int ct = 0; ct < 4; ++ct)
#pragma unroll
      for (int r = 0; r < 4; ++r) {
        const int rm = base + kg * 4 + r;
        if (rm < n) x1u[(size_t)rm * D64 + ct * 16 + r16] = f2b(acc[ct][r]);
      }
  }
}

// agg[nd] = sum over incoming edges of x1[src] * Tb[k]; half-wave edge pairing.
__global__ __launch_bounds__(256) void k_gather(const __hip_bfloat16* __restrict__ x1,
                                                const __hip_bfloat16* __restrict__ Tb,
                                                const unsigned* __restrict__ ep,
                                                const int* __restrict__ rp,
                                                float* __restrict__ agg, int n) {
  const int lane = threadIdx.x & 63;
  const int half = lane >> 5;
  const int fl = lane & 31;            // features 2*fl, 2*fl+1
  const unsigned short* __restrict__ x1u = (const unsigned short*)x1;
  const unsigned short* __restrict__ Tu = (const unsigned short*)Tb;
  const int wid = (blockIdx.x * blockDim.x + threadIdx.x) >> 6;
  const int nw = (gridDim.x * blockDim.x) >> 6;
  for (int nd = wid; nd < n; nd += nw) {
    const int j0 = rp[nd], j1 = rp[nd + 1];
    float ax0 = 0.0f, ay0 = 0.0f, ax1 = 0.0f, ay1 = 0.0f;
    int j = j0;
    for (; j + 8 <= j1; j += 8) {
      const uint4a uu = *(const uint4a*)(ep + j + 4 * half);
      const unsigned u0 = uu.x, u1 = uu.y, u2 = uu.z, u3 = uu.w;
      const ushort2 xA = *(const ushort2*)&x1u[(size_t)(u0 >> 16) * D64 + fl * 2];
      const ushort2 xB = *(const ushort2*)&x1u[(size_t)(u1 >> 16) * D64 + fl * 2];
      const ushort2 xC = *(const ushort2*)&x1u[(size_t)(u2 >> 16) * D64 + fl * 2];
      const ushort2 xD = *(const ushort2*)&x1u[(size_t)(u3 >> 16) * D64 + fl * 2];
      const ushort2 tA = *(const ushort2*)&Tu[(size_t)(u0 & 0x1FFFu) * D64 + fl * 2];
      const ushort2 tB = *(const ushort2*)&Tu[(size_t)(u1 & 0x1FFFu) * D64 + fl * 2];
      const ushort2 tC = *(const ushort2*)&Tu[(size_t)(u2 & 0x1FFFu) * D64 + fl * 2];
      const ushort2 tD = *(const ushort2*)&Tu[(size_t)(u3 & 0x1FFFu) * D64 + fl * 2];
      ax0 = fmaf(bx(xA.x), bx(tA.x), ax0);
      ay0 = fmaf(bx(xA.y), bx(tA.y), ay0);
      ax1 = fmaf(bx(xB.x), bx(tB.x), ax1);
      ay1 = fmaf(bx(xB.y), bx(tB.y), ay1);
      ax0 = fmaf(bx(xC.x), bx(tC.x), ax0);
      ay0 = fmaf(bx(xC.y), bx(tC.y), ay0);
      ax1 = fmaf(bx(xD.x), bx(tD.x), ax1);
      ay1 = fmaf(bx(xD.y), bx(tD.y), ay1);
    }
    for (; j + 2 <= j1; j += 2) {
      const unsigned u = ep[j + half];
      const ushort2 xr = *(const ushort2*)&x1u[(size_t)(u >> 16) * D64 + fl * 2];
      const ushort2 tw = *(const ushort2*)&Tu[(size_t)(u & 0x1FFFu) * D64 + fl * 2];
      ax0 = fmaf(bx(xr.x), bx(tw.x), ax0);
      ay0 = fmaf(bx(xr.y), bx(tw.y), ay0);
    }
    if (j < j1 && half == 0) {
      const unsigned u = ep[j];
      const ushort2 xr = *(const ushort2*)&x1u[(size_t)(u >> 16) * D64 + fl * 2];
      const ushort2 tw = *(const ushort2*)&Tu[(size_t)(u & 0x1FFFu) * D64 + fl * 2];
      ax0 = fmaf(bx(xr.x), bx(tw.x), ax0);
      ay0 = fmaf(bx(xr.y), bx(tw.y), ay0);
    }
    float ax = ax0 + ax1, ay = ay0 + ay1;
    ax += __shfl_xor(ax, 32);
    ay += __shfl_xor(ay, 32);
    if (half == 0) {
      float2 o; o.x = ax; o.y = ay;
      *(float2*)&agg[(size_t)nd * D64 + fl * 2] = o;
    }
  }
}

// y = swish(agg@Wo1+bo1)@Wo2+bo2; feat = norm(feat) + y, via two chained MFMA
// GEMMs per 16-row tile.  Weights in registers; only a per-wave 16x72-bf16 LDS
// tile for the swish-output transpose (C-layout write -> A-layout read).
__global__ __launch_bounds__(256) void k_out(const float* __restrict__ agg,
                                             const float* __restrict__ Wo1,
                                             const float* __restrict__ bo1,
                                             const float* __restrict__ Wo2,
                                             const float* __restrict__ bo2,
                                             const float* __restrict__ nstats,
                                             float* __restrict__ feat,
                                             float* __restrict__ part, int n) {
  __shared__ __align__(16) unsigned short tl[4][16 * 72];
  const int lane = threadIdx.x & 63;
  const int wsl = threadIdx.x >> 6;
  const int r16 = lane & 15;
  const int kg = lane >> 4;
  bf16x8 bw1[4][2], bw2[4][2];
#pragma unroll
  for (int ct = 0; ct < 4; ++ct)
#pragma unroll
    for (int ks = 0; ks < 2; ++ks) {
      const int c = ct * 16 + r16;
      const int k0 = ks * 32 + kg * 8;
      bf16x8 v1, v2;
#pragma unroll
      for (int j = 0; j < 8; ++j) {
        v1[j] = (short)f2b(Wo1[(k0 + j) * D64 + c]);
        v2[j] = (short)f2b(Wo2[(k0 + j) * D64 + c]);
      }
      bw1[ct][ks] = v1;
      bw2[ct][ks] = v2;
    }
  float b1c[4], b2c[4], scc[4], shc[4];
#pragma unroll
  for (int ct = 0; ct < 4; ++ct) {
    b1c[ct] = bo1[ct * 16 + r16];
    b2c[ct] = bo2[ct * 16 + r16];
    scc[ct] = nstats[128 + ct * 16 + r16];
    shc[ct] = nstats[192 + ct * 16 + r16];
  }
  float sf[4] = {0, 0, 0, 0}, sf2[4] = {0, 0, 0, 0};
  unsigned short* tw = tl[wsl];
  const int ntile = (n + 15) >> 4;
  const int wid = (blockIdx.x * blockDim.x + threadIdx.x) >> 6;
  const int nw = (gridDim.x * blockDim.x) >> 6;
  for (int t = wid; t < ntile; t += nw) {
    const int base = t * 16;
    int ra = base + r16; if (ra > n - 1) ra = n - 1;
    bf16x8 a1[2];
#pragma unroll
    for (int ks = 0; ks < 2; ++ks) {
      const float* p = &agg[(size_t)ra * D64 + ks * 32 + kg * 8];
      bf16x8 v;
#pragma unroll
      for (int j = 0; j < 8; ++j) v[j] = (short)f2b(p[j]);
      a1[ks] = v;
    }
    f32x4 acc[4];
#pragma unroll
    for (int ct = 0; ct < 4; ++ct) {
      f32x4 z = {0.0f, 0.0f, 0.0f, 0.0f};
      z = __builtin_amdgcn_mfma_f32_16x16x32_bf16(a1[0], bw1[ct][0], z, 0, 0, 0);
      z = __builtin_amdgcn_mfma_f32_16x16x32_bf16(a1[1], bw1[ct][1], z, 0, 0, 0);
      acc[ct] = z;
    }
    // swish + bias -> LDS (transpose C-layout -> A-layout); same-wave, compiler
    // inserts the lgkmcnt before the dependent reads.
#pragma unroll
    for (int ct = 0; ct < 4; ++ct)
#pragma unroll
      for (int r = 0; r < 4; ++r)
        tw[(kg * 4 + r) * 72 + ct * 16 + r16] = f2b(swishf(acc[ct][r] + b1c[ct]));
    bf16x8 a2[2];
#pragma unroll
    for (int ks = 0; ks < 2; ++ks)
      a2[ks] = *(const bf16x8*)&tw[r16 * 72 + ks * 32 + kg * 8];
    f32x4 acc2[4];
#pragma unroll
    for (int ct = 0; ct < 4; ++ct) {
      f32x4 z = {0.0f, 0.0f, 0.0f, 0.0f};
      z = __builtin_amdgcn_mfma_f32_16x16x32_bf16(a2[0], bw2[ct][0], z, 0, 0, 0);
      z = __builtin_amdgcn_mfma_f32_16x16x32_bf16(a2[1], bw2[ct][1], z, 0, 0, 0);
      acc2[ct] = z;
    }
#pragma unroll
    for (int ct = 0; ct < 4; ++ct)
#pragma unroll
      for (int r = 0; r < 4; ++r) {
        const int rm = base + kg * 4 + r;
        if (rm < n) {
          const size_t ix = (size_t)rm * D64 + ct * 16 + r16;
          float fv = fmaf(feat[ix], scc[ct], shc[ct]);
          float fn = fv + acc2[ct][r] + b2c[ct];
          feat[ix] = fn;
          sf[ct] += fn;
          sf2[ct] += fn * fn;
        }
      }
  }
  const int slot = blockIdx.x & 63;
#pragma unroll
  for (int ct = 0; ct < 4; ++ct) {
    atomAddF(&part[slot * 128 + ct * 16 + r16], sf[ct]);
    atomAddF(&part[slot * 128 + 64 + ct * 16 + r16], sf2[ct]);
  }
}

// reduce striped partials; compute scale/shift. var = E[f^2] - (2a - a^2) mu^2
__global__ void k_nfin(const float* __restrict__ part, float* __restrict__ stats,
                       const float* __restrict__ al, const float* __restrict__ ga,
                       const float* __restrict__ be, int n) {
  __shared__ float red[128];
  const int t = threadIdx.x;  // 128 threads
  float s = 0.0f;
#pragma unroll 8
  for (int b = 0; b < 64; ++b) s += part[b * 128 + t];
  red[t] = s;
  __syncthreads();
  if (t < 64) {
    float invN = 1.0f / (float)n;
    float mu = red[t] * invN;
    float ex2 = red[64 + t] * invN;
    float a = al[t];
    float var = ex2 - (2.0f * a - a * a) * mu * mu;
    float sc = ga[t] * rsqrtf(var + 1e-5f);
    stats[128 + t] = sc;
    stats[192 + t] = be[t] - sc * a * mu;
  }
}

// apply the last layer's norm (materialize normalized feat) + column max
__global__ __launch_bounds__(256) void k_colmax(float* __restrict__ feat,
                                                const float* __restrict__ stats,
                                                unsigned* __restrict__ um, int n) {
  const int lane = threadIdx.x & 63;
  const int wid = (blockIdx.x * blockDim.x + threadIdx.x) >> 6;
  const int nw = (gridDim.x * blockDim.x) >> 6;
  const float sc = stats[128 + lane], sh = stats[192 + lane];
  float m = -3.402823e38f;
  for (int r = wid; r < n; r += nw) {
    float f = fmaf(feat[(size_t)r * D64 + lane], sc, sh);
    feat[(size_t)r * D64 + lane] = f;
    m = fmaxf(m, f);
  }
  atomicMax(&um[lane], fkey(m));
}

__global__ __launch_bounds__(256) void k_colsum(const float* __restrict__ feat,
                                                float* __restrict__ rd, int n) {
  const unsigned* um = (const unsigned*)rd;
  const int lane = threadIdx.x & 63;
  const int wid = (blockIdx.x * blockDim.x + threadIdx.x) >> 6;
  const int nw = (gridDim.x * blockDim.x) >> 6;
  const float mx = funkey(um[lane]);
  float s1 = 0.0f, s2 = 0.0f;
  for (int r = wid; r < n; r += nw) {
    float f = feat[(size_t)r * D64 + lane];
    float e = expf(f - mx);
    s1 += e;
    s2 += e * f;
  }
  atomAddF(&rd[64 + lane], s1);
  atomAddF(&rd[128 + lane], s2);
}

__global__ void k_pooled(const float* __restrict__ rd, float* __restrict__ out) {
  int d = threadIdx.x;
  if (d < D64) out[d] = rd[128 + d] / rd[64 + d];
}

extern "C" void kernel_launch(void* const* d_in, const int* in_sizes, int n_in,
                              void* d_out, int out_size, void* d_ws, size_t ws_size,
                              hipStream_t stream) {
  const int* z = (const int*)d_in[0];
  const int* src = (const int*)d_in[1];
  const int* dst = (const int*)d_in[2];
  const float* rij = (const float*)d_in[3];
  const float* emb = (const float*)d_in[4];
  const float* Win = (const float*)d_in[5];
  const float* Wf1 = (const float*)d_in[6];
  const float* bf1 = (const float*)d_in[7];
  const float* Wf2 = (const float*)d_in[8];
  const float* bf2 = (const float*)d_in[9];
  const float* Wo1 = (const float*)d_in[10];
  const float* bo1 = (const float*)d_in[11];
  const float* Wo2 = (const float*)d_in[12];
  const float* bo2 = (const float*)d_in[13];
  const float* gal = (const float*)d_in[14];
  const float* gga = (const float*)d_in[15];
  const float* gbe = (const float*)d_in[16];
  const int n = in_sizes[0];
  const int E = in_sizes[1];
  (void)n_in; (void)out_size; (void)ws_size;

  float* feat = (float*)d_out;                 // [n,64] lives in d_out
  float* pooled = feat + (size_t)n * D64;      // [64]

  char* w = (char*)d_ws;
  size_t off = 0;
  auto take = [&](size_t bytes) {
    size_t o = (off + 255) & ~(size_t)255;
    off = o + bytes;
    return (void*)(w + o);
  };
  __hip_bfloat16* x1 = (__hip_bfloat16*)take((size_t)n * D64 * 2);
  size_t aggrec = ((size_t)n * D64 * 4 > (size_t)E * 8) ? (size_t)n * D64 * 4
                                                        : (size_t)E * 8;
  float* agg = (float*)take(aggrec);           // aliased with rec (disjoint lifetimes)
  uint2* rec = (uint2*)agg;
  float* stats = (float*)take(256 * 4);
  float* part = (float*)take(64 * 128 * 4);
  float* rdst = (float*)take(192 * 4);
  __hip_bfloat16* Tb = (__hip_bfloat16*)take((size_t)3 * TROWS * D64 * 2);
  int* deg = (int*)take((size_t)n * 4);
  int* rp = (int*)take((size_t)(n + 1) * 4);
  int* cur = (int*)take((size_t)n * 4);
  unsigned* ep = (unsigned*)take((size_t)E * 4);
  int* bbase = (int*)take(65 * 4);
  int* gcur = (int*)take(64 * 4);

  hipMemsetAsync(deg, 0, (size_t)n * 4, stream);
  k_init<<<(n * D64 + 255) / 256, 256, 0, stream>>>(z, emb, feat, n * D64);
  k_hist<<<1024, 256, 0, stream>>>(dst, deg, E);
  k_scan<<<1, 1024, 0, stream>>>(deg, rp, cur, n);
  k_bbase<<<1, 128, 0, stream>>>(rp, bbase, gcur, n);
  k_part<<<784, 256, 0, stream>>>(src, dst, rij, gcur, rec, E);
  k_place<<<512, 256, 0, stream>>>(rec, bbase, cur, ep);
  k_tables<<<3 * 129, 256, 0, stream>>>(Wf1, bf1, Wf2, bf2, Tb);
  k_nid<<<1, 64, 0, stream>>>(stats);

  for (int l = 0; l < 3; ++l) {
    k_x1<<<512, 256, 0, stream>>>(feat, Win + (size_t)l * D64 * D64, stats, x1, n);
    hipMemsetAsync(part, 0, 64 * 128 * 4, stream);
    k_gather<<<2048, 256, 0, stream>>>(x1, Tb + (size_t)l * TROWS * D64,
                                       ep, rp, agg, n);
    k_out<<<512, 256, 0, stream>>>(agg, Wo1 + (size_t)l * D64 * D64, bo1 + l * D64,
                                   Wo2 + (size_t)l * D64 * D64, bo2 + l * D64, stats,
                                   feat, part, n);
    k_nfin<<<1, 128, 0, stream>>>(part, stats, gal + l * D64, gga + l * D64, gbe + l * D64, n);
  }

  hipMemsetAsync(rdst, 0, 192 * 4, stream);
  k_colmax<<<512, 256, 0, stream>>>(feat, stats, (unsigned*)rdst, n);
  k_colsum<<<512, 256, 0, stream>>>(feat, rdst, n);
  k_pooled<<<1, 64, 0, stream>>>(rdst, pooled);
}

// Round 10
// 434.548 us; speedup vs baseline: 2.8857x; 1.2979x over previous
//
#include <hip/hip_runtime.h>
#include <hip/hip_bf16.h>
#include <math.h>

#define D64 64
#define KTAB 4096          // nearest-neighbor table intervals over r in [0,5]
#define TROWS (KTAB + 1)   // 4097 rows

typedef unsigned int uint4a __attribute__((ext_vector_type(4), aligned(4)));
typedef __attribute__((ext_vector_type(8))) short bf16x8;   // 8 bf16 (4 VGPRs)
typedef __attribute__((ext_vector_type(4))) float f32x4;    // MFMA C/D frag

// ---------------- helpers ----------------
__device__ __forceinline__ void atomAddF(float* p, float v) {
  __hip_atomic_fetch_add(p, v, __ATOMIC_RELAXED, __HIP_MEMORY_SCOPE_AGENT);
}
__device__ __forceinline__ unsigned fkey(float f) {
  unsigned u = __float_as_uint(f);
  return (u & 0x80000000u) ? ~u : (u | 0x80000000u);
}
__device__ __forceinline__ float funkey(unsigned k) {
  return __uint_as_float((k & 0x80000000u) ? (k & 0x7fffffffu) : ~k);
}
__device__ __forceinline__ float swishf(float x) { return x / (1.0f + expf(-x)); }
__device__ __forceinline__ float bx(unsigned short s) {
  return __uint_as_float((unsigned)s << 16);
}
// fp32 -> bf16 bits, round-to-nearest-even (finite inputs)
__device__ __forceinline__ unsigned short f2b(float f) {
  unsigned u = __float_as_uint(f);
  return (unsigned short)((u + 0x7FFFu + ((u >> 16) & 1u)) >> 16);
}

// feat[i,d] = emb[z[i],d]
__global__ void k_init(const int* __restrict__ z, const float* __restrict__ emb,
                       float* __restrict__ feat, int total) {
  int idx = blockIdx.x * 256 + threadIdx.x;
  if (idx < total) feat[idx] = emb[z[idx >> 6] * D64 + (idx & 63)];
}

// 64-bin bucket histogram of dst>>10.  LDS-accumulated; only 64 device
// atomics per block (R9 lesson: 1.6M random device atomics = ~32B HBM
// write-through each = 50MB traffic; LDS first).
__global__ __launch_bounds__(256) void k_hist64(const int* __restrict__ dst,
                                                int* __restrict__ bcnt, int E) {
  __shared__ int c[64];
  if (threadIdx.x < 64) c[threadIdx.x] = 0;
  __syncthreads();
  const int step = gridDim.x * blockDim.x * 4;
  for (int i = (blockIdx.x * blockDim.x + threadIdx.x) * 4; i < E; i += step) {
    if (i + 4 <= E) {
      int4 d = *(const int4*)&dst[i];
      atomicAdd(&c[d.x >> 10], 1);
      atomicAdd(&c[d.y >> 10], 1);
      atomicAdd(&c[d.z >> 10], 1);
      atomicAdd(&c[d.w >> 10], 1);
    } else {
      for (int q = i; q < E; ++q) atomicAdd(&c[dst[q] >> 10], 1);
    }
  }
  __syncthreads();
  if (threadIdx.x < 64 && c[threadIdx.x] > 0)
    atomicAdd(&bcnt[threadIdx.x], c[threadIdx.x]);
}

// tiny exclusive scan of the 64 bucket counts -> bbase[0..64], gcur
__global__ void k_scan64(const int* __restrict__ bcnt, int* __restrict__ bbase,
                         int* __restrict__ gcur) {
  const int t = threadIdx.x;  // 64 threads
  int v = bcnt[t];
  int x = v;
  for (int o = 1; o < 64; o <<= 1) {
    int y = __shfl_up(x, o);
    if (t >= o) x += y;
  }
  bbase[t] = x - v;
  gcur[t] = x - v;
  if (t == 63) bbase[64] = x;
}

// Phase 1 of CSR build: LDS counting-sort per 2048-edge chunk into 64 dst-range
// buckets, contiguous chunked copy-out (full-line writes).
__global__ __launch_bounds__(256) void k_part(const int* __restrict__ src,
                                              const int* __restrict__ dst,
                                              const float* __restrict__ rij,
                                              int* __restrict__ gcur,
                                              uint2* __restrict__ rec, int E) {
  __shared__ uint2 ord[2048];
  __shared__ unsigned char obk[2048];
  __shared__ int cnt[64], cbase[64], cpos[64], gpos[64];
  __shared__ int tot_s;
  const int tid = threadIdx.x;
  for (int c = blockIdx.x; c * 2048 < E; c += gridDim.x) {
    const int s0 = c * 2048;
    if (tid < 64) cnt[tid] = 0;
    __syncthreads();
    const int i0 = s0 + tid * 8;
    int dd[8], ss[8];
    float rr[8];
    bool val[8];
    if (i0 + 8 <= E) {
      int4 d0 = *(const int4*)&dst[i0];
      int4 d1 = *(const int4*)&dst[i0 + 4];
      int4 sa = *(const int4*)&src[i0];
      int4 sb2 = *(const int4*)&src[i0 + 4];
      float4 r0 = *(const float4*)&rij[i0];
      float4 r1 = *(const float4*)&rij[i0 + 4];
      dd[0] = d0.x; dd[1] = d0.y; dd[2] = d0.z; dd[3] = d0.w;
      dd[4] = d1.x; dd[5] = d1.y; dd[6] = d1.z; dd[7] = d1.w;
      ss[0] = sa.x; ss[1] = sa.y; ss[2] = sa.z; ss[3] = sa.w;
      ss[4] = sb2.x; ss[5] = sb2.y; ss[6] = sb2.z; ss[7] = sb2.w;
      rr[0] = r0.x; rr[1] = r0.y; rr[2] = r0.z; rr[3] = r0.w;
      rr[4] = r1.x; rr[5] = r1.y; rr[6] = r1.z; rr[7] = r1.w;
#pragma unroll
      for (int q = 0; q < 8; ++q) val[q] = true;
    } else {
#pragma unroll
      for (int q = 0; q < 8; ++q) {
        int i = i0 + q;
        val[q] = (i < E);
        if (val[q]) { dd[q] = dst[i]; ss[q] = src[i]; rr[q] = rij[i]; }
        else { dd[q] = 0; ss[q] = 0; rr[q] = 0.0f; }
      }
    }
    int bk[8];
    unsigned ry[8];
#pragma unroll
    for (int q = 0; q < 8; ++q) {
      bk[q] = dd[q] >> 10;
      int k = (int)(rr[q] * ((float)KTAB * 0.2f) + 0.5f);
      if (k > KTAB) k = KTAB;
      ry[q] = ((unsigned)ss[q] << 16) | (unsigned)k;
      if (val[q]) atomicAdd(&cnt[bk[q]], 1);
    }
    __syncthreads();
    if (tid < 64) {
      int v = cnt[tid];
      int x = v;
      for (int o = 1; o < 64; o <<= 1) {
        int y = __shfl_up(x, o);
        if (tid >= o) x += y;
      }
      cbase[tid] = x - v;
      cpos[tid] = x - v;
      if (tid == 63) tot_s = x;
    }
    __syncthreads();
#pragma unroll
    for (int q = 0; q < 8; ++q) {
      if (val[q]) {
        int slot = atomicAdd(&cpos[bk[q]], 1);
        ord[slot] = make_uint2((unsigned)dd[q], ry[q]);
        obk[slot] = (unsigned char)bk[q];
      }
    }
    __syncthreads();
    if (tid < 64 && cnt[tid] > 0) gpos[tid] = atomicAdd(&gcur[tid], cnt[tid]);
    __syncthreads();
    const int tot = tot_s;
    for (int t = tid; t < tot; t += 256) {
      int b2 = obk[t];
      rec[gpos[b2] + (t - cbase[b2])] = ord[t];
    }
    __syncthreads();
  }
}

// Phase 2: one 1024-thread block per bucket.  Pass 1: LDS histogram of the
// bucket's records; LDS scan -> per-node offsets; coalesced rp write.  Pass 2:
// place ep via LDS-atomic cursors.  ZERO per-edge device atomics (replaces
// k_hist + k_scan + k_place + deg/cur).
__global__ __launch_bounds__(1024) void k_build(const uint2* __restrict__ rec,
                                                const int* __restrict__ bbase,
                                                int* __restrict__ rp,
                                                unsigned* __restrict__ ep, int n) {
  __shared__ int cnt[1024];
  __shared__ int curl[1024];
  const int tid = threadIdx.x;
  const int b = blockIdx.x;
  const int lo = bbase[b], hi = bbase[b + 1];
  cnt[tid] = 0;
  __syncthreads();
  for (int i = lo + tid; i < hi; i += 1024)
    atomicAdd(&cnt[rec[i].x & 1023], 1);
  __syncthreads();
  const int v = cnt[tid];
  // Hillis-Steele inclusive scan over 1024 entries
  for (int o = 1; o < 1024; o <<= 1) {
    int t = (tid >= o) ? cnt[tid - o] : 0;
    __syncthreads();
    cnt[tid] += t;
    __syncthreads();
  }
  const int excl = cnt[tid] - v;
  curl[tid] = excl;
  const int node = (b << 10) + tid;
  if (node <= n) rp[node] = lo + excl;
  __syncthreads();
  for (int i = lo + tid; i < hi; i += 1024) {
    uint2 e = rec[i];
    int pos = lo + atomicAdd(&curl[e.x & 1023], 1);
    ep[pos] = e.y;
  }
}

// bf16 nearest-neighbor table: Tb[l][g][d] = bf16(W(r_g)[d] * C(r_g)).
__global__ __launch_bounds__(256) void k_tables(const float* __restrict__ Wf1,
                                                const float* __restrict__ bf1,
                                                const float* __restrict__ Wf2,
                                                const float* __restrict__ bf2,
                                                __hip_bfloat16* __restrict__ Tb) {
  __shared__ float w1[25 * D64];
  __shared__ float w2[D64 * D64];
  __shared__ float rb[4][D64];
  const int lane = threadIdx.x & 63;
  const int wsl = threadIdx.x >> 6;
  const int l = blockIdx.x / 129;
  const int gb = blockIdx.x % 129;
  for (int i = threadIdx.x; i < 25 * D64; i += 256) w1[i] = Wf1[l * 25 * D64 + i];
  for (int i = threadIdx.x; i < D64 * D64; i += 256) w2[i] = Wf2[l * D64 * D64 + i];
  __syncthreads();
  const float bias1 = bf1[l * D64 + lane];
  const float bias2 = bf2[l * D64 + lane];
  const float width = 5.0f / 24.0f;
  const float coeff = -0.5f / (width * width);
  for (int gi = 0; gi < 8; ++gi) {
    const int g = gb * 32 + wsl * 8 + gi;
    if (g >= TROWS) break;
    const float r = (float)g * (5.0f / KTAB);
    float fv = 0.0f;
    if (lane < 25) { float ddv = r - (float)lane * width; fv = expf(coeff * ddv * ddv); }
    rb[wsl][lane] = fv;   // same-wave LDS reuse; program order preserves deps
    float a1 = bias1;
#pragma unroll
    for (int b = 0; b < 25; ++b)
      a1 = fmaf(rb[wsl][b], w1[b * D64 + lane], a1);
    float sw = swishf(a1);
    rb[wsl][lane] = sw;
    float a2 = bias2;
#pragma unroll
    for (int k = 0; k < D64; ++k)
      a2 = fmaf(rb[wsl][k], w2[k * D64 + lane], a2);
    float C = (r < 5.0f) ? 0.5f * (cosf(r * 0.62831853f) + 1.0f) : 0.0f;
    Tb[(size_t)(l * TROWS + g) * D64 + lane] = __float2bfloat16(a2 * C);
  }
}

// identity norm for layer 0
__global__ void k_nid(float* __restrict__ stats) {
  int d = threadIdx.x;
  stats[128 + d] = 1.0f;
  stats[192 + d] = 0.0f;
}

// x1 = bf16(norm(feat) @ Win) via MFMA.  One wave computes a 16x64 output tile;
// Win fragments live in registers; NO LDS at all.
__global__ __launch_bounds__(256) void k_x1(const float* __restrict__ feat,
                                            const float* __restrict__ Win,
                                            const float* __restrict__ stats,
                                            __hip_bfloat16* __restrict__ x1, int n) {
  const int lane = threadIdx.x & 63;
  const int r16 = lane & 15;
  const int kg = lane >> 4;
  unsigned short* __restrict__ x1u = (unsigned short*)x1;
  bf16x8 bw[4][2];
#pragma unroll
  for (int ct = 0; ct < 4; ++ct)
#pragma unroll
    for (int ks = 0; ks < 2; ++ks) {
      const int c = ct * 16 + r16;
      const int k0 = ks * 32 + kg * 8;
      bf16x8 v;
#pragma unroll
      for (int j = 0; j < 8; ++j) v[j] = (short)f2b(Win[(k0 + j) * D64 + c]);
      bw[ct][ks] = v;
    }
  float sca[2][8], sha[2][8];
#pragma unroll
  for (int ks = 0; ks < 2; ++ks) {
    const int k0 = ks * 32 + kg * 8;
#pragma unroll
    for (int j = 0; j < 8; ++j) {
      sca[ks][j] = stats[128 + k0 + j];
      sha[ks][j] = stats[192 + k0 + j];
    }
  }
  const int ntile = (n + 15) >> 4;
  const int wid = (blockIdx.x * blockDim.x + threadIdx.x) >> 6;
  const int nw = (gridDim.x * blockDim.x) >> 6;
  for (int t = wid; t < ntile; t += nw) {
    const int base = t * 16;
    int ra = base + r16; if (ra > n - 1) ra = n - 1;
    bf16x8 a[2];
#pragma unroll
    for (int ks = 0; ks < 2; ++ks) {
      const float* p = &feat[(size_t)ra * D64 + ks * 32 + kg * 8];
      bf16x8 v;
#pragma unroll
      for (int j = 0; j < 8; ++j) v[j] = (short)f2b(fmaf(p[j], sca[ks][j], sha[ks][j]));
      a[ks] = v;
    }
    f32x4 acc[4];
#pragma unroll
    for (int ct = 0; ct < 4; ++ct) {
      f32x4 z = {0.0f, 0.0f, 0.0f, 0.0f};
      z = __builtin_amdgcn_mfma_f32_16x16x32_bf16(a[0], bw[ct][0], z, 0, 0, 0);
      z = __builtin_amdgcn_mfma_f32_16x16x32_bf16(a[1], bw[ct][1], z, 0, 0, 0);
      acc[ct] = z;
    }
#pragma unroll
    for (int ct = 0; ct < 4; ++ct)
#pragma unroll
      for (int r = 0; r < 4; ++r) {
        const int rm = base + kg * 4 + r;
        if (rm < n) x1u[(size_t)rm * D64 + ct * 16 + r16] = f2b(acc[ct][r]);
      }
  }
}

// agg[nd] = sum over incoming edges of x1[src] * Tb[k]; half-wave edge pairing.
__global__ __launch_bounds__(256) void k_gather(const __hip_bfloat16* __restrict__ x1,
                                                const __hip_bfloat16* __restrict__ Tb,
                                                const unsigned* __restrict__ ep,
                                                const int* __restrict__ rp,
                                                float* __restrict__ agg, int n) {
  const int lane = threadIdx.x & 63;
  const int half = lane >> 5;
  const int fl = lane & 31;            // features 2*fl, 2*fl+1
  const unsigned short* __restrict__ x1u = (const unsigned short*)x1;
  const unsigned short* __restrict__ Tu = (const unsigned short*)Tb;
  const int wid = (blockIdx.x * blockDim.x + threadIdx.x) >> 6;
  const int nw = (gridDim.x * blockDim.x) >> 6;
  for (int nd = wid; nd < n; nd += nw) {
    const int j0 = rp[nd], j1 = rp[nd + 1];
    float ax0 = 0.0f, ay0 = 0.0f, ax1 = 0.0f, ay1 = 0.0f;
    int j = j0;
    for (; j + 8 <= j1; j += 8) {
      const uint4a uu = *(const uint4a*)(ep + j + 4 * half);
      const unsigned u0 = uu.x, u1 = uu.y, u2 = uu.z, u3 = uu.w;
      const ushort2 xA = *(const ushort2*)&x1u[(size_t)(u0 >> 16) * D64 + fl * 2];
      const ushort2 xB = *(const ushort2*)&x1u[(size_t)(u1 >> 16) * D64 + fl * 2];
      const ushort2 xC = *(const ushort2*)&x1u[(size_t)(u2 >> 16) * D64 + fl * 2];
      const ushort2 xD = *(const ushort2*)&x1u[(size_t)(u3 >> 16) * D64 + fl * 2];
      const ushort2 tA = *(const ushort2*)&Tu[(size_t)(u0 & 0x1FFFu) * D64 + fl * 2];
      const ushort2 tB = *(const ushort2*)&Tu[(size_t)(u1 & 0x1FFFu) * D64 + fl * 2];
      const ushort2 tC = *(const ushort2*)&Tu[(size_t)(u2 & 0x1FFFu) * D64 + fl * 2];
      const ushort2 tD = *(const ushort2*)&Tu[(size_t)(u3 & 0x1FFFu) * D64 + fl * 2];
      ax0 = fmaf(bx(xA.x), bx(tA.x), ax0);
      ay0 = fmaf(bx(xA.y), bx(tA.y), ay0);
      ax1 = fmaf(bx(xB.x), bx(tB.x), ax1);
      ay1 = fmaf(bx(xB.y), bx(tB.y), ay1);
      ax0 = fmaf(bx(xC.x), bx(tC.x), ax0);
      ay0 = fmaf(bx(xC.y), bx(tC.y), ay0);
      ax1 = fmaf(bx(xD.x), bx(tD.x), ax1);
      ay1 = fmaf(bx(xD.y), bx(tD.y), ay1);
    }
    for (; j + 2 <= j1; j += 2) {
      const unsigned u = ep[j + half];
      const ushort2 xr = *(const ushort2*)&x1u[(size_t)(u >> 16) * D64 + fl * 2];
      const ushort2 tw = *(const ushort2*)&Tu[(size_t)(u & 0x1FFFu) * D64 + fl * 2];
      ax0 = fmaf(bx(xr.x), bx(tw.x), ax0);
      ay0 = fmaf(bx(xr.y), bx(tw.y), ay0);
    }
    if (j < j1 && half == 0) {
      const unsigned u = ep[j];
      const ushort2 xr = *(const ushort2*)&x1u[(size_t)(u >> 16) * D64 + fl * 2];
      const ushort2 tw = *(const ushort2*)&Tu[(size_t)(u & 0x1FFFu) * D64 + fl * 2];
      ax0 = fmaf(bx(xr.x), bx(tw.x), ax0);
      ay0 = fmaf(bx(xr.y), bx(tw.y), ay0);
    }
    float ax = ax0 + ax1, ay = ay0 + ay1;
    ax += __shfl_xor(ax, 32);
    ay += __shfl_xor(ay, 32);
    if (half == 0) {
      float2 o; o.x = ax; o.y = ay;
      *(float2*)&agg[(size_t)nd * D64 + fl * 2] = o;
    }
  }
}

// y = swish(agg@Wo1+bo1)@Wo2+bo2; feat = norm(feat) + y, via two chained MFMA
// GEMMs per 16-row tile.  Weights in registers; per-wave 16x72-bf16 LDS tile
// only for the swish-output transpose.
__global__ __launch_bounds__(256) void k_out(const float* __restrict__ agg,
                                             const float* __restrict__ Wo1,
                                             const float* __restrict__ bo1,
                                             const float* __restrict__ Wo2,
                                             const float* __restrict__ bo2,
                                             const float* __restrict__ nstats,
                                             float* __restrict__ feat,
                                             float* __restrict__ part, int n) {
  __shared__ __align__(16) unsigned short tl[4][16 * 72];
  const int lane = threadIdx.x & 63;
  const int wsl = threadIdx.x >> 6;
  const int r16 = lane & 15;
  const int kg = lane >> 4;
  bf16x8 bw1[4][2], bw2[4][2];
#pragma unroll
  for (int ct = 0; ct < 4; ++ct)
#pragma unroll
    for (int ks = 0; ks < 2; ++ks) {
      const int c = ct * 16 + r16;
      const int k0 = ks * 32 + kg * 8;
      bf16x8 v1, v2;
#pragma unroll
      for (int j = 0; j < 8; ++j) {
        v1[j] = (short)f2b(Wo1[(k0 + j) * D64 + c]);
        v2[j] = (short)f2b(Wo2[(k0 + j) * D64 + c]);
      }
      bw1[ct][ks] = v1;
      bw2[ct][ks] = v2;
    }
  float b1c[4], b2c[4], scc[4], shc[4];
#pragma unroll
  for (int ct = 0; ct < 4; ++ct) {
    b1c[ct] = bo1[ct * 16 + r16];
    b2c[ct] = bo2[ct * 16 + r16];
    scc[ct] = nstats[128 + ct * 16 + r16];
    shc[ct] = nstats[192 + ct * 16 + r16];
  }
  float sf[4] = {0, 0, 0, 0}, sf2[4] = {0, 0, 0, 0};
  unsigned short* tw = tl[wsl];
  const int ntile = (n + 15) >> 4;
  const int wid = (blockIdx.x * blockDim.x + threadIdx.x) >> 6;
  const int nw = (gridDim.x * blockDim.x) >> 6;
  for (int t = wid; t < ntile; t += nw) {
    const int base = t * 16;
    int ra = base + r16; if (ra > n - 1) ra = n - 1;
    bf16x8 a1[2];
#pragma unroll
    for (int ks = 0; ks < 2; ++ks) {
      const float* p = &agg[(size_t)ra * D64 + ks * 32 + kg * 8];
      bf16x8 v;
#pragma unroll
      for (int j = 0; j < 8; ++j) v[j] = (short)f2b(p[j]);
      a1[ks] = v;
    }
    f32x4 acc[4];
#pragma unroll
    for (int ct = 0; ct < 4; ++ct) {
      f32x4 z = {0.0f, 0.0f, 0.0f, 0.0f};
      z = __builtin_amdgcn_mfma_f32_16x16x32_bf16(a1[0], bw1[ct][0], z, 0, 0, 0);
      z = __builtin_amdgcn_mfma_f32_16x16x32_bf16(a1[1], bw1[ct][1], z, 0, 0, 0);
      acc[ct] = z;
    }
#pragma unroll
    for (int ct = 0; ct < 4; ++ct)
#pragma unroll
      for (int r = 0; r < 4; ++r)
        tw[(kg * 4 + r) * 72 + ct * 16 + r16] = f2b(swishf(acc[ct][r] + b1c[ct]));
    bf16x8 a2[2];
#pragma unroll
    for (int ks = 0; ks < 2; ++ks)
      a2[ks] = *(const bf16x8*)&tw[r16 * 72 + ks * 32 + kg * 8];
    f32x4 acc2[4];
#pragma unroll
    for (int ct = 0; ct < 4; ++ct) {
      f32x4 z = {0.0f, 0.0f, 0.0f, 0.0f};
      z = __builtin_amdgcn_mfma_f32_16x16x32_bf16(a2[0], bw2[ct][0], z, 0, 0, 0);
      z = __builtin_amdgcn_mfma_f32_16x16x32_bf16(a2[1], bw2[ct][1], z, 0, 0, 0);
      acc2[ct] = z;
    }
#pragma unroll
    for (int ct = 0; ct < 4; ++ct)
#pragma unroll
      for (int r = 0; r < 4; ++r) {
        const int rm = base + kg * 4 + r;
        if (rm < n) {
          const size_t ix = (size_t)rm * D64 + ct * 16 + r16;
          float fv = fmaf(feat[ix], scc[ct], shc[ct]);
          float fn = fv + acc2[ct][r] + b2c[ct];
          feat[ix] = fn;
          sf[ct] += fn;
          sf2[ct] += fn * fn;
        }
      }
  }
  const int slot = blockIdx.x & 63;
#pragma unroll
  for (int ct = 0; ct < 4; ++ct) {
    atomAddF(&part[slot * 128 + ct * 16 + r16], sf[ct]);
    atomAddF(&part[slot * 128 + 64 + ct * 16 + r16], sf2[ct]);
  }
}

// reduce striped partials; compute scale/shift. var = E[f^2] - (2a - a^2) mu^2
__global__ void k_nfin(const float* __restrict__ part, float* __restrict__ stats,
                       const float* __restrict__ al, const float* __restrict__ ga,
                       const float* __restrict__ be, int n) {
  __shared__ float red[128];
  const int t = threadIdx.x;  // 128 threads
  float s = 0.0f;
#pragma unroll 8
  for (int b = 0; b < 64; ++b) s += part[b * 128 + t];
  red[t] = s;
  __syncthreads();
  if (t < 64) {
    float invN = 1.0f / (float)n;
    float mu = red[t] * invN;
    float ex2 = red[64 + t] * invN;
    float a = al[t];
    float var = ex2 - (2.0f * a - a * a) * mu * mu;
    float sc = ga[t] * rsqrtf(var + 1e-5f);
    stats[128 + t] = sc;
    stats[192 + t] = be[t] - sc * a * mu;
  }
}

// apply the last layer's norm (materialize normalized feat) + column max
__global__ __launch_bounds__(256) void k_colmax(float* __restrict__ feat,
                                                const float* __restrict__ stats,
                                                unsigned* __restrict__ um, int n) {
  const int lane = threadIdx.x & 63;
  const int wid = (blockIdx.x * blockDim.x + threadIdx.x) >> 6;
  const int nw = (gridDim.x * blockDim.x) >> 6;
  const float sc = stats[128 + lane], sh = stats[192 + lane];
  float m = -3.402823e38f;
  for (int r = wid; r < n; r += nw) {
    float f = fmaf(feat[(size_t)r * D64 + lane], sc, sh);
    feat[(size_t)r * D64 + lane] = f;
    m = fmaxf(m, f);
  }
  atomicMax(&um[lane], fkey(m));
}

__global__ __launch_bounds__(256) void k_colsum(const float* __restrict__ feat,
                                                float* __restrict__ rd, int n) {
  const unsigned* um = (const unsigned*)rd;
  const int lane = threadIdx.x & 63;
  const int wid = (blockIdx.x * blockDim.x + threadIdx.x) >> 6;
  const int nw = (gridDim.x * blockDim.x) >> 6;
  const float mx = funkey(um[lane]);
  float s1 = 0.0f, s2 = 0.0f;
  for (int r = wid; r < n; r += nw) {
    float f = feat[(size_t)r * D64 + lane];
    float e = expf(f - mx);
    s1 += e;
    s2 += e * f;
  }
  atomAddF(&rd[64 + lane], s1);
  atomAddF(&rd[128 + lane], s2);
}

__global__ void k_pooled(const float* __restrict__ rd, float* __restrict__ out) {
  int d = threadIdx.x;
  if (d < D64) out[d] = rd[128 + d] / rd[64 + d];
}

extern "C" void kernel_launch(void* const* d_in, const int* in_sizes, int n_in,
                              void* d_out, int out_size, void* d_ws, size_t ws_size,
                              hipStream_t stream) {
  const int* z = (const int*)d_in[0];
  const int* src = (const int*)d_in[1];
  const int* dst = (const int*)d_in[2];
  const float* rij = (const float*)d_in[3];
  const float* emb = (const float*)d_in[4];
  const float* Win = (const float*)d_in[5];
  const float* Wf1 = (const float*)d_in[6];
  const float* bf1 = (const float*)d_in[7];
  const float* Wf2 = (const float*)d_in[8];
  const float* bf2 = (const float*)d_in[9];
  const float* Wo1 = (const float*)d_in[10];
  const float* bo1 = (const float*)d_in[11];
  const float* Wo2 = (const float*)d_in[12];
  const float* bo2 = (const float*)d_in[13];
  const float* gal = (const float*)d_in[14];
  const float* gga = (const float*)d_in[15];
  const float* gbe = (const float*)d_in[16];
  const int n = in_sizes[0];
  const int E = in_sizes[1];
  (void)n_in; (void)out_size; (void)ws_size;

  float* feat = (float*)d_out;                 // [n,64] lives in d_out
  float* pooled = feat + (size_t)n * D64;      // [64]

  char* w = (char*)d_ws;
  size_t off = 0;
  auto take = [&](size_t bytes) {
    size_t o = (off + 255) & ~(size_t)255;
    off = o + bytes;
    return (void*)(w + o);
  };
  __hip_bfloat16* x1 = (__hip_bfloat16*)take((size_t)n * D64 * 2);
  size_t aggrec = ((size_t)n * D64 * 4 > (size_t)E * 8) ? (size_t)n * D64 * 4
                                                        : (size_t)E * 8;
  float* agg = (float*)take(aggrec);           // aliased with rec (disjoint lifetimes)
  uint2* rec = (uint2*)agg;
  float* stats = (float*)take(256 * 4);
  float* part = (float*)take(64 * 128 * 4);
  float* rdst = (float*)take(192 * 4);
  __hip_bfloat16* Tb = (__hip_bfloat16*)take((size_t)3 * TROWS * D64 * 2);
  int* rp = (int*)take((size_t)(n + 1) * 4);
  unsigned* ep = (unsigned*)take((size_t)E * 4);
  int* bbase = (int*)take(65 * 4);
  int* gcur = (int*)take(64 * 4);
  int* bcnt = (int*)take(64 * 4);

  hipMemsetAsync(bcnt, 0, 64 * 4, stream);
  k_init<<<(n * D64 + 255) / 256, 256, 0, stream>>>(z, emb, feat, n * D64);
  k_hist64<<<256, 256, 0, stream>>>(dst, bcnt, E);
  k_scan64<<<1, 64, 0, stream>>>(bcnt, bbase, gcur);
  k_part<<<784, 256, 0, stream>>>(src, dst, rij, gcur, rec, E);
  k_build<<<64, 1024, 0, stream>>>(rec, bbase, rp, ep, n);
  k_tables<<<3 * 129, 256, 0, stream>>>(Wf1, bf1, Wf2, bf2, Tb);
  k_nid<<<1, 64, 0, stream>>>(stats);

  for (int l = 0; l < 3; ++l) {
    k_x1<<<512, 256, 0, stream>>>(feat, Win + (size_t)l * D64 * D64, stats, x1, n);
    hipMemsetAsync(part, 0, 64 * 128 * 4, stream);
    k_gather<<<2048, 256, 0, stream>>>(x1, Tb + (size_t)l * TROWS * D64,
                                       ep, rp, agg, n);
    k_out<<<512, 256, 0, stream>>>(agg, Wo1 + (size_t)l * D64 * D64, bo1 + l * D64,
                                   Wo2 + (size_t)l * D64 * D64, bo2 + l * D64, stats,
                                   feat, part, n);
    k_nfin<<<1, 128, 0, stream>>>(part, stats, gal + l * D64, gga + l * D64, gbe + l * D64, n);
  }

  hipMemsetAsync(rdst, 0, 192 * 4, stream);
  k_colmax<<<512, 256, 0, stream>>>(feat, stats, (unsigned*)rdst, n);
  k_colsum<<<512, 256, 0, stream>>>(feat, rdst, n);
  k_pooled<<<1, 64, 0, stream>>>(rdst, pooled);
}

// Round 11
// 350.554 us; speedup vs baseline: 3.5772x; 1.2396x over previous
//
#include <hip/hip_runtime.h>
#include <hip/hip_bf16.h>
#include <math.h>

#define D64 64
#define KTAB 4096          // nearest-neighbor table intervals over r in [0,5]
#define TROWS (KTAB + 1)   // 4097 rows

typedef unsigned int uint4a __attribute__((ext_vector_type(4), aligned(4)));
typedef __attribute__((ext_vector_type(8))) short bf16x8;   // 8 bf16 (4 VGPRs)
typedef __attribute__((ext_vector_type(4))) float f32x4;    // MFMA C/D frag

// ---------------- helpers ----------------
__device__ __forceinline__ void atomAddF(float* p, float v) {
  __hip_atomic_fetch_add(p, v, __ATOMIC_RELAXED, __HIP_MEMORY_SCOPE_AGENT);
}
__device__ __forceinline__ float swishf(float x) { return x / (1.0f + expf(-x)); }
__device__ __forceinline__ float bx(unsigned short s) {
  return __uint_as_float((unsigned)s << 16);
}
// fp32 -> bf16 bits, round-to-nearest-even (finite inputs)
__device__ __forceinline__ unsigned short f2b(float f) {
  unsigned u = __float_as_uint(f);
  return (unsigned short)((u + 0x7FFFu + ((u >> 16) & 1u)) >> 16);
}

// feat[i,d] = emb[z[i],d]
__global__ void k_init(const int* __restrict__ z, const float* __restrict__ emb,
                       float* __restrict__ feat, int total) {
  int idx = blockIdx.x * 256 + threadIdx.x;
  if (idx < total) feat[idx] = emb[z[idx >> 6] * D64 + (idx & 63)];
}

// 64-bin bucket histogram of dst>>10 (LDS-accumulated, 64 device atomics/block)
__global__ __launch_bounds__(256) void k_hist64(const int* __restrict__ dst,
                                                int* __restrict__ bcnt, int E) {
  __shared__ int c[64];
  if (threadIdx.x < 64) c[threadIdx.x] = 0;
  __syncthreads();
  const int step = gridDim.x * blockDim.x * 4;
  for (int i = (blockIdx.x * blockDim.x + threadIdx.x) * 4; i < E; i += step) {
    if (i + 4 <= E) {
      int4 d = *(const int4*)&dst[i];
      atomicAdd(&c[d.x >> 10], 1);
      atomicAdd(&c[d.y >> 10], 1);
      atomicAdd(&c[d.z >> 10], 1);
      atomicAdd(&c[d.w >> 10], 1);
    } else {
      for (int q = i; q < E; ++q) atomicAdd(&c[dst[q] >> 10], 1);
    }
  }
  __syncthreads();
  if (threadIdx.x < 64 && c[threadIdx.x] > 0)
    atomicAdd(&bcnt[threadIdx.x], c[threadIdx.x]);
}

// tiny exclusive scan of the 64 bucket counts -> bbase[0..64], gcur
__global__ void k_scan64(const int* __restrict__ bcnt, int* __restrict__ bbase,
                         int* __restrict__ gcur) {
  const int t = threadIdx.x;  // 64 threads
  int v = bcnt[t];
  int x = v;
  for (int o = 1; o < 64; o <<= 1) {
    int y = __shfl_up(x, o);
    if (t >= o) x += y;
  }
  bbase[t] = x - v;
  gcur[t] = x - v;
  if (t == 63) bbase[64] = x;
}

// Phase 1 of CSR build: LDS counting-sort per 2048-edge chunk into 64 dst-range
// buckets, contiguous chunked copy-out (full-line writes).
__global__ __launch_bounds__(256) void k_part(const int* __restrict__ src,
                                              const int* __restrict__ dst,
                                              const float* __restrict__ rij,
                                              int* __restrict__ gcur,
                                              uint2* __restrict__ rec, int E) {
  __shared__ uint2 ord[2048];
  __shared__ unsigned char obk[2048];
  __shared__ int cnt[64], cbase[64], cpos[64], gpos[64];
  __shared__ int tot_s;
  const int tid = threadIdx.x;
  for (int c = blockIdx.x; c * 2048 < E; c += gridDim.x) {
    const int s0 = c * 2048;
    if (tid < 64) cnt[tid] = 0;
    __syncthreads();
    const int i0 = s0 + tid * 8;
    int dd[8], ss[8];
    float rr[8];
    bool val[8];
    if (i0 + 8 <= E) {
      int4 d0 = *(const int4*)&dst[i0];
      int4 d1 = *(const int4*)&dst[i0 + 4];
      int4 sa = *(const int4*)&src[i0];
      int4 sb2 = *(const int4*)&src[i0 + 4];
      float4 r0 = *(const float4*)&rij[i0];
      float4 r1 = *(const float4*)&rij[i0 + 4];
      dd[0] = d0.x; dd[1] = d0.y; dd[2] = d0.z; dd[3] = d0.w;
      dd[4] = d1.x; dd[5] = d1.y; dd[6] = d1.z; dd[7] = d1.w;
      ss[0] = sa.x; ss[1] = sa.y; ss[2] = sa.z; ss[3] = sa.w;
      ss[4] = sb2.x; ss[5] = sb2.y; ss[6] = sb2.z; ss[7] = sb2.w;
      rr[0] = r0.x; rr[1] = r0.y; rr[2] = r0.z; rr[3] = r0.w;
      rr[4] = r1.x; rr[5] = r1.y; rr[6] = r1.z; rr[7] = r1.w;
#pragma unroll
      for (int q = 0; q < 8; ++q) val[q] = true;
    } else {
#pragma unroll
      for (int q = 0; q < 8; ++q) {
        int i = i0 + q;
        val[q] = (i < E);
        if (val[q]) { dd[q] = dst[i]; ss[q] = src[i]; rr[q] = rij[i]; }
        else { dd[q] = 0; ss[q] = 0; rr[q] = 0.0f; }
      }
    }
    int bk[8];
    unsigned ry[8];
#pragma unroll
    for (int q = 0; q < 8; ++q) {
      bk[q] = dd[q] >> 10;
      int k = (int)(rr[q] * ((float)KTAB * 0.2f) + 0.5f);
      if (k > KTAB) k = KTAB;
      ry[q] = ((unsigned)ss[q] << 16) | (unsigned)k;
      if (val[q]) atomicAdd(&cnt[bk[q]], 1);
    }
    __syncthreads();
    if (tid < 64) {
      int v = cnt[tid];
      int x = v;
      for (int o = 1; o < 64; o <<= 1) {
        int y = __shfl_up(x, o);
        if (tid >= o) x += y;
      }
      cbase[tid] = x - v;
      cpos[tid] = x - v;
      if (tid == 63) tot_s = x;
    }
    __syncthreads();
#pragma unroll
    for (int q = 0; q < 8; ++q) {
      if (val[q]) {
        int slot = atomicAdd(&cpos[bk[q]], 1);
        ord[slot] = make_uint2((unsigned)dd[q], ry[q]);
        obk[slot] = (unsigned char)bk[q];
      }
    }
    __syncthreads();
    if (tid < 64 && cnt[tid] > 0) gpos[tid] = atomicAdd(&gcur[tid], cnt[tid]);
    __syncthreads();
    const int tot = tot_s;
    for (int t = tid; t < tot; t += 256) {
      int b2 = obk[t];
      rec[gpos[b2] + (t - cbase[b2])] = ord[t];
    }
    __syncthreads();
  }
}

// Phase 2: one 1024-thread block per bucket; LDS histogram + scan -> rp,
// LDS-atomic cursors -> ep.  Zero per-edge device atomics.
__global__ __launch_bounds__(1024) void k_build(const uint2* __restrict__ rec,
                                                const int* __restrict__ bbase,
                                                int* __restrict__ rp,
                                                unsigned* __restrict__ ep, int n) {
  __shared__ int cnt[1024];
  __shared__ int curl[1024];
  const int tid = threadIdx.x;
  const int b = blockIdx.x;
  const int lo = bbase[b], hi = bbase[b + 1];
  cnt[tid] = 0;
  __syncthreads();
  for (int i = lo + tid; i < hi; i += 1024)
    atomicAdd(&cnt[rec[i].x & 1023], 1);
  __syncthreads();
  const int v = cnt[tid];
  for (int o = 1; o < 1024; o <<= 1) {
    int t = (tid >= o) ? cnt[tid - o] : 0;
    __syncthreads();
    cnt[tid] += t;
    __syncthreads();
  }
  const int excl = cnt[tid] - v;
  curl[tid] = excl;
  const int node = (b << 10) + tid;
  if (node <= n) rp[node] = lo + excl;
  __syncthreads();
  for (int i = lo + tid; i < hi; i += 1024) {
    uint2 e = rec[i];
    int pos = lo + atomicAdd(&curl[e.x & 1023], 1);
    ep[pos] = e.y;
  }
}

// bf16 nearest-neighbor table: Tb[l][g][d] = bf16(W(r_g)[d] * C(r_g)).
__global__ __launch_bounds__(256) void k_tables(const float* __restrict__ Wf1,
                                                const float* __restrict__ bf1,
                                                const float* __restrict__ Wf2,
                                                const float* __restrict__ bf2,
                                                __hip_bfloat16* __restrict__ Tb) {
  __shared__ float w1[25 * D64];
  __shared__ float w2[D64 * D64];
  __shared__ float rb[4][D64];
  const int lane = threadIdx.x & 63;
  const int wsl = threadIdx.x >> 6;
  const int l = blockIdx.x / 129;
  const int gb = blockIdx.x % 129;
  for (int i = threadIdx.x; i < 25 * D64; i += 256) w1[i] = Wf1[l * 25 * D64 + i];
  for (int i = threadIdx.x; i < D64 * D64; i += 256) w2[i] = Wf2[l * D64 * D64 + i];
  __syncthreads();
  const float bias1 = bf1[l * D64 + lane];
  const float bias2 = bf2[l * D64 + lane];
  const float width = 5.0f / 24.0f;
  const float coeff = -0.5f / (width * width);
  for (int gi = 0; gi < 8; ++gi) {
    const int g = gb * 32 + wsl * 8 + gi;
    if (g >= TROWS) break;
    const float r = (float)g * (5.0f / KTAB);
    float fv = 0.0f;
    if (lane < 25) { float ddv = r - (float)lane * width; fv = expf(coeff * ddv * ddv); }
    rb[wsl][lane] = fv;   // same-wave LDS reuse; program order preserves deps
    float a1 = bias1;
#pragma unroll
    for (int b = 0; b < 25; ++b)
      a1 = fmaf(rb[wsl][b], w1[b * D64 + lane], a1);
    float sw = swishf(a1);
    rb[wsl][lane] = sw;
    float a2 = bias2;
#pragma unroll
    for (int k = 0; k < D64; ++k)
      a2 = fmaf(rb[wsl][k], w2[k * D64 + lane], a2);
    float C = (r < 5.0f) ? 0.5f * (cosf(r * 0.62831853f) + 1.0f) : 0.0f;
    Tb[(size_t)(l * TROWS + g) * D64 + lane] = __float2bfloat16(a2 * C);
  }
}

// identity norm for layer 0
__global__ void k_nid(float* __restrict__ stats) {
  int d = threadIdx.x;
  stats[128 + d] = 1.0f;
  stats[192 + d] = 0.0f;
}

// x1 = bf16(norm(feat) @ Win) via MFMA.  One wave computes a 16x64 output tile;
// Win fragments live in registers; NO LDS at all.
__global__ __launch_bounds__(256) void k_x1(const float* __restrict__ feat,
                                            const float* __restrict__ Win,
                                            const float* __restrict__ stats,
                                            __hip_bfloat16* __restrict__ x1, int n) {
  const int lane = threadIdx.x & 63;
  const int r16 = lane & 15;
  const int kg = lane >> 4;
  unsigned short* __restrict__ x1u = (unsigned short*)x1;
  bf16x8 bw[4][2];
#pragma unroll
  for (int ct = 0; ct < 4; ++ct)
#pragma unroll
    for (int ks = 0; ks < 2; ++ks) {
      const int c = ct * 16 + r16;
      const int k0 = ks * 32 + kg * 8;
      bf16x8 v;
#pragma unroll
      for (int j = 0; j < 8; ++j) v[j] = (short)f2b(Win[(k0 + j) * D64 + c]);
      bw[ct][ks] = v;
    }
  float sca[2][8], sha[2][8];
#pragma unroll
  for (int ks = 0; ks < 2; ++ks) {
    const int k0 = ks * 32 + kg * 8;
#pragma unroll
    for (int j = 0; j < 8; ++j) {
      sca[ks][j] = stats[128 + k0 + j];
      sha[ks][j] = stats[192 + k0 + j];
    }
  }
  const int ntile = (n + 15) >> 4;
  const int wid = (blockIdx.x * blockDim.x + threadIdx.x) >> 6;
  const int nw = (gridDim.x * blockDim.x) >> 6;
  for (int t = wid; t < ntile; t += nw) {
    const int base = t * 16;
    int ra = base + r16; if (ra > n - 1) ra = n - 1;
    bf16x8 a[2];
#pragma unroll
    for (int ks = 0; ks < 2; ++ks) {
      const float* p = &feat[(size_t)ra * D64 + ks * 32 + kg * 8];
      bf16x8 v;
#pragma unroll
      for (int j = 0; j < 8; ++j) v[j] = (short)f2b(fmaf(p[j], sca[ks][j], sha[ks][j]));
      a[ks] = v;
    }
    f32x4 acc[4];
#pragma unroll
    for (int ct = 0; ct < 4; ++ct) {
      f32x4 z = {0.0f, 0.0f, 0.0f, 0.0f};
      z = __builtin_amdgcn_mfma_f32_16x16x32_bf16(a[0], bw[ct][0], z, 0, 0, 0);
      z = __builtin_amdgcn_mfma_f32_16x16x32_bf16(a[1], bw[ct][1], z, 0, 0, 0);
      acc[ct] = z;
    }
#pragma unroll
    for (int ct = 0; ct < 4; ++ct)
#pragma unroll
      for (int r = 0; r < 4; ++r) {
        const int rm = base + kg * 4 + r;
        if (rm < n) x1u[(size_t)rm * D64 + ct * 16 + r16] = f2b(acc[ct][r]);
      }
  }
}

// agg[nd] = sum over incoming edges of x1[src] * Tb[k]; half-wave edge pairing.
__global__ __launch_bounds__(256) void k_gather(const __hip_bfloat16* __restrict__ x1,
                                                const __hip_bfloat16* __restrict__ Tb,
                                                const unsigned* __restrict__ ep,
                                                const int* __restrict__ rp,
                                                float* __restrict__ agg, int n) {
  const int lane = threadIdx.x & 63;
  const int half = lane >> 5;
  const int fl = lane & 31;            // features 2*fl, 2*fl+1
  const unsigned short* __restrict__ x1u = (const unsigned short*)x1;
  const unsigned short* __restrict__ Tu = (const unsigned short*)Tb;
  const int wid = (blockIdx.x * blockDim.x + threadIdx.x) >> 6;
  const int nw = (gridDim.x * blockDim.x) >> 6;
  for (int nd = wid; nd < n; nd += nw) {
    const int j0 = rp[nd], j1 = rp[nd + 1];
    float ax0 = 0.0f, ay0 = 0.0f, ax1 = 0.0f, ay1 = 0.0f;
    int j = j0;
    for (; j + 8 <= j1; j += 8) {
      const uint4a uu = *(const uint4a*)(ep + j + 4 * half);
      const unsigned u0 = uu.x, u1 = uu.y, u2 = uu.z, u3 = uu.w;
      const ushort2 xA = *(const ushort2*)&x1u[(size_t)(u0 >> 16) * D64 + fl * 2];
      const ushort2 xB = *(const ushort2*)&x1u[(size_t)(u1 >> 16) * D64 + fl * 2];
      const ushort2 xC = *(const ushort2*)&x1u[(size_t)(u2 >> 16) * D64 + fl * 2];
      const ushort2 xD = *(const ushort2*)&x1u[(size_t)(u3 >> 16) * D64 + fl * 2];
      const ushort2 tA = *(const ushort2*)&Tu[(size_t)(u0 & 0x1FFFu) * D64 + fl * 2];
      const ushort2 tB = *(const ushort2*)&Tu[(size_t)(u1 & 0x1FFFu) * D64 + fl * 2];
      const ushort2 tC = *(const ushort2*)&Tu[(size_t)(u2 & 0x1FFFu) * D64 + fl * 2];
      const ushort2 tD = *(const ushort2*)&Tu[(size_t)(u3 & 0x1FFFu) * D64 + fl * 2];
      ax0 = fmaf(bx(xA.x), bx(tA.x), ax0);
      ay0 = fmaf(bx(xA.y), bx(tA.y), ay0);
      ax1 = fmaf(bx(xB.x), bx(tB.x), ax1);
      ay1 = fmaf(bx(xB.y), bx(tB.y), ay1);
      ax0 = fmaf(bx(xC.x), bx(tC.x), ax0);
      ay0 = fmaf(bx(xC.y), bx(tC.y), ay0);
      ax1 = fmaf(bx(xD.x), bx(tD.x), ax1);
      ay1 = fmaf(bx(xD.y), bx(tD.y), ay1);
    }
    for (; j + 2 <= j1; j += 2) {
      const unsigned u = ep[j + half];
      const ushort2 xr = *(const ushort2*)&x1u[(size_t)(u >> 16) * D64 + fl * 2];
      const ushort2 tw = *(const ushort2*)&Tu[(size_t)(u & 0x1FFFu) * D64 + fl * 2];
      ax0 = fmaf(bx(xr.x), bx(tw.x), ax0);
      ay0 = fmaf(bx(xr.y), bx(tw.y), ay0);
    }
    if (j < j1 && half == 0) {
      const unsigned u = ep[j];
      const ushort2 xr = *(const ushort2*)&x1u[(size_t)(u >> 16) * D64 + fl * 2];
      const ushort2 tw = *(const ushort2*)&Tu[(size_t)(u & 0x1FFFu) * D64 + fl * 2];
      ax0 = fmaf(bx(xr.x), bx(tw.x), ax0);
      ay0 = fmaf(bx(xr.y), bx(tw.y), ay0);
    }
    float ax = ax0 + ax1, ay = ay0 + ay1;
    ax += __shfl_xor(ax, 32);
    ay += __shfl_xor(ay, 32);
    if (half == 0) {
      float2 o; o.x = ax; o.y = ay;
      *(float2*)&agg[(size_t)nd * D64 + fl * 2] = o;
    }
  }
}

// y = swish(agg@Wo1+bo1)@Wo2+bo2; feat = norm(feat) + y, via two chained MFMA
// GEMMs per 16-row tile.  Weights in registers; per-wave 16x72-bf16 LDS tile
// only for the swish-output transpose.
__global__ __launch_bounds__(256) void k_out(const float* __restrict__ agg,
                                             const float* __restrict__ Wo1,
                                             const float* __restrict__ bo1,
                                             const float* __restrict__ Wo2,
                                             const float* __restrict__ bo2,
                                             const float* __restrict__ nstats,
                                             float* __restrict__ feat,
                                             float* __restrict__ part, int n) {
  __shared__ __align__(16) unsigned short tl[4][16 * 72];
  const int lane = threadIdx.x & 63;
  const int wsl = threadIdx.x >> 6;
  const int r16 = lane & 15;
  const int kg = lane >> 4;
  bf16x8 bw1[4][2], bw2[4][2];
#pragma unroll
  for (int ct = 0; ct < 4; ++ct)
#pragma unroll
    for (int ks = 0; ks < 2; ++ks) {
      const int c = ct * 16 + r16;
      const int k0 = ks * 32 + kg * 8;
      bf16x8 v1, v2;
#pragma unroll
      for (int j = 0; j < 8; ++j) {
        v1[j] = (short)f2b(Wo1[(k0 + j) * D64 + c]);
        v2[j] = (short)f2b(Wo2[(k0 + j) * D64 + c]);
      }
      bw1[ct][ks] = v1;
      bw2[ct][ks] = v2;
    }
  float b1c[4], b2c[4], scc[4], shc[4];
#pragma unroll
  for (int ct = 0; ct < 4; ++ct) {
    b1c[ct] = bo1[ct * 16 + r16];
    b2c[ct] = bo2[ct * 16 + r16];
    scc[ct] = nstats[128 + ct * 16 + r16];
    shc[ct] = nstats[192 + ct * 16 + r16];
  }
  float sf[4] = {0, 0, 0, 0}, sf2[4] = {0, 0, 0, 0};
  unsigned short* tw = tl[wsl];
  const int ntile = (n + 15) >> 4;
  const int wid = (blockIdx.x * blockDim.x + threadIdx.x) >> 6;
  const int nw = (gridDim.x * blockDim.x) >> 6;
  for (int t = wid; t < ntile; t += nw) {
    const int base = t * 16;
    int ra = base + r16; if (ra > n - 1) ra = n - 1;
    bf16x8 a1[2];
#pragma unroll
    for (int ks = 0; ks < 2; ++ks) {
      const float* p = &agg[(size_t)ra * D64 + ks * 32 + kg * 8];
      bf16x8 v;
#pragma unroll
      for (int j = 0; j < 8; ++j) v[j] = (short)f2b(p[j]);
      a1[ks] = v;
    }
    f32x4 acc[4];
#pragma unroll
    for (int ct = 0; ct < 4; ++ct) {
      f32x4 z = {0.0f, 0.0f, 0.0f, 0.0f};
      z = __builtin_amdgcn_mfma_f32_16x16x32_bf16(a1[0], bw1[ct][0], z, 0, 0, 0);
      z = __builtin_amdgcn_mfma_f32_16x16x32_bf16(a1[1], bw1[ct][1], z, 0, 0, 0);
      acc[ct] = z;
    }
#pragma unroll
    for (int ct = 0; ct < 4; ++ct)
#pragma unroll
      for (int r = 0; r < 4; ++r)
        tw[(kg * 4 + r) * 72 + ct * 16 + r16] = f2b(swishf(acc[ct][r] + b1c[ct]));
    bf16x8 a2[2];
#pragma unroll
    for (int ks = 0; ks < 2; ++ks)
      a2[ks] = *(const bf16x8*)&tw[r16 * 72 + ks * 32 + kg * 8];
    f32x4 acc2[4];
#pragma unroll
    for (int ct = 0; ct < 4; ++ct) {
      f32x4 z = {0.0f, 0.0f, 0.0f, 0.0f};
      z = __builtin_amdgcn_mfma_f32_16x16x32_bf16(a2[0], bw2[ct][0], z, 0, 0, 0);
      z = __builtin_amdgcn_mfma_f32_16x16x32_bf16(a2[1], bw2[ct][1], z, 0, 0, 0);
      acc2[ct] = z;
    }
#pragma unroll
    for (int ct = 0; ct < 4; ++ct)
#pragma unroll
      for (int r = 0; r < 4; ++r) {
        const int rm = base + kg * 4 + r;
        if (rm < n) {
          const size_t ix = (size_t)rm * D64 + ct * 16 + r16;
          float fv = fmaf(feat[ix], scc[ct], shc[ct]);
          float fn = fv + acc2[ct][r] + b2c[ct];
          feat[ix] = fn;
          sf[ct] += fn;
          sf2[ct] += fn * fn;
        }
      }
  }
  const int slot = blockIdx.x & 63;
#pragma unroll
  for (int ct = 0; ct < 4; ++ct) {
    atomAddF(&part[slot * 128 + ct * 16 + r16], sf[ct]);
    atomAddF(&part[slot * 128 + 64 + ct * 16 + r16], sf2[ct]);
  }
}

// reduce striped partials; compute scale/shift; ZERO part for its next use
// (saves the per-layer memset launch). var = E[f^2] - (2a - a^2) mu^2
__global__ void k_nfin(float* __restrict__ part, float* __restrict__ stats,
                       const float* __restrict__ al, const float* __restrict__ ga,
                       const float* __restrict__ be, int n) {
  const int t = threadIdx.x;  // 128 threads
  float s = 0.0f;
#pragma unroll 8
  for (int b = 0; b < 64; ++b) s += part[b * 128 + t];
  __shared__ float red[128];
  red[t] = s;
#pragma unroll 8
  for (int b = 0; b < 64; ++b) part[b * 128 + t] = 0.0f;  // own column: no race
  __syncthreads();
  if (t < 64) {
    float invN = 1.0f / (float)n;
    float mu = red[t] * invN;
    float ex2 = red[64 + t] * invN;
    float a = al[t];
    float var = ex2 - (2.0f * a - a * a) * mu * mu;
    float sc = ga[t] * rsqrtf(var + 1e-5f);
    stats[128 + t] = sc;
    stats[192 + t] = be[t] - sc * a * mu;
  }
}

// Fused readout: apply last norm (materialize normalized feat), accumulate
// s1 = sum e^(f-20), s2 = sum f*e^(f-20) per feature into striped partials.
// The fixed shift C=20 replaces the separate column-max pass: pooled =
// s2/s1 is shift-invariant, and |f| <= ~10 for GraphNorm'ed features so
// e^(f-20) in [e^-30, e^-10] -- no overflow/underflow.  4 rows per wave
// iteration = 4 independent load chains (R10: 1-chain colsum was 58us
// latency-bound at 2.5% VALU).
__global__ __launch_bounds__(256) void k_pool(float* __restrict__ feat,
                                              const float* __restrict__ stats,
                                              float* __restrict__ part, int n) {
  const int lane = threadIdx.x & 63;
  const float sc = stats[128 + lane], sh = stats[192 + lane];
  float s1 = 0.0f, s2 = 0.0f;
  const int wid = (blockIdx.x * blockDim.x + threadIdx.x) >> 6;
  const int nw = (gridDim.x * blockDim.x) >> 6;
  int base = wid * 4;
  const int stride = nw * 4;
  for (; base + 4 <= n; base += stride) {
    float f0 = feat[(size_t)(base + 0) * D64 + lane];
    float f1 = feat[(size_t)(base + 1) * D64 + lane];
    float f2 = feat[(size_t)(base + 2) * D64 + lane];
    float f3 = feat[(size_t)(base + 3) * D64 + lane];
    f0 = fmaf(f0, sc, sh);
    f1 = fmaf(f1, sc, sh);
    f2 = fmaf(f2, sc, sh);
    f3 = fmaf(f3, sc, sh);
    feat[(size_t)(base + 0) * D64 + lane] = f0;
    feat[(size_t)(base + 1) * D64 + lane] = f1;
    feat[(size_t)(base + 2) * D64 + lane] = f2;
    feat[(size_t)(base + 3) * D64 + lane] = f3;
    float e0 = expf(f0 - 20.0f);
    float e1 = expf(f1 - 20.0f);
    float e2 = expf(f2 - 20.0f);
    float e3 = expf(f3 - 20.0f);
    s1 += (e0 + e1) + (e2 + e3);
    s2 += fmaf(f0, e0, f1 * e1) + fmaf(f2, e2, f3 * e3);
  }
  for (int r = base; r < n; ++r) {
    float f = fmaf(feat[(size_t)r * D64 + lane], sc, sh);
    feat[(size_t)r * D64 + lane] = f;
    float e = expf(f - 20.0f);
    s1 += e;
    s2 += f * e;
  }
  const int slot = blockIdx.x & 63;
  atomAddF(&part[slot * 128 + lane], s1);
  atomAddF(&part[slot * 128 + 64 + lane], s2);
}

// final reduce of striped pool partials -> pooled = s2/s1
__global__ void k_pooled(const float* __restrict__ part, float* __restrict__ out) {
  int d = threadIdx.x;  // 64 threads
  float s1 = 0.0f, s2 = 0.0f;
#pragma unroll 8
  for (int b = 0; b < 64; ++b) {
    s1 += part[b * 128 + d];
    s2 += part[b * 128 + 64 + d];
  }
  out[d] = s2 / s1;
}

extern "C" void kernel_launch(void* const* d_in, const int* in_sizes, int n_in,
                              void* d_out, int out_size, void* d_ws, size_t ws_size,
                              hipStream_t stream) {
  const int* z = (const int*)d_in[0];
  const int* src = (const int*)d_in[1];
  const int* dst = (const int*)d_in[2];
  const float* rij = (const float*)d_in[3];
  const float* emb = (const float*)d_in[4];
  const float* Win = (const float*)d_in[5];
  const float* Wf1 = (const float*)d_in[6];
  const float* bf1 = (const float*)d_in[7];
  const float* Wf2 = (const float*)d_in[8];
  const float* bf2 = (const float*)d_in[9];
  const float* Wo1 = (const float*)d_in[10];
  const float* bo1 = (const float*)d_in[11];
  const float* Wo2 = (const float*)d_in[12];
  const float* bo2 = (const float*)d_in[13];
  const float* gal = (const float*)d_in[14];
  const float* gga = (const float*)d_in[15];
  const float* gbe = (const float*)d_in[16];
  const int n = in_sizes[0];
  const int E = in_sizes[1];
  (void)n_in; (void)out_size; (void)ws_size;

  float* feat = (float*)d_out;                 // [n,64] lives in d_out
  float* pooled = feat + (size_t)n * D64;      // [64]

  char* w = (char*)d_ws;
  size_t off = 0;
  auto take = [&](size_t bytes) {
    size_t o = (off + 255) & ~(size_t)255;
    off = o + bytes;
    return (void*)(w + o);
  };
  __hip_bfloat16* x1 = (__hip_bfloat16*)take((size_t)n * D64 * 2);
  size_t aggrec = ((size_t)n * D64 * 4 > (size_t)E * 8) ? (size_t)n * D64 * 4
                                                        : (size_t)E * 8;
  float* agg = (float*)take(aggrec);           // aliased with rec (disjoint lifetimes)
  uint2* rec = (uint2*)agg;
  float* stats = (float*)take(256 * 4);
  float* part = (float*)take(64 * 128 * 4);
  __hip_bfloat16* Tb = (__hip_bfloat16*)take((size_t)3 * TROWS * D64 * 2);
  int* rp = (int*)take((size_t)(n + 1) * 4);
  unsigned* ep = (unsigned*)take((size_t)E * 4);
  int* bbase = (int*)take(65 * 4);
  int* gcur = (int*)take(64 * 4);
  int* bcnt = (int*)take(64 * 4);

  hipMemsetAsync(bcnt, 0, 64 * 4, stream);
  hipMemsetAsync(part, 0, 64 * 128 * 4, stream);
  k_init<<<(n * D64 + 255) / 256, 256, 0, stream>>>(z, emb, feat, n * D64);
  k_hist64<<<256, 256, 0, stream>>>(dst, bcnt, E);
  k_scan64<<<1, 64, 0, stream>>>(bcnt, bbase, gcur);
  k_part<<<784, 256, 0, stream>>>(src, dst, rij, gcur, rec, E);
  k_build<<<64, 1024, 0, stream>>>(rec, bbase, rp, ep, n);
  k_tables<<<3 * 129, 256, 0, stream>>>(Wf1, bf1, Wf2, bf2, Tb);
  k_nid<<<1, 64, 0, stream>>>(stats);

  for (int l = 0; l < 3; ++l) {
    k_x1<<<512, 256, 0, stream>>>(feat, Win + (size_t)l * D64 * D64, stats, x1, n);
    k_gather<<<2048, 256, 0, stream>>>(x1, Tb + (size_t)l * TROWS * D64,
                                       ep, rp, agg, n);
    k_out<<<512, 256, 0, stream>>>(agg, Wo1 + (size_t)l * D64 * D64, bo1 + l * D64,
                                   Wo2 + (size_t)l * D64 * D64, bo2 + l * D64, stats,
                                   feat, part, n);
    k_nfin<<<1, 128, 0, stream>>>(part, stats, gal + l * D64, gga + l * D64, gbe + l * D64, n);
  }

  k_pool<<<2048, 256, 0, stream>>>(feat, stats, part, n);
  k_pooled<<<1, 64, 0, stream>>>(part, pooled);
}